// Round 9
// baseline (183.177 us; speedup 1.0000x reference)
//
#include <hip/hip_runtime.h>
#include <hip/hip_bf16.h>

#define B_   2
#define L_   2048
#define C_   256
#define H_   8
#define DK_  32
#define HD_  256
#define RSQRT_DK 0.17677669529663687f  // 1/sqrt(32)
#define NBLK 256

typedef __attribute__((ext_vector_type(8))) short bf16x8;
typedef __attribute__((ext_vector_type(4))) float f32x4;

__device__ __forceinline__ unsigned short f2bf(float x) {
    unsigned int u = __float_as_uint(x);
    u += 0x7fffu + ((u >> 16) & 1u);
    return (unsigned short)(u >> 16);
}
__device__ __forceinline__ float bf2f(unsigned short h) {
    return __uint_as_float((unsigned int)h << 16);
}

// LDS weight-slice layout (per 64x256 plane of shorts): row pitch 256 shorts
// (uniform bank base), 16B-chunk XOR swizzle -> b128 reads/writes at bank floor.
#define WT_IDX(n, k) (((n) << 8) + (((((k) >> 3) ^ ((n) & 7))) << 3) + ((k) & 7))

// Copy pre-converted 64-col weight slice (cols n0..n0+63, k 0..255) from a
// global wT plane into swizzled LDS.  Pure coalesced bf16x8 copy.
__device__ __forceinline__ void stage_wT_copy(
    const unsigned short* __restrict__ wTp, int n0, int tid,
    short* __restrict__ WTh, short* __restrict__ WTl)
{
    #pragma unroll
    for (int it = 0; it < 8; ++it) {
        const int c = tid + it * 256;      // chunk 0..2047
        const int n = c >> 5, k8 = c & 31;
        const size_t go = (size_t)(n0 + n) * 256 + k8 * 8;
        const int o = (n << 8) + ((k8 ^ (n & 7)) << 3);
        *reinterpret_cast<bf16x8*>(&WTh[o]) = *reinterpret_cast<const bf16x8*>(&wTp[go]);
        *reinterpret_cast<bf16x8*>(&WTl[o]) = *reinterpret_cast<const bf16x8*>(&wTp[65536 + go]);
    }
}

// Grid-wide barrier: counters/flags zeroed by hipMemsetAsync before launch.
// Device-scope (agent) atomics + threadfence for cross-XCD release/acquire.
__device__ __forceinline__ void gridbar(unsigned* bar, int slot) {
    __syncthreads();
    if (threadIdx.x == 0) {
        __threadfence();
        unsigned prev = __hip_atomic_fetch_add(&bar[slot * 2], 1u,
                            __ATOMIC_ACQ_REL, __HIP_MEMORY_SCOPE_AGENT);
        if (prev == NBLK - 1) {
            __hip_atomic_store(&bar[slot * 2 + 1], 1u,
                               __ATOMIC_RELEASE, __HIP_MEMORY_SCOPE_AGENT);
        } else {
            while (__hip_atomic_load(&bar[slot * 2 + 1],
                                     __ATOMIC_ACQUIRE, __HIP_MEMORY_SCOPE_AGENT) == 0u)
                __builtin_amdgcn_s_sleep(16);
        }
        __threadfence();
    }
    __syncthreads();
}

// ---------------------------------------------------------------------------
// The whole pipeline in one persistent kernel, 256 blocks x 256 threads.
// P0 prep (convert W -> wT split-bf16 [n][k]; qx/kx/vx -> ah/al split-bf16)
// P1 QKV GEMM (768 units of 64x64, MFMA, LDS-staged W; V col-sum partials)
// P2 attention (interior: 1 row/lane, no staging; global rows: 32 blocks)
// P3 out GEMM (256 units of 64x64, MFMA)
// ---------------------------------------------------------------------------
__global__ __launch_bounds__(256) void bigbird_mega(
    const float* __restrict__ qx, const float* __restrict__ kx, const float* __restrict__ vx,
    const float* __restrict__ WQ, const float* __restrict__ bQ,
    const float* __restrict__ WK, const float* __restrict__ bK,
    const float* __restrict__ WV, const float* __restrict__ bV,
    const float* __restrict__ WO, const float* __restrict__ bO,
    float* __restrict__ q, float* __restrict__ k, float* __restrict__ v,
    unsigned short* __restrict__ zh, unsigned short* __restrict__ zl,
    unsigned short* __restrict__ wT, float* __restrict__ part,
    unsigned short* __restrict__ ah, unsigned short* __restrict__ al,
    unsigned* __restrict__ bar, float* __restrict__ out)
{
    __shared__ __align__(16) char LDSS[66560];
    short* WTh = (short*)LDSS;
    short* WTl = WTh + 16384;
    float* red = (float*)(LDSS + 65536);    // 1 KB, disjoint from planes

    const int blk = blockIdx.x;
    const int tid = threadIdx.x;

    // ===================== P0: prep =====================
    {
        const int tg = blk * 256 + tid;
        #pragma unroll
        for (int n = 0; n < 6; ++n) {
            const int ci = tg + n * 65536;       // 0..393215
            const int proj = ci >> 17;
            const int cj = ci & 131071;
            const float* src = proj == 0 ? qx : (proj == 1 ? kx : vx);
            const float* p = src + (size_t)cj * 8;
            float4 x0 = *reinterpret_cast<const float4*>(p);
            float4 x1 = *reinterpret_cast<const float4*>(p + 4);
            float xs[8] = {x0.x, x0.y, x0.z, x0.w, x1.x, x1.y, x1.z, x1.w};
            bf16x8 hv, lv;
            #pragma unroll
            for (int e = 0; e < 8; ++e) {
                const unsigned short h = f2bf(xs[e]);
                hv[e] = (short)h;
                lv[e] = (short)f2bf(xs[e] - bf2f(h));
            }
            const size_t o = (size_t)proj * 1048576 + (size_t)cj * 8;
            *reinterpret_cast<bf16x8*>(&ah[o]) = hv;
            *reinterpret_cast<bf16x8*>(&al[o]) = lv;
        }
        if (blk < 64) {
            float (*ts)[65] = (float(*)[65])LDSS;
            const int p = blk >> 4, tile = blk & 15;
            const int k0 = (tile >> 2) * 64, n0 = (tile & 3) * 64;
            const float* W = p == 0 ? WQ : (p == 1 ? WK : (p == 2 ? WV : WO));
            unsigned short* Th = wT + (size_t)p * 131072;
            unsigned short* Tl = Th + 65536;
            const int r = tid >> 2, cq = (tid & 3) * 16;
            #pragma unroll
            for (int u = 0; u < 4; ++u) {
                float4 w4 = *reinterpret_cast<const float4*>(&W[(size_t)(k0 + r) * 256 + n0 + cq + u * 4]);
                ts[r][cq + u * 4 + 0] = w4.x;
                ts[r][cq + u * 4 + 1] = w4.y;
                ts[r][cq + u * 4 + 2] = w4.z;
                ts[r][cq + u * 4 + 3] = w4.w;
            }
            __syncthreads();
            bf16x8 hv0, hv1, lv0, lv1;
            #pragma unroll
            for (int e = 0; e < 8; ++e) {
                float x0 = ts[cq + e][r];
                float x1 = ts[cq + 8 + e][r];
                unsigned short h0 = f2bf(x0), h1 = f2bf(x1);
                hv0[e] = (short)h0;  lv0[e] = (short)f2bf(x0 - bf2f(h0));
                hv1[e] = (short)h1;  lv1[e] = (short)f2bf(x1 - bf2f(h1));
            }
            const size_t o = (size_t)(n0 + r) * 256 + k0 + cq;
            *reinterpret_cast<bf16x8*>(&Th[o])     = hv0;
            *reinterpret_cast<bf16x8*>(&Th[o + 8]) = hv1;
            *reinterpret_cast<bf16x8*>(&Tl[o])     = lv0;
            *reinterpret_cast<bf16x8*>(&Tl[o + 8]) = lv1;
        }
    }
    gridbar(bar, 0);

    // ===================== P1: QKV GEMM =====================
    {
        const int w = tid >> 6, l = tid & 63;
        const int lm = l & 15, lk8 = (l >> 4) * 8, cr = (l >> 4) * 4;
        int prev_slice = -1;
        for (int uu = 0; uu < 3; ++uu) {
            const int u = blk * 3 + uu;          // 0..767
            const int slice = u >> 6;            // 0..11 (proj*4 + nt)
            const int bx = u & 63;
            const int proj = slice >> 2, nt = slice & 3, n0 = nt * 64;
            if (slice != prev_slice) {
                __syncthreads();
                stage_wT_copy(wT + (size_t)proj * 131072, n0, tid, WTh, WTl);
                __syncthreads();
                prev_slice = slice;
            }
            const unsigned short* Ahp = ah + (size_t)proj * 1048576;
            const unsigned short* Alp = al + (size_t)proj * 1048576;
            const float* bias = proj == 0 ? bQ : (proj == 1 ? bK : bV);
            float* outp       = proj == 0 ? q  : (proj == 1 ? k  : v);
            const int R = bx * 64 + w * 16;

            f32x4 acc[4];
            #pragma unroll
            for (int nf = 0; nf < 4; ++nf) acc[nf] = (f32x4){0.f, 0.f, 0.f, 0.f};

            bf16x8 fh[2], fl[2];
            {
                const size_t o0 = (size_t)(R + lm) * C_ + lk8;
                fh[0] = *reinterpret_cast<const bf16x8*>(&Ahp[o0]);
                fl[0] = *reinterpret_cast<const bf16x8*>(&Alp[o0]);
                fh[1] = *reinterpret_cast<const bf16x8*>(&Ahp[o0 + 32]);
                fl[1] = *reinterpret_cast<const bf16x8*>(&Alp[o0 + 32]);
            }
            #pragma unroll
            for (int ks = 0; ks < 8; ++ks) {
                const int cur = ks & 1;
                const bf16x8 a_h = fh[cur], a_l = fl[cur];
                if (ks < 6) {
                    const size_t o = (size_t)(R + lm) * C_ + (ks + 2) * 32 + lk8;
                    fh[cur] = *reinterpret_cast<const bf16x8*>(&Ahp[o]);
                    fl[cur] = *reinterpret_cast<const bf16x8*>(&Alp[o]);
                }
                #pragma unroll
                for (int nf = 0; nf < 4; ++nf) {
                    const int o = WT_IDX(nf * 16 + lm, ks * 32 + lk8);
                    const bf16x8 b_h = *reinterpret_cast<const bf16x8*>(&WTh[o]);
                    const bf16x8 b_l = *reinterpret_cast<const bf16x8*>(&WTl[o]);
                    acc[nf] = __builtin_amdgcn_mfma_f32_16x16x32_bf16(a_h, b_h, acc[nf], 0, 0, 0);
                    acc[nf] = __builtin_amdgcn_mfma_f32_16x16x32_bf16(a_h, b_l, acc[nf], 0, 0, 0);
                    acc[nf] = __builtin_amdgcn_mfma_f32_16x16x32_bf16(a_l, b_h, acc[nf], 0, 0, 0);
                }
            }
            // epilogue: bias + scatter to (B,H,L,DK)
            #pragma unroll
            for (int nf = 0; nf < 4; ++nf) {
                const int col = n0 + nf * 16 + lm;
                const int hh = col >> 5, d = col & 31;
                const float bb = bias[col];
                #pragma unroll
                for (int rr = 0; rr < 4; ++rr) {
                    const int m = R + cr + rr;
                    const int b2 = m >> 11, lrow = m & (L_ - 1);
                    outp[((size_t)(b2 * H_ + hh) * L_ + lrow) * DK_ + d] = acc[nf][rr] + bb;
                }
            }
            // V column-sum partials (per 64-row x 64-col unit, deterministic)
            if (proj == 2) {
                float sl[4];
                #pragma unroll
                for (int nf = 0; nf < 4; ++nf) {
                    float s = acc[nf][0] + acc[nf][1] + acc[nf][2] + acc[nf][3];
                    s += __shfl_xor(s, 16);
                    s += __shfl_xor(s, 32);
                    sl[nf] = s;
                }
                __syncthreads();
                if (l < 16) {
                    #pragma unroll
                    for (int nf = 0; nf < 4; ++nf) red[(w * 4 + nf) * 16 + l] = sl[nf];
                }
                __syncthreads();
                if (tid < 64) {
                    const int nf = tid >> 4, lmm = tid & 15;
                    float tot = red[(0 + nf) * 16 + lmm] + red[(4 + nf) * 16 + lmm]
                              + red[(8 + nf) * 16 + lmm] + red[(12 + nf) * 16 + lmm];
                    const int col = n0 + nf * 16 + lmm;
                    tot += 64.f * bias[col];
                    const int hh = col >> 5, d = col & 31;
                    const int bh = (bx >> 5) * H_ + hh;
                    part[((size_t)bh * 32 + d) * 32 + (bx & 31)] = tot;
                }
            }
        }
    }
    gridbar(bar, 1);

    // ===================== P2: attention =====================
    if (blk < 128) {
        // interior rows: one row per thread, cached global reads (no staging)
        float* vs_sh = (float*)LDSS;     // 32 floats
        const int bh = blk >> 3;
        if (tid < 32) {
            const float4* pp = reinterpret_cast<const float4*>(&part[((size_t)bh * 32 + tid) * 32]);
            float s = 0.f;
            #pragma unroll
            for (int c = 0; c < 8; ++c) {
                float4 x = pp[c];
                s += x.x + x.y + x.z + x.w;
            }
            vs_sh[tid] = s;
        }
        __syncthreads();
        const int i = (blk * 256 + tid) & (L_ - 1);
        if (i != 0 && i != L_ - 1) {
            const float* qb = q + (size_t)bh * L_ * DK_;
            const float* kb = k + (size_t)bh * L_ * DK_;
            const float* vb = v + (size_t)bh * L_ * DK_;
            float qr[32];
            {
                const float4* qp = reinterpret_cast<const float4*>(&qb[(size_t)i * DK_]);
                #pragma unroll
                for (int u2 = 0; u2 < 8; ++u2) {
                    float4 x = qp[u2];
                    qr[u2 * 4 + 0] = x.x; qr[u2 * 4 + 1] = x.y;
                    qr[u2 * 4 + 2] = x.z; qr[u2 * 4 + 3] = x.w;
                }
            }
            const int cols[5] = {0, i - 1, i, i + 1, L_ - 1};
            float sv[5];
            #pragma unroll
            for (int jj = 0; jj < 5; ++jj) {
                const float4* kp = reinterpret_cast<const float4*>(&kb[(size_t)cols[jj] * DK_]);
                float p = 0.f;
                #pragma unroll
                for (int u2 = 0; u2 < 8; ++u2) {
                    float4 kv = kp[u2];
                    p += qr[u2 * 4 + 0] * kv.x + qr[u2 * 4 + 1] * kv.y
                       + qr[u2 * 4 + 2] * kv.z + qr[u2 * 4 + 3] * kv.w;
                }
                sv[jj] = p * RSQRT_DK;
            }
            const bool v1 = (i != 1), v3 = (i != L_ - 2);
            float m = fmaxf(0.f, sv[0]);     // zero fillers join the max
            m = fmaxf(m, sv[2]); m = fmaxf(m, sv[4]);
            if (v1) m = fmaxf(m, sv[1]);
            if (v3) m = fmaxf(m, sv[3]);
            float e[5];
            e[0] = __expf(sv[0] - m);
            e[1] = v1 ? __expf(sv[1] - m) : 0.f;
            e[2] = __expf(sv[2] - m);
            e[3] = v3 ? __expf(sv[3] - m) : 0.f;
            e[4] = __expf(sv[4] - m);
            const int ns = 3 + (int)v1 + (int)v3;
            const float e0 = __expf(-m);
            const float Z = e[0] + e[1] + e[2] + e[3] + e[4] + (float)(L_ - ns) * e0;
            const float rZ = 1.f / Z;
            const float f1 = v1 ? 1.f : 0.f, f3 = v3 ? 1.f : 0.f;

            const float4* vp0 = reinterpret_cast<const float4*>(&vb[0]);
            const float4* vp1 = reinterpret_cast<const float4*>(&vb[(size_t)cols[1] * DK_]);
            const float4* vp2 = reinterpret_cast<const float4*>(&vb[(size_t)i * DK_]);
            const float4* vp3 = reinterpret_cast<const float4*>(&vb[(size_t)cols[3] * DK_]);
            const float4* vp4 = reinterpret_cast<const float4*>(&vb[(size_t)(L_ - 1) * DK_]);
            bf16x8 zh8[4], zl8[4];
            #pragma unroll
            for (int u2 = 0; u2 < 8; ++u2) {
                float4 x0 = vp0[u2], x1 = vp1[u2], x2 = vp2[u2], x3 = vp3[u2], x4 = vp4[u2];
                float a0[4] = {x0.x, x0.y, x0.z, x0.w};
                float a1[4] = {x1.x, x1.y, x1.z, x1.w};
                float a2[4] = {x2.x, x2.y, x2.z, x2.w};
                float a3[4] = {x3.x, x3.y, x3.z, x3.w};
                float a4[4] = {x4.x, x4.y, x4.z, x4.w};
                #pragma unroll
                for (int e2 = 0; e2 < 4; ++e2) {
                    const int d = u2 * 4 + e2;
                    const float num = e[0] * a0[e2] + e[1] * a1[e2] + e[2] * a2[e2]
                                    + e[3] * a3[e2] + e[4] * a4[e2];
                    const float vp_ = a0[e2] + f1 * a1[e2] + a2[e2] + f3 * a3[e2] + a4[e2];
                    const float zd = (num + e0 * (vs_sh[d] - vp_)) * rZ;
                    const unsigned short hb = f2bf(zd);
                    zh8[d >> 3][d & 7] = (short)hb;
                    zl8[d >> 3][d & 7] = (short)f2bf(zd - bf2f(hb));
                }
            }
            const int b2 = bh >> 3, hh = bh & 7;
            const size_t o = (size_t)(b2 * L_ + i) * HD_ + hh * DK_;
            #pragma unroll
            for (int u4 = 0; u4 < 4; ++u4) {
                *reinterpret_cast<bf16x8*>(&zh[o + u4 * 8]) = zh8[u4];
                *reinterpret_cast<bf16x8*>(&zl[o + u4 * 8]) = zl8[u4];
            }
        }
    } else if (blk < 160) {
        // global rows: one block per (bh, row), dense softmax, vectorized PV
        float* sc   = (float*)LDSS;          // 2048
        float* qs   = sc + 2048;             // 32
        float* wred = qs + 32;               // 8
        float* pzs  = wred + 8;              // 1024
        const int gr = blk - 128;            // 0..31
        const int bh = gr >> 1;
        const int r = (gr & 1) ? (L_ - 1) : 0;
        const float* qb = q + (size_t)bh * L_ * DK_;
        const float* kb = k + (size_t)bh * L_ * DK_;
        const float* vb = v + (size_t)bh * L_ * DK_;

        if (tid < 32) qs[tid] = qb[(size_t)r * DK_ + tid];
        __syncthreads();

        float lmax = -1e30f;
        #pragma unroll
        for (int rep = 0; rep < 8; ++rep) {
            const int j = tid + rep * 256;
            const float4* kp = reinterpret_cast<const float4*>(&kb[(size_t)j * DK_]);
            float p = 0.f;
            #pragma unroll
            for (int u = 0; u < 8; ++u) {
                float4 kv = kp[u];
                p += qs[u * 4 + 0] * kv.x + qs[u * 4 + 1] * kv.y
                   + qs[u * 4 + 2] * kv.z + qs[u * 4 + 3] * kv.w;
            }
            p *= RSQRT_DK;
            sc[j] = p;
            lmax = fmaxf(lmax, p);
        }
        #pragma unroll
        for (int off = 32; off; off >>= 1) lmax = fmaxf(lmax, __shfl_xor(lmax, off, 64));
        if ((tid & 63) == 0) wred[tid >> 6] = lmax;
        __syncthreads();
        const float m = fmaxf(fmaxf(wred[0], wred[1]), fmaxf(wred[2], wred[3]));

        float lsum = 0.f;
        #pragma unroll
        for (int rep = 0; rep < 8; ++rep) {
            const int j = tid + rep * 256;
            const float ee = __expf(sc[j] - m);
            sc[j] = ee;
            lsum += ee;
        }
        #pragma unroll
        for (int off = 32; off; off >>= 1) lsum += __shfl_xor(lsum, off, 64);
        if ((tid & 63) == 0) wred[4 + (tid >> 6)] = lsum;
        __syncthreads();
        const float Z = wred[4] + wred[5] + wred[6] + wred[7];

        const int jg = tid >> 3, dq = tid & 7;
        f32x4 a4 = (f32x4){0.f, 0.f, 0.f, 0.f};
        const float4* vb4 = reinterpret_cast<const float4*>(vb);
        for (int it = 0; it < 64; ++it) {
            const int j = jg + it * 32;
            const float s = sc[j];
            const float4 vv = vb4[(size_t)j * 8 + dq];
            a4[0] += s * vv.x; a4[1] += s * vv.y; a4[2] += s * vv.z; a4[3] += s * vv.w;
        }
        pzs[jg * 32 + dq * 4 + 0] = a4[0];
        pzs[jg * 32 + dq * 4 + 1] = a4[1];
        pzs[jg * 32 + dq * 4 + 2] = a4[2];
        pzs[jg * 32 + dq * 4 + 3] = a4[3];
        __syncthreads();
        if (tid < 32) {
            float zsum = 0.f;
            #pragma unroll
            for (int g2 = 0; g2 < 32; ++g2) zsum += pzs[g2 * 32 + tid];
            const float zd = zsum / Z;
            const int b2 = bh >> 3, hh = bh & 7;
            const size_t o = (size_t)(b2 * L_ + r) * HD_ + hh * DK_ + tid;
            const unsigned short hb = f2bf(zd);
            zh[o] = hb;
            zl[o] = f2bf(zd - bf2f(hb));
        }
    }
    gridbar(bar, 2);

    // ===================== P3: out GEMM =====================
    {
        const int bx = blk & 63, nt = blk >> 6, n0 = nt * 64;
        stage_wT_copy(wT + (size_t)3 * 131072, n0, tid, WTh, WTl);
        __syncthreads();

        const int w = tid >> 6, l = tid & 63;
        const int lm = l & 15, lk8 = (l >> 4) * 8, cr = (l >> 4) * 4;
        const int R = bx * 64 + w * 16;

        f32x4 acc[4];
        #pragma unroll
        for (int nf = 0; nf < 4; ++nf) acc[nf] = (f32x4){0.f, 0.f, 0.f, 0.f};

        bf16x8 fh[2], fl[2];
        {
            const size_t o0 = (size_t)(R + lm) * HD_ + lk8;
            fh[0] = *reinterpret_cast<const bf16x8*>(&zh[o0]);
            fl[0] = *reinterpret_cast<const bf16x8*>(&zl[o0]);
            fh[1] = *reinterpret_cast<const bf16x8*>(&zh[o0 + 32]);
            fl[1] = *reinterpret_cast<const bf16x8*>(&zl[o0 + 32]);
        }
        #pragma unroll
        for (int ks = 0; ks < 8; ++ks) {
            const int cur = ks & 1;
            const bf16x8 a_h = fh[cur], a_l = fl[cur];
            if (ks < 6) {
                const size_t o = (size_t)(R + lm) * HD_ + (ks + 2) * 32 + lk8;
                fh[cur] = *reinterpret_cast<const bf16x8*>(&zh[o]);
                fl[cur] = *reinterpret_cast<const bf16x8*>(&zl[o]);
            }
            #pragma unroll
            for (int nf = 0; nf < 4; ++nf) {
                const int o = WT_IDX(nf * 16 + lm, ks * 32 + lk8);
                const bf16x8 b_h = *reinterpret_cast<const bf16x8*>(&WTh[o]);
                const bf16x8 b_l = *reinterpret_cast<const bf16x8*>(&WTl[o]);
                acc[nf] = __builtin_amdgcn_mfma_f32_16x16x32_bf16(a_h, b_h, acc[nf], 0, 0, 0);
                acc[nf] = __builtin_amdgcn_mfma_f32_16x16x32_bf16(a_h, b_l, acc[nf], 0, 0, 0);
                acc[nf] = __builtin_amdgcn_mfma_f32_16x16x32_bf16(a_l, b_h, acc[nf], 0, 0, 0);
            }
        }
        #pragma unroll
        for (int nf = 0; nf < 4; ++nf) {
            const int col = n0 + nf * 16 + lm;
            const float bb = bO[col];
            #pragma unroll
            for (int rr = 0; rr < 4; ++rr) {
                const int m = R + cr + rr;
                out[(size_t)m * HD_ + col] = acc[nf][rr] + bb;
            }
        }
    }
}

// ---------------------------------------------------------------------------
extern "C" void kernel_launch(void* const* d_in, const int* in_sizes, int n_in,
                              void* d_out, int out_size, void* d_ws, size_t ws_size,
                              hipStream_t stream)
{
    const float* qx = (const float*)d_in[0];
    const float* kx = (const float*)d_in[1];
    const float* vx = (const float*)d_in[2];
    const float* WQ = (const float*)d_in[3];
    const float* bQ = (const float*)d_in[4];
    const float* WK = (const float*)d_in[5];
    const float* bK = (const float*)d_in[6];
    const float* WV = (const float*)d_in[7];
    const float* bV = (const float*)d_in[8];
    const float* WO = (const float*)d_in[9];
    const float* bO = (const float*)d_in[10];
    float* out = (float*)d_out;

    char* wsb = (char*)d_ws;
    float*          q    = (float*)(wsb);                            // 4 MB
    float*          k    = (float*)(wsb + (4u  << 20));              // 4 MB
    float*          v    = (float*)(wsb + (8u  << 20));              // 4 MB
    unsigned short* zh   = (unsigned short*)(wsb + (12u << 20));     // 2 MB
    unsigned short* zl   = (unsigned short*)(wsb + (14u << 20));     // 2 MB
    unsigned short* wT   = (unsigned short*)(wsb + (16u << 20));     // 1 MB
    float*          part = (float*)(wsb + (17u << 20));              // 64 KB
    unsigned short* ah   = (unsigned short*)(wsb + (18u << 20));     // 6 MB
    unsigned short* al   = (unsigned short*)(wsb + (24u << 20));     // 6 MB
    unsigned*       bar  = (unsigned*)(wsb + (30u << 20));           // 64 B

    hipMemsetAsync(bar, 0, 64, stream);
    bigbird_mega<<<NBLK, 256, 0, stream>>>(qx, kx, vx, WQ, bQ, WK, bK, WV, bV, WO, bO,
                                           q, k, v, zh, zl, wT, part, ah, al, bar, out);
}

// Round 10
// 143.196 us; speedup vs baseline: 1.2792x; 1.2792x over previous
//
#include <hip/hip_runtime.h>
#include <hip/hip_bf16.h>

#define B_   2
#define L_   2048
#define C_   256
#define H_   8
#define DK_  32
#define HD_  256
#define RSQRT_DK 0.17677669529663687f  // 1/sqrt(32)

// Measurement round: each kernel repeats its (idempotent) body REP_* times so
// every dispatch exceeds the ~45us harness fill dispatches and surfaces in
// rocprof top-5 with full counters.  True per-kernel time = dur_us / REP.
#define REP_PREP 16
#define REP_K1   8
#define REP_ATTN 4
#define REP_G2   32
#define REP_K3   16
#define REP_FENCE() asm volatile("" ::: "memory")

typedef __attribute__((ext_vector_type(8))) short bf16x8;
typedef __attribute__((ext_vector_type(4))) float f32x4;

__device__ __forceinline__ unsigned short f2bf(float x) {
    unsigned int u = __float_as_uint(x);
    u += 0x7fffu + ((u >> 16) & 1u);
    return (unsigned short)(u >> 16);
}
__device__ __forceinline__ float bf2f(unsigned short h) {
    return __uint_as_float((unsigned int)h << 16);
}

// LDS weight-slice layout (per 64x256 plane of shorts): row pitch 256 shorts
// (uniform bank base), 16B-chunk XOR swizzle -> b128 reads/writes at bank floor.
#define WT_IDX(n, k) (((n) << 8) + (((((k) >> 3) ^ ((n) & 7))) << 3) + ((k) & 7))

__device__ __forceinline__ void stage_wT_copy(
    const unsigned short* __restrict__ wTp, int n0, int tid,
    short* __restrict__ WTh, short* __restrict__ WTl)
{
    #pragma unroll
    for (int it = 0; it < 8; ++it) {
        const int c = tid + it * 256;      // chunk 0..2047
        const int n = c >> 5, k8 = c & 31;
        const size_t go = (size_t)(n0 + n) * 256 + k8 * 8;
        const int o = (n << 8) + ((k8 ^ (n & 7)) << 3);
        *reinterpret_cast<bf16x8*>(&WTh[o]) = *reinterpret_cast<const bf16x8*>(&wTp[go]);
        *reinterpret_cast<bf16x8*>(&WTl[o]) = *reinterpret_cast<const bf16x8*>(&wTp[65536 + go]);
    }
}

// ---------------------------------------------------------------------------
// P0: one-time conversion (x REP_PREP).
// ---------------------------------------------------------------------------
__global__ __launch_bounds__(256) void prep_kernel(
    const float* __restrict__ qx, const float* __restrict__ kx, const float* __restrict__ vx,
    const float* __restrict__ WQ, const float* __restrict__ WK,
    const float* __restrict__ WV, const float* __restrict__ WO,
    unsigned short* __restrict__ wT,
    unsigned short* __restrict__ ah, unsigned short* __restrict__ al)
{
    __shared__ float ts[64][65];
    const int blk = blockIdx.x;
    const int t = threadIdx.x;

    #pragma unroll 1
    for (int rep = 0; rep < REP_PREP; ++rep) {
        if (blk < 64) {
            const int p = blk >> 4, tile = blk & 15;
            const int k0 = (tile >> 2) * 64, n0 = (tile & 3) * 64;
            const float* W = p == 0 ? WQ : (p == 1 ? WK : (p == 2 ? WV : WO));
            unsigned short* Th = wT + (size_t)p * 131072;
            unsigned short* Tl = Th + 65536;

            const int r = t >> 2, cq = (t & 3) * 16;
            #pragma unroll
            for (int u = 0; u < 4; ++u) {
                float4 w4 = *reinterpret_cast<const float4*>(&W[(size_t)(k0 + r) * 256 + n0 + cq + u * 4]);
                ts[r][cq + u * 4 + 0] = w4.x;
                ts[r][cq + u * 4 + 1] = w4.y;
                ts[r][cq + u * 4 + 2] = w4.z;
                ts[r][cq + u * 4 + 3] = w4.w;
            }
            __syncthreads();
            bf16x8 hv0, hv1, lv0, lv1;
            #pragma unroll
            for (int e = 0; e < 8; ++e) {
                float x0 = ts[cq + e][r];
                float x1 = ts[cq + 8 + e][r];
                unsigned short h0 = f2bf(x0), h1 = f2bf(x1);
                hv0[e] = (short)h0;  lv0[e] = (short)f2bf(x0 - bf2f(h0));
                hv1[e] = (short)h1;  lv1[e] = (short)f2bf(x1 - bf2f(h1));
            }
            const size_t o = (size_t)(n0 + r) * 256 + k0 + cq;
            *reinterpret_cast<bf16x8*>(&Th[o])     = hv0;
            *reinterpret_cast<bf16x8*>(&Th[o + 8]) = hv1;
            *reinterpret_cast<bf16x8*>(&Tl[o])     = lv0;
            *reinterpret_cast<bf16x8*>(&Tl[o + 8]) = lv1;
        } else {
            const int blk2 = blk - 64;                 // 0..1535
            const int proj = blk2 >> 9;                // 512 blocks per proj
            const int ci = (blk2 & 511) * 256 + t;     // 8-float chunk id
            const float* src = proj == 0 ? qx : (proj == 1 ? kx : vx);
            const float* p = src + (size_t)ci * 8;
            float4 x0 = *reinterpret_cast<const float4*>(p);
            float4 x1 = *reinterpret_cast<const float4*>(p + 4);
            float xs[8] = {x0.x, x0.y, x0.z, x0.w, x1.x, x1.y, x1.z, x1.w};
            bf16x8 hv, lv;
            #pragma unroll
            for (int e = 0; e < 8; ++e) {
                const unsigned short h = f2bf(xs[e]);
                hv[e] = (short)h;
                lv[e] = (short)f2bf(xs[e] - bf2f(h));
            }
            const size_t o = (size_t)proj * 1048576 + (size_t)ci * 8;
            *reinterpret_cast<bf16x8*>(&ah[o]) = hv;
            *reinterpret_cast<bf16x8*>(&al[o]) = lv;
        }
        __syncthreads();
        REP_FENCE();
    }
}

// ---------------------------------------------------------------------------
// K1: QKV projection GEMM (x REP_K1).
// ---------------------------------------------------------------------------
__global__ __launch_bounds__(256) void gemm_qkv_fused(
    const unsigned short* __restrict__ ah, const unsigned short* __restrict__ al,
    const unsigned short* __restrict__ wT,
    const float* __restrict__ bQ, const float* __restrict__ bK, const float* __restrict__ bV,
    float* __restrict__ q, float* __restrict__ k, float* __restrict__ v,
    float* __restrict__ part)
{
    const int bx = blockIdx.x;          // 0..31
    const int yy = blockIdx.y;          // 0..11
    const int proj = yy >> 2, nt = yy & 3;
    const float* bias = proj == 0 ? bQ : (proj == 1 ? bK : bV);
    float* out        = proj == 0 ? q  : (proj == 1 ? k  : v);
    const unsigned short* Ah = ah + (size_t)proj * 1048576;
    const unsigned short* Al = al + (size_t)proj * 1048576;
    const int n0 = nt * 64;

    __shared__ short WTh[64 * 256];
    __shared__ short WTl[64 * 256];
    __shared__ float red[4][4][16];

    const int tid = threadIdx.x;
    const int w  = tid >> 6;            // wave 0..3
    const int l  = tid & 63;
    const int lm = l & 15, lk8 = (l >> 4) * 8, cr = (l >> 4) * 4;
    const int R  = bx * 128 + w * 32;

    #pragma unroll 1
    for (int rep = 0; rep < REP_K1; ++rep) {
        stage_wT_copy(wT + (size_t)proj * 131072, n0, tid, WTh, WTl);
        __syncthreads();

        f32x4 acc[2][4];
        #pragma unroll
        for (int mf = 0; mf < 2; ++mf)
            #pragma unroll
            for (int nf = 0; nf < 4; ++nf)
                acc[mf][nf] = (f32x4){0.f, 0.f, 0.f, 0.f};

        bf16x8 Ahf[2][2], Alf[2][2];
        #define LOAD_A(buf, ks)                                                          \
        {                                                                                \
            const size_t o0 = (size_t)(R + lm) * C_ + (ks) * 32 + lk8;                   \
            const size_t o1 = (size_t)(R + 16 + lm) * C_ + (ks) * 32 + lk8;              \
            Ahf[buf][0] = *reinterpret_cast<const bf16x8*>(&Ah[o0]);                     \
            Ahf[buf][1] = *reinterpret_cast<const bf16x8*>(&Ah[o1]);                     \
            Alf[buf][0] = *reinterpret_cast<const bf16x8*>(&Al[o0]);                     \
            Alf[buf][1] = *reinterpret_cast<const bf16x8*>(&Al[o1]);                     \
        }
        LOAD_A(0, 0)
        LOAD_A(1, 1)

        #pragma unroll
        for (int ks = 0; ks < 8; ++ks) {
            const int cur = ks & 1;
            bf16x8 a_h[2] = {Ahf[cur][0], Ahf[cur][1]};
            bf16x8 a_l[2] = {Alf[cur][0], Alf[cur][1]};
            if (ks < 6) LOAD_A(cur, ks + 2)
            bf16x8 Bh[4], Bl[4];
            #pragma unroll
            for (int nf = 0; nf < 4; ++nf) {
                const int o = WT_IDX(nf * 16 + lm, ks * 32 + lk8);
                Bh[nf] = *reinterpret_cast<const bf16x8*>(&WTh[o]);
                Bl[nf] = *reinterpret_cast<const bf16x8*>(&WTl[o]);
            }
            #pragma unroll
            for (int mf = 0; mf < 2; ++mf)
                #pragma unroll
                for (int nf = 0; nf < 4; ++nf) {
                    acc[mf][nf] = __builtin_amdgcn_mfma_f32_16x16x32_bf16(a_h[mf], Bh[nf], acc[mf][nf], 0, 0, 0);
                    acc[mf][nf] = __builtin_amdgcn_mfma_f32_16x16x32_bf16(a_h[mf], Bl[nf], acc[mf][nf], 0, 0, 0);
                    acc[mf][nf] = __builtin_amdgcn_mfma_f32_16x16x32_bf16(a_l[mf], Bh[nf], acc[mf][nf], 0, 0, 0);
                }
        }
        #undef LOAD_A

        // epilogue: bias + scatter to (B,H,L,DK)
        #pragma unroll
        for (int mf = 0; mf < 2; ++mf)
            #pragma unroll
            for (int nf = 0; nf < 4; ++nf) {
                const int col = n0 + nf * 16 + lm;
                const int h = col >> 5, d = col & 31;
                const float bb = bias[col];
                #pragma unroll
                for (int r = 0; r < 4; ++r) {
                    const int m = R + mf * 16 + cr + r;
                    const int b = m >> 11, lrow = m & (L_ - 1);
                    out[((size_t)(b * H_ + h) * L_ + lrow) * DK_ + d] = acc[mf][nf][r] + bb;
                }
            }

        // V column-sum partials (deterministic, per block = 128 rows x 64 cols)
        if (proj == 2) {
            float sl[4];
            #pragma unroll
            for (int nf = 0; nf < 4; ++nf) {
                float s = 0.f;
                #pragma unroll
                for (int mf = 0; mf < 2; ++mf)
                    #pragma unroll
                    for (int r = 0; r < 4; ++r) s += acc[mf][nf][r];
                s += __shfl_xor(s, 16);
                s += __shfl_xor(s, 32);
                sl[nf] = s;
            }
            if (l < 16) {
                #pragma unroll
                for (int nf = 0; nf < 4; ++nf) red[w][nf][l] = sl[nf];
            }
            __syncthreads();
            if (tid < 64) {
                const int nf = tid >> 4, lmm = tid & 15;
                float tot = red[0][nf][lmm] + red[1][nf][lmm] + red[2][nf][lmm] + red[3][nf][lmm];
                const int col = n0 + nf * 16 + lmm;
                tot += 128.f * bias[col];
                const int h = col >> 5, d = col & 31;
                const int bh = (bx >> 4) * H_ + h;       // block spans one b
                part[((size_t)bh * 32 + d) * 16 + (bx & 15)] = tot;
            }
        }
        __syncthreads();
        REP_FENCE();
    }
}

// ---------------------------------------------------------------------------
// K2: attention (x REP_ATTN).
// ---------------------------------------------------------------------------
#define NSLOT 200            // 68 K + 68 V + 64 Q
#define VOFF  68
#define QOFF  136

__global__ __launch_bounds__(128) void attn_main(
    const float* __restrict__ q, const float* __restrict__ k,
    const float* __restrict__ v, const float* __restrict__ part,
    float* __restrict__ pm, float* __restrict__ pZ, float* __restrict__ pzv,
    unsigned short* __restrict__ zh, unsigned short* __restrict__ zl)
{
    __shared__ float Sf[NSLOT * 32 + 32];
    float* vs_sh = &Sf[NSLOT * 32];

    #define LDS_F4(slot, u2) (*reinterpret_cast<const float4*>(&Sf[((slot) << 5) + (((u2) ^ ((slot) & 7)) << 2)]))

    const int blk = blockIdx.x;
    const int t = threadIdx.x;

    #pragma unroll 1
    for (int rep = 0; rep < REP_ATTN; ++rep) {
        if (blk < 512) {
            // interior rows, per-lane, 64-row chunks
            const int bh = blk >> 5, c = blk & 31;
            const int base = c * 64;
            const float* qb = q + (size_t)bh * L_ * DK_;
            const float* kb = k + (size_t)bh * L_ * DK_;
            const float* vb = v + (size_t)bh * L_ * DK_;

            for (int u = t; u < NSLOT * 8; u += 128) {
                const int slot = u >> 3, quad = u & 7;
                int row; const float* src;
                if (slot < VOFF) {
                    const int s = slot;
                    row = (s < 66) ? min(base + s, L_ - 1) : ((s == 66) ? 0 : L_ - 1);
                    src = kb;
                } else if (slot < QOFF) {
                    const int s = slot - VOFF;
                    row = (s < 66) ? min(base + s, L_ - 1) : ((s == 66) ? 0 : L_ - 1);
                    src = vb;
                } else {
                    row = min(base + 1 + (slot - QOFF), L_ - 1);
                    src = qb;
                }
                float4 w4 = *reinterpret_cast<const float4*>(&src[(size_t)row * DK_ + quad * 4]);
                float* dst = &Sf[(slot << 5) + ((quad ^ (slot & 7)) << 2)];
                dst[0] = w4.x; dst[1] = w4.y; dst[2] = w4.z; dst[3] = w4.w;
            }
            if (t < 32) {
                const float4* pp = reinterpret_cast<const float4*>(&part[((size_t)bh * 32 + t) * 16]);
                float4 pa = pp[0], pb = pp[1], pc = pp[2], pd = pp[3];
                vs_sh[t] = pa.x + pa.y + pa.z + pa.w + pb.x + pb.y + pb.z + pb.w
                         + pc.x + pc.y + pc.z + pc.w + pd.x + pd.y + pd.z + pd.w;
            }
            __syncthreads();

            const int i = base + 1 + t;
            if (t < 64 && i <= L_ - 2) {
                float qr[32];
                {
                    const int qs = QOFF + t;
                    #pragma unroll
                    for (int u2 = 0; u2 < 8; ++u2) {
                        float4 x = LDS_F4(qs, u2);
                        qr[u2 * 4 + 0] = x.x; qr[u2 * 4 + 1] = x.y;
                        qr[u2 * 4 + 2] = x.z; qr[u2 * 4 + 3] = x.w;
                    }
                }
                const int ks_[5] = {66, t, t + 1, t + 2, 67};
                float sv[5];
                #pragma unroll
                for (int jj = 0; jj < 5; ++jj) {
                    const int s = ks_[jj];
                    float p = 0.f;
                    #pragma unroll
                    for (int u2 = 0; u2 < 8; ++u2) {
                        float4 kv = LDS_F4(s, u2);
                        p += qr[u2 * 4 + 0] * kv.x + qr[u2 * 4 + 1] * kv.y
                           + qr[u2 * 4 + 2] * kv.z + qr[u2 * 4 + 3] * kv.w;
                    }
                    sv[jj] = p * RSQRT_DK;
                }
                const bool v1 = (i != 1), v3 = (i != L_ - 2);
                float m = fmaxf(0.f, sv[0]);
                m = fmaxf(m, sv[2]); m = fmaxf(m, sv[4]);
                if (v1) m = fmaxf(m, sv[1]);
                if (v3) m = fmaxf(m, sv[3]);
                float e[5];
                e[0] = __expf(sv[0] - m);
                e[1] = v1 ? __expf(sv[1] - m) : 0.f;
                e[2] = __expf(sv[2] - m);
                e[3] = v3 ? __expf(sv[3] - m) : 0.f;
                e[4] = __expf(sv[4] - m);
                const int ns = 3 + (int)v1 + (int)v3;
                const float e0 = __expf(-m);
                const float Z = e[0] + e[1] + e[2] + e[3] + e[4] + (float)(L_ - ns) * e0;
                const float rZ = 1.f / Z;
                const float f1 = v1 ? 1.f : 0.f, f3 = v3 ? 1.f : 0.f;

                bf16x8 zh8[4], zl8[4];
                #pragma unroll
                for (int u2 = 0; u2 < 8; ++u2) {
                    float4 x0 = LDS_F4(VOFF + 66,    u2);
                    float4 x1 = LDS_F4(VOFF + t,     u2);
                    float4 x2 = LDS_F4(VOFF + t + 1, u2);
                    float4 x3 = LDS_F4(VOFF + t + 2, u2);
                    float4 x4 = LDS_F4(VOFF + 67,    u2);
                    float a0[4] = {x0.x, x0.y, x0.z, x0.w};
                    float a1[4] = {x1.x, x1.y, x1.z, x1.w};
                    float a2[4] = {x2.x, x2.y, x2.z, x2.w};
                    float a3[4] = {x3.x, x3.y, x3.z, x3.w};
                    float a4[4] = {x4.x, x4.y, x4.z, x4.w};
                    #pragma unroll
                    for (int e2 = 0; e2 < 4; ++e2) {
                        const int d = u2 * 4 + e2;
                        const float num = e[0] * a0[e2] + e[1] * a1[e2] + e[2] * a2[e2]
                                        + e[3] * a3[e2] + e[4] * a4[e2];
                        const float vp = a0[e2] + f1 * a1[e2] + a2[e2] + f3 * a3[e2] + a4[e2];
                        const float zd = (num + e0 * (vs_sh[d] - vp)) * rZ;
                        const unsigned short hb = f2bf(zd);
                        zh8[d >> 3][d & 7] = (short)hb;
                        zl8[d >> 3][d & 7] = (short)f2bf(zd - bf2f(hb));
                    }
                }
                const int b = bh >> 3, h = bh & 7;
                const size_t o = (size_t)(b * L_ + i) * HD_ + h * DK_;
                #pragma unroll
                for (int u4 = 0; u4 < 4; ++u4) {
                    *reinterpret_cast<bf16x8*>(&zh[o + u4 * 8]) = zh8[u4];
                    *reinterpret_cast<bf16x8*>(&zl[o + u4 * 8]) = zl8[u4];
                }
            }
        } else {
            // global-row partials
            const int blk2 = blk - 512;                 // 0..511
            const int bh = blk2 >> 5;
            const int pair = (blk2 >> 4) & 1;
            const int chunk = blk2 & 15;
            const int r = pair ? (L_ - 1) : 0;
            const int j0 = chunk * 128;
            const float* qb = q + (size_t)bh * L_ * DK_;
            const float* kb = k + (size_t)bh * L_ * DK_;
            const float* vb = v + (size_t)bh * L_ * DK_;

            float* qs  = Sf;          // 32
            float* sc  = Sf + 32;     // 128
            float* red = Sf + 160;    // 4
            float* pzs = Sf + 192;    // 128

            if (t < 32) qs[t] = qb[(size_t)r * DK_ + t];
            __syncthreads();

            const int j = j0 + t;
            const float4* kr = reinterpret_cast<const float4*>(&kb[(size_t)j * DK_]);
            float p = 0.f;
            #pragma unroll
            for (int u = 0; u < 8; ++u) {
                float4 kv = kr[u];
                p += qs[u * 4 + 0] * kv.x + qs[u * 4 + 1] * kv.y
                   + qs[u * 4 + 2] * kv.z + qs[u * 4 + 3] * kv.w;
            }
            p *= RSQRT_DK;

            float lm = p;
            #pragma unroll
            for (int off = 32; off; off >>= 1) lm = fmaxf(lm, __shfl_xor(lm, off, 64));
            if ((t & 63) == 0) red[t >> 6] = lm;
            __syncthreads();
            const float m = fmaxf(red[0], red[1]);

            const float e = __expf(p - m);
            sc[t] = e;
            float ls = e;
            #pragma unroll
            for (int off = 32; off; off >>= 1) ls += __shfl_xor(ls, off, 64);
            if ((t & 63) == 0) red[2 + (t >> 6)] = ls;
            __syncthreads();
            const float Zc = red[2] + red[3];

            const int d = t & 31, g = t >> 5;
            float acc = 0.f;
            #pragma unroll 4
            for (int jj = 0; jj < 32; ++jj)
                acc += sc[g * 32 + jj] * vb[(size_t)(j0 + g * 32 + jj) * DK_ + d];
            pzs[g * 32 + d] = acc;
            __syncthreads();
            if (g == 0) {
                const float s2 = pzs[d] + pzs[32 + d] + pzs[64 + d] + pzs[96 + d];
                pzv[(size_t)blk2 * 32 + d] = s2;
            }
            if (t == 0) { pm[blk2] = m; pZ[blk2] = Zc; }
        }
        __syncthreads();
        REP_FENCE();
    }
    #undef LDS_F4
}

// ---------------------------------------------------------------------------
// K2b: combine (x REP_G2).
// ---------------------------------------------------------------------------
__global__ __launch_bounds__(1024) void attn_g2_kernel(
    const float* __restrict__ pm, const float* __restrict__ pZ,
    const float* __restrict__ pzv,
    unsigned short* __restrict__ zh, unsigned short* __restrict__ zl)
{
    const int t = threadIdx.x;           // 0..1023
    const int rowIdx = t >> 5;           // 0..31 (= bh*2 + pair)
    const int d = t & 31;
    const int bh = rowIdx >> 1, pair = rowIdx & 1;
    const int base = rowIdx * 16;

    #pragma unroll 1
    for (int rep = 0; rep < REP_G2; ++rep) {
        float m = -1e30f;
        #pragma unroll
        for (int c = 0; c < 16; ++c) m = fmaxf(m, pm[base + c]);
        float Z = 0.f, zd = 0.f;
        #pragma unroll
        for (int c = 0; c < 16; ++c) {
            const float w = __expf(pm[base + c] - m);
            Z  += pZ[base + c] * w;
            zd += pzv[(size_t)(base + c) * 32 + d] * w;
        }
        zd /= Z;

        const int r = pair ? (L_ - 1) : 0;
        const int b = bh >> 3, h = bh & 7;
        const size_t o = (size_t)(b * L_ + r) * HD_ + h * DK_ + d;
        const unsigned short hb = f2bf(zd);
        zh[o] = hb;
        zl[o] = f2bf(zd - bf2f(hb));
        REP_FENCE();
    }
}

// ---------------------------------------------------------------------------
// K3: out GEMM (x REP_K3).
// ---------------------------------------------------------------------------
__global__ __launch_bounds__(256) void gemm_out_fused(
    const unsigned short* __restrict__ zh, const unsigned short* __restrict__ zl,
    const unsigned short* __restrict__ wT, const float* __restrict__ bO,
    float* __restrict__ out)
{
    const int bx = blockIdx.x;          // 0..63
    const int nt = blockIdx.y;          // 0..3
    const int n0 = nt * 64;

    __shared__ short WTh[64 * 256];
    __shared__ short WTl[64 * 256];

    const int tid = threadIdx.x;
    const int w  = tid >> 6;
    const int l  = tid & 63;
    const int lm = l & 15, lk8 = (l >> 4) * 8, cr = (l >> 4) * 4;
    const int R  = bx * 64 + w * 16;

    #pragma unroll 1
    for (int rep = 0; rep < REP_K3; ++rep) {
        stage_wT_copy(wT + (size_t)3 * 131072, n0, tid, WTh, WTl);
        __syncthreads();

        f32x4 acc[4];
        #pragma unroll
        for (int nf = 0; nf < 4; ++nf) acc[nf] = (f32x4){0.f, 0.f, 0.f, 0.f};

        bf16x8 Ah[2], Al[2];
        #define LOAD_Z(buf, ks)                                                          \
        {                                                                                \
            const size_t o = (size_t)(R + lm) * HD_ + (ks) * 32 + lk8;                   \
            Ah[buf] = *reinterpret_cast<const bf16x8*>(&zh[o]);                          \
            Al[buf] = *reinterpret_cast<const bf16x8*>(&zl[o]);                          \
        }
        LOAD_Z(0, 0)
        LOAD_Z(1, 1)

        #pragma unroll
        for (int ks = 0; ks < 8; ++ks) {
            const int cur = ks & 1;
            const bf16x8 a_h = Ah[cur], a_l = Al[cur];
            if (ks < 6) LOAD_Z(cur, ks + 2)
            #pragma unroll
            for (int nf = 0; nf < 4; ++nf) {
                const int o = WT_IDX(nf * 16 + lm, ks * 32 + lk8);
                const bf16x8 b_h = *reinterpret_cast<const bf16x8*>(&WTh[o]);
                const bf16x8 b_l = *reinterpret_cast<const bf16x8*>(&WTl[o]);
                acc[nf] = __builtin_amdgcn_mfma_f32_16x16x32_bf16(a_h, b_h, acc[nf], 0, 0, 0);
                acc[nf] = __builtin_amdgcn_mfma_f32_16x16x32_bf16(a_h, b_l, acc[nf], 0, 0, 0);
                acc[nf] = __builtin_amdgcn_mfma_f32_16x16x32_bf16(a_l, b_h, acc[nf], 0, 0, 0);
            }
        }
        #undef LOAD_Z

        #pragma unroll
        for (int nf = 0; nf < 4; ++nf) {
            const int col = n0 + nf * 16 + lm;
            const float bb = bO[col];
            #pragma unroll
            for (int r = 0; r < 4; ++r) {
                const int m = R + cr + r;
                out[(size_t)m * HD_ + col] = acc[nf][r] + bb;
            }
        }
        __syncthreads();
        REP_FENCE();
    }
}

// ---------------------------------------------------------------------------
extern "C" void kernel_launch(void* const* d_in, const int* in_sizes, int n_in,
                              void* d_out, int out_size, void* d_ws, size_t ws_size,
                              hipStream_t stream)
{
    const float* qx = (const float*)d_in[0];
    const float* kx = (const float*)d_in[1];
    const float* vx = (const float*)d_in[2];
    const float* WQ = (const float*)d_in[3];
    const float* bQ = (const float*)d_in[4];
    const float* WK = (const float*)d_in[5];
    const float* bK = (const float*)d_in[6];
    const float* WV = (const float*)d_in[7];
    const float* bV = (const float*)d_in[8];
    const float* WO = (const float*)d_in[9];
    const float* bO = (const float*)d_in[10];
    float* out = (float*)d_out;

    char* wsb = (char*)d_ws;
    float*          q    = (float*)(wsb);                            // 4 MB
    float*          k    = (float*)(wsb + (4u  << 20));              // 4 MB
    float*          v    = (float*)(wsb + (8u  << 20));              // 4 MB
    unsigned short* zh   = (unsigned short*)(wsb + (12u << 20));     // 2 MB
    unsigned short* zl   = (unsigned short*)(wsb + (14u << 20));     // 2 MB
    unsigned short* wT   = (unsigned short*)(wsb + (16u << 20));     // 1 MB
    float*          part = (float*)(wsb + (17u << 20));              // 32 KB
    float*          pm   = (float*)(wsb + (17u << 20) + (1u << 16)); // 512 f
    float*          pZ   = pm + 512;
    float*          pzv  = pm + 1024;                                // 16384 f
    unsigned short* ah   = (unsigned short*)(wsb + (18u << 20));     // 6 MB
    unsigned short* al   = (unsigned short*)(wsb + (24u << 20));     // 6 MB

    prep_kernel<<<1600, 256, 0, stream>>>(qx, kx, vx, WQ, WK, WV, WO, wT, ah, al);
    gemm_qkv_fused<<<dim3(32, 12), 256, 0, stream>>>(ah, al, wT, bQ, bK, bV, q, k, v, part);
    attn_main<<<1024, 128, 0, stream>>>(q, k, v, part, pm, pZ, pzv, zh, zl);
    attn_g2_kernel<<<1, 1024, 0, stream>>>(pm, pZ, pzv, zh, zl);
    gemm_out_fused<<<dim3(64, 4), 256, 0, stream>>>(zh, zl, wT, bO, out);
}

// Round 11
// 55.823 us; speedup vs baseline: 3.2814x; 2.5652x over previous
//
#include <hip/hip_runtime.h>
#include <hip/hip_bf16.h>

#define B_   2
#define L_   2048
#define C_   256
#define H_   8
#define DK_  32
#define HD_  256
#define RSQRT_DK 0.17677669529663687f  // 1/sqrt(32)

typedef __attribute__((ext_vector_type(8))) short bf16x8;
typedef __attribute__((ext_vector_type(4))) float f32x4;

__device__ __forceinline__ unsigned short f2bf(float x) {
    unsigned int u = __float_as_uint(x);
    u += 0x7fffu + ((u >> 16) & 1u);
    return (unsigned short)(u >> 16);
}
__device__ __forceinline__ float bf2f(unsigned short h) {
    return __uint_as_float((unsigned int)h << 16);
}

// LDS weight-slice layout (per 64x256 plane of shorts): row pitch 256 shorts
// (uniform bank base), 16B-chunk XOR swizzle -> b128 reads/writes at bank floor.
#define WT_IDX(n, k) (((n) << 8) + (((((k) >> 3) ^ ((n) & 7))) << 3) + ((k) & 7))

// Stage W cols [n0, n0+63], k 0..255 from fp32 into LDS planes as split-bf16
// [n][k].  256 threads: wave w handles k-rows [w*64..]; lane n = tid&63.
// Global loads: 64 consecutive lanes read 64 consecutive floats (coalesced).
__device__ __forceinline__ void stage_wT(
    const float* __restrict__ W, int n0, int tid,
    short* __restrict__ WTh, short* __restrict__ WTl)
{
    const int n  = tid & 63;
    const int kc = tid >> 6;           // 0..3
    #pragma unroll
    for (int c8 = 0; c8 < 8; ++c8) {
        const int k0 = kc * 64 + c8 * 8;
        bf16x8 hv, lv;
        #pragma unroll
        for (int e = 0; e < 8; ++e) {
            const float x = W[(size_t)(k0 + e) * HD_ + n0 + n];
            const unsigned short h = f2bf(x);
            hv[e] = (short)h;
            lv[e] = (short)f2bf(x - bf2f(h));
        }
        const int o = (n << 8) + ((((k0 >> 3) ^ (n & 7))) << 3);
        *reinterpret_cast<bf16x8*>(&WTh[o]) = hv;
        *reinterpret_cast<bf16x8*>(&WTl[o]) = lv;
    }
}

// ---------------------------------------------------------------------------
// K1: QKV projection, split-bf16 MFMA, self-contained (W transpose+convert
// fused in LDS; A converted in-loop from fp32).  Grid (32, 12 = proj*4+nt),
// 256 thr = 4 waves; block tile 128x64, wave tile 32x64.  Also emits
// deterministic per-block V column-sum partials.
// ---------------------------------------------------------------------------
__global__ __launch_bounds__(256) void gemm_qkv_fused(
    const float* __restrict__ qx, const float* __restrict__ kx, const float* __restrict__ vx,
    const float* __restrict__ WQ, const float* __restrict__ bQ,
    const float* __restrict__ WK, const float* __restrict__ bK,
    const float* __restrict__ WV, const float* __restrict__ bV,
    float* __restrict__ q, float* __restrict__ k, float* __restrict__ v,
    float* __restrict__ part)
{
    const int bx = blockIdx.x;          // 0..31
    const int yy = blockIdx.y;          // 0..11
    const int proj = yy >> 2, nt = yy & 3;
    const float* A    = proj == 0 ? qx : (proj == 1 ? kx : vx);
    const float* W    = proj == 0 ? WQ : (proj == 1 ? WK : WV);
    const float* bias = proj == 0 ? bQ : (proj == 1 ? bK : bV);
    float* out        = proj == 0 ? q  : (proj == 1 ? k  : v);
    const int n0 = nt * 64;

    __shared__ short WTh[64 * 256];
    __shared__ short WTl[64 * 256];
    __shared__ float red[4][4][16];

    const int tid = threadIdx.x;
    stage_wT(W, n0, tid, WTh, WTl);
    __syncthreads();

    const int w  = tid >> 6;            // wave 0..3
    const int l  = tid & 63;
    const int lm = l & 15, lk8 = (l >> 4) * 8, cr = (l >> 4) * 4;
    const int R  = bx * 128 + w * 32;

    f32x4 acc[2][4];
    #pragma unroll
    for (int mf = 0; mf < 2; ++mf)
        #pragma unroll
        for (int nf = 0; nf < 4; ++nf)
            acc[mf][nf] = (f32x4){0.f, 0.f, 0.f, 0.f};

    float4 Ab[2][4];
    #define LOAD_A(buf, ks)                                                          \
    {                                                                                \
        const float* p0 = &A[(size_t)(R + lm) * C_ + (ks) * 32 + lk8];               \
        const float* p1 = &A[(size_t)(R + 16 + lm) * C_ + (ks) * 32 + lk8];          \
        Ab[buf][0] = *reinterpret_cast<const float4*>(p0);                           \
        Ab[buf][1] = *reinterpret_cast<const float4*>(p0 + 4);                       \
        Ab[buf][2] = *reinterpret_cast<const float4*>(p1);                           \
        Ab[buf][3] = *reinterpret_cast<const float4*>(p1 + 4);                       \
    }
    LOAD_A(0, 0)
    LOAD_A(1, 1)

    #pragma unroll
    for (int ks = 0; ks < 8; ++ks) {
        const int cur = ks & 1;
        bf16x8 ah[2], al[2];
        #pragma unroll
        for (int mf = 0; mf < 2; ++mf) {
            float4 v0 = Ab[cur][mf * 2], v1 = Ab[cur][mf * 2 + 1];
            float xs[8] = {v0.x, v0.y, v0.z, v0.w, v1.x, v1.y, v1.z, v1.w};
            #pragma unroll
            for (int e = 0; e < 8; ++e) {
                const unsigned short h = f2bf(xs[e]);
                ah[mf][e] = (short)h;
                al[mf][e] = (short)f2bf(xs[e] - bf2f(h));
            }
        }
        if (ks < 6) LOAD_A(cur, ks + 2)
        bf16x8 Bh[4], Bl[4];
        #pragma unroll
        for (int nf = 0; nf < 4; ++nf) {
            const int o = WT_IDX(nf * 16 + lm, ks * 32 + lk8);
            Bh[nf] = *reinterpret_cast<const bf16x8*>(&WTh[o]);
            Bl[nf] = *reinterpret_cast<const bf16x8*>(&WTl[o]);
        }
        #pragma unroll
        for (int mf = 0; mf < 2; ++mf)
            #pragma unroll
            for (int nf = 0; nf < 4; ++nf) {
                acc[mf][nf] = __builtin_amdgcn_mfma_f32_16x16x32_bf16(ah[mf], Bh[nf], acc[mf][nf], 0, 0, 0);
                acc[mf][nf] = __builtin_amdgcn_mfma_f32_16x16x32_bf16(ah[mf], Bl[nf], acc[mf][nf], 0, 0, 0);
                acc[mf][nf] = __builtin_amdgcn_mfma_f32_16x16x32_bf16(al[mf], Bh[nf], acc[mf][nf], 0, 0, 0);
            }
    }
    #undef LOAD_A

    // epilogue: bias + scatter to (B,H,L,DK)
    #pragma unroll
    for (int mf = 0; mf < 2; ++mf)
        #pragma unroll
        for (int nf = 0; nf < 4; ++nf) {
            const int col = n0 + nf * 16 + lm;
            const int h = col >> 5, d = col & 31;
            const float bb = bias[col];
            #pragma unroll
            for (int r = 0; r < 4; ++r) {
                const int m = R + mf * 16 + cr + r;
                const int b = m >> 11, lrow = m & (L_ - 1);
                out[((size_t)(b * H_ + h) * L_ + lrow) * DK_ + d] = acc[mf][nf][r] + bb;
            }
        }

    // V column-sum partials (deterministic, per block = 128 rows x 64 cols)
    if (proj == 2) {
        float sl[4];
        #pragma unroll
        for (int nf = 0; nf < 4; ++nf) {
            float s = 0.f;
            #pragma unroll
            for (int mf = 0; mf < 2; ++mf)
                #pragma unroll
                for (int r = 0; r < 4; ++r) s += acc[mf][nf][r];
            s += __shfl_xor(s, 16);
            s += __shfl_xor(s, 32);
            sl[nf] = s;
        }
        if (l < 16) {
            #pragma unroll
            for (int nf = 0; nf < 4; ++nf) red[w][nf][l] = sl[nf];
        }
        __syncthreads();
        if (tid < 64) {
            const int nf = tid >> 4, lmm = tid & 15;
            float tot = red[0][nf][lmm] + red[1][nf][lmm] + red[2][nf][lmm] + red[3][nf][lmm];
            const int col = n0 + nf * 16 + lmm;
            tot += 128.f * bias[col];
            const int h = col >> 5, d = col & 31;
            const int bh = (bx >> 4) * H_ + h;       // block spans one b
            part[((size_t)bh * 32 + d) * 16 + (bx & 15)] = tot;
        }
    }
}

// ---------------------------------------------------------------------------
// K2: ALL attention in one dispatch, 544 blocks x 128 thr.
//  Blocks 0..511  : interior rows, one row per lane, 64-row chunks
//                   (bh = blk>>5, chunk = blk&31), K/V/Q staged in LDS.
//  Blocks 512..543: global rows 0 / L-1, one block per (bh,row), dense
//                   softmax with PARALLEL PV (16 row-groups x 8 quad-cols).
// ---------------------------------------------------------------------------
#define NSLOT 200            // 68 K + 68 V + 64 Q
#define VOFF  68
#define QOFF  136

__global__ __launch_bounds__(128) void attn_all(
    const float* __restrict__ q, const float* __restrict__ k,
    const float* __restrict__ v, const float* __restrict__ part,
    unsigned short* __restrict__ zh, unsigned short* __restrict__ zl)
{
    __shared__ float Sf[NSLOT * 32 + 32];
    float* vs_sh = &Sf[NSLOT * 32];

    // logical (slot, quad, elem) -> phys dword: slot*32 + ((quad ^ (slot&7))<<2) + elem
    #define LDS_F4(slot, u2) (*reinterpret_cast<const float4*>(&Sf[((slot) << 5) + (((u2) ^ ((slot) & 7)) << 2)]))

    const int blk = blockIdx.x;
    const int t = threadIdx.x;

    if (blk < 512) {
        // ----------------- interior rows, per-lane, 64-row chunks -----------------
        const int bh = blk >> 5, c = blk & 31;
        const int base = c * 64;                    // K/V slot s (<66) = row base+s
        const float* qb = q + (size_t)bh * L_ * DK_;
        const float* kb = k + (size_t)bh * L_ * DK_;
        const float* vb = v + (size_t)bh * L_ * DK_;

        // stage K(68 slots) V(68) Q(64) = 1600 float4 units
        for (int u = t; u < NSLOT * 8; u += 128) {
            const int slot = u >> 3, quad = u & 7;
            int row; const float* src;
            if (slot < VOFF) {
                const int s = slot;
                row = (s < 66) ? min(base + s, L_ - 1) : ((s == 66) ? 0 : L_ - 1);
                src = kb;
            } else if (slot < QOFF) {
                const int s = slot - VOFF;
                row = (s < 66) ? min(base + s, L_ - 1) : ((s == 66) ? 0 : L_ - 1);
                src = vb;
            } else {
                row = min(base + 1 + (slot - QOFF), L_ - 1);
                src = qb;
            }
            float4 w4 = *reinterpret_cast<const float4*>(&src[(size_t)row * DK_ + quad * 4]);
            float* dst = &Sf[(slot << 5) + ((quad ^ (slot & 7)) << 2)];
            dst[0] = w4.x; dst[1] = w4.y; dst[2] = w4.z; dst[3] = w4.w;
        }
        if (t < 32) {
            const float4* pp = reinterpret_cast<const float4*>(&part[((size_t)bh * 32 + t) * 16]);
            float4 pa = pp[0], pb = pp[1], pc = pp[2], pd = pp[3];
            vs_sh[t] = pa.x + pa.y + pa.z + pa.w + pb.x + pb.y + pb.z + pb.w
                     + pc.x + pc.y + pc.z + pc.w + pd.x + pd.y + pd.z + pd.w;
        }
        __syncthreads();

        const int i = base + 1 + t;
        if (t < 64 && i <= L_ - 2) {
            float qr[32];
            {
                const int qs = QOFF + t;
                #pragma unroll
                for (int u2 = 0; u2 < 8; ++u2) {
                    float4 x = LDS_F4(qs, u2);
                    qr[u2 * 4 + 0] = x.x; qr[u2 * 4 + 1] = x.y;
                    qr[u2 * 4 + 2] = x.z; qr[u2 * 4 + 3] = x.w;
                }
            }
            const int ks_[5] = {66, t, t + 1, t + 2, 67};   // cols 0, i-1, i, i+1, L-1
            float sv[5];
            #pragma unroll
            for (int jj = 0; jj < 5; ++jj) {
                const int s = ks_[jj];
                float p = 0.f;
                #pragma unroll
                for (int u2 = 0; u2 < 8; ++u2) {
                    float4 kv = LDS_F4(s, u2);
                    p += qr[u2 * 4 + 0] * kv.x + qr[u2 * 4 + 1] * kv.y
                       + qr[u2 * 4 + 2] * kv.z + qr[u2 * 4 + 3] * kv.w;
                }
                sv[jj] = p * RSQRT_DK;
            }
            const bool v1 = (i != 1), v3 = (i != L_ - 2);
            float m = fmaxf(0.f, sv[0]);                 // zero fillers join the max
            m = fmaxf(m, sv[2]); m = fmaxf(m, sv[4]);
            if (v1) m = fmaxf(m, sv[1]);
            if (v3) m = fmaxf(m, sv[3]);
            float e[5];
            e[0] = __expf(sv[0] - m);
            e[1] = v1 ? __expf(sv[1] - m) : 0.f;
            e[2] = __expf(sv[2] - m);
            e[3] = v3 ? __expf(sv[3] - m) : 0.f;
            e[4] = __expf(sv[4] - m);
            const int ns = 3 + (int)v1 + (int)v3;
            const float e0 = __expf(-m);
            const float Z = e[0] + e[1] + e[2] + e[3] + e[4] + (float)(L_ - ns) * e0;
            const float rZ = 1.f / Z;
            const float f1 = v1 ? 1.f : 0.f, f3 = v3 ? 1.f : 0.f;

            bf16x8 zh8[4], zl8[4];
            #pragma unroll
            for (int u2 = 0; u2 < 8; ++u2) {
                float4 x0 = LDS_F4(VOFF + 66,    u2);
                float4 x1 = LDS_F4(VOFF + t,     u2);
                float4 x2 = LDS_F4(VOFF + t + 1, u2);
                float4 x3 = LDS_F4(VOFF + t + 2, u2);
                float4 x4 = LDS_F4(VOFF + 67,    u2);
                float a0[4] = {x0.x, x0.y, x0.z, x0.w};
                float a1[4] = {x1.x, x1.y, x1.z, x1.w};
                float a2[4] = {x2.x, x2.y, x2.z, x2.w};
                float a3[4] = {x3.x, x3.y, x3.z, x3.w};
                float a4[4] = {x4.x, x4.y, x4.z, x4.w};
                #pragma unroll
                for (int e2 = 0; e2 < 4; ++e2) {
                    const int d = u2 * 4 + e2;
                    const float num = e[0] * a0[e2] + e[1] * a1[e2] + e[2] * a2[e2]
                                    + e[3] * a3[e2] + e[4] * a4[e2];
                    const float vp = a0[e2] + f1 * a1[e2] + a2[e2] + f3 * a3[e2] + a4[e2];
                    const float zd = (num + e0 * (vs_sh[d] - vp)) * rZ;
                    const unsigned short hb = f2bf(zd);
                    zh8[d >> 3][d & 7] = (short)hb;
                    zl8[d >> 3][d & 7] = (short)f2bf(zd - bf2f(hb));
                }
            }
            const int b = bh >> 3, h = bh & 7;
            const size_t o = (size_t)(b * L_ + i) * HD_ + h * DK_;
            #pragma unroll
            for (int u4 = 0; u4 < 4; ++u4) {
                *reinterpret_cast<bf16x8*>(&zh[o + u4 * 8]) = zh8[u4];
                *reinterpret_cast<bf16x8*>(&zl[o + u4 * 8]) = zl8[u4];
            }
        }
    } else {
        // ----------- global rows: whole-row dense softmax, parallel PV -----------
        const int gr = blk - 512;                   // 0..31
        const int bh = gr >> 1;
        const int r = (gr & 1) ? (L_ - 1) : 0;
        const float* qb = q + (size_t)bh * L_ * DK_;
        const float* kb = k + (size_t)bh * L_ * DK_;
        const float* vb = v + (size_t)bh * L_ * DK_;

        float* qs  = Sf;              // 32
        float* sc  = Sf + 32;         // 2048
        float* red = Sf + 2080;       // 8
        float* pzs = Sf + 2088;       // 512

        if (t < 32) qs[t] = qb[(size_t)r * DK_ + t];
        __syncthreads();

        float lmax = -1e30f;
        #pragma unroll
        for (int rep = 0; rep < 16; ++rep) {
            const int j = t + rep * 128;
            const float4* kp = reinterpret_cast<const float4*>(&kb[(size_t)j * DK_]);
            float p = 0.f;
            #pragma unroll
            for (int u = 0; u < 8; ++u) {
                float4 kv = kp[u];
                p += qs[u * 4 + 0] * kv.x + qs[u * 4 + 1] * kv.y
                   + qs[u * 4 + 2] * kv.z + qs[u * 4 + 3] * kv.w;
            }
            p *= RSQRT_DK;
            sc[j] = p;
            lmax = fmaxf(lmax, p);
        }
        #pragma unroll
        for (int off = 32; off; off >>= 1) lmax = fmaxf(lmax, __shfl_xor(lmax, off, 64));
        if ((t & 63) == 0) red[t >> 6] = lmax;
        __syncthreads();
        const float m = fmaxf(red[0], red[1]);

        float lsum = 0.f;
        #pragma unroll
        for (int rep = 0; rep < 16; ++rep) {
            const int j = t + rep * 128;
            const float e = __expf(sc[j] - m);
            sc[j] = e;
            lsum += e;
        }
        #pragma unroll
        for (int off = 32; off; off >>= 1) lsum += __shfl_xor(lsum, off, 64);
        if ((t & 63) == 0) red[2 + (t >> 6)] = lsum;
        __syncthreads();
        const float Z = red[2] + red[3];

        // parallel PV: 16 row-groups x 8 quad-columns; 128 coalesced iters
        const int jg = t >> 3, dq = t & 7;
        f32x4 a4 = (f32x4){0.f, 0.f, 0.f, 0.f};
        const float4* vb4 = reinterpret_cast<const float4*>(vb);
        #pragma unroll 4
        for (int it = 0; it < 128; ++it) {
            const int j = jg + it * 16;
            const float s = sc[j];
            const float4 vv = vb4[(size_t)j * 8 + dq];
            a4[0] += s * vv.x; a4[1] += s * vv.y; a4[2] += s * vv.z; a4[3] += s * vv.w;
        }
        pzs[jg * 32 + dq * 4 + 0] = a4[0];
        pzs[jg * 32 + dq * 4 + 1] = a4[1];
        pzs[jg * 32 + dq * 4 + 2] = a4[2];
        pzs[jg * 32 + dq * 4 + 3] = a4[3];
        __syncthreads();
        if (t < 32) {
            float zsum = 0.f;
            #pragma unroll
            for (int g2 = 0; g2 < 16; ++g2) zsum += pzs[g2 * 32 + t];
            const float zd = zsum / Z;
            const int b = bh >> 3, h = bh & 7;
            const size_t o = (size_t)(b * L_ + r) * HD_ + h * DK_ + t;
            const unsigned short hb = f2bf(zd);
            zh[o] = hb;
            zl[o] = f2bf(zd - bf2f(hb));
        }
    }
    #undef LDS_F4
}

// ---------------------------------------------------------------------------
// K3: out = z @ WO + bO via split-bf16 MFMA, self-contained (WO transpose+
// convert fused in LDS).  Grid (64, 4), 256 thr = 4 waves; block tile 64x64,
// wave tile 16x64.
// ---------------------------------------------------------------------------
__global__ __launch_bounds__(256) void gemm_out_fused(
    const unsigned short* __restrict__ zh, const unsigned short* __restrict__ zl,
    const float* __restrict__ WO, const float* __restrict__ bO,
    float* __restrict__ out)
{
    const int bx = blockIdx.x;          // 0..63
    const int nt = blockIdx.y;          // 0..3
    const int n0 = nt * 64;

    __shared__ short WTh[64 * 256];
    __shared__ short WTl[64 * 256];

    const int tid = threadIdx.x;
    stage_wT(WO, n0, tid, WTh, WTl);
    __syncthreads();

    const int w  = tid >> 6;
    const int l  = tid & 63;
    const int lm = l & 15, lk8 = (l >> 4) * 8, cr = (l >> 4) * 4;
    const int R  = bx * 64 + w * 16;

    f32x4 acc[4];
    #pragma unroll
    for (int nf = 0; nf < 4; ++nf) acc[nf] = (f32x4){0.f, 0.f, 0.f, 0.f};

    bf16x8 Ah[2], Al[2];
    #define LOAD_Z(buf, ks)                                                          \
    {                                                                                \
        const size_t o = (size_t)(R + lm) * HD_ + (ks) * 32 + lk8;                   \
        Ah[buf] = *reinterpret_cast<const bf16x8*>(&zh[o]);                          \
        Al[buf] = *reinterpret_cast<const bf16x8*>(&zl[o]);                          \
    }
    LOAD_Z(0, 0)
    LOAD_Z(1, 1)

    #pragma unroll
    for (int ks = 0; ks < 8; ++ks) {
        const int cur = ks & 1;
        const bf16x8 a_h = Ah[cur], a_l = Al[cur];
        if (ks < 6) LOAD_Z(cur, ks + 2)
        #pragma unroll
        for (int nf = 0; nf < 4; ++nf) {
            const int o = WT_IDX(nf * 16 + lm, ks * 32 + lk8);
            const bf16x8 b_h = *reinterpret_cast<const bf16x8*>(&WTh[o]);
            const bf16x8 b_l = *reinterpret_cast<const bf16x8*>(&WTl[o]);
            acc[nf] = __builtin_amdgcn_mfma_f32_16x16x32_bf16(a_h, b_h, acc[nf], 0, 0, 0);
            acc[nf] = __builtin_amdgcn_mfma_f32_16x16x32_bf16(a_h, b_l, acc[nf], 0, 0, 0);
            acc[nf] = __builtin_amdgcn_mfma_f32_16x16x32_bf16(a_l, b_h, acc[nf], 0, 0, 0);
        }
    }
    #undef LOAD_Z

    #pragma unroll
    for (int nf = 0; nf < 4; ++nf) {
        const int col = n0 + nf * 16 + lm;
        const float bb = bO[col];
        #pragma unroll
        for (int r = 0; r < 4; ++r) {
            const int m = R + cr + r;
            out[(size_t)m * HD_ + col] = acc[nf][r] + bb;
        }
    }
}

// ---------------------------------------------------------------------------
extern "C" void kernel_launch(void* const* d_in, const int* in_sizes, int n_in,
                              void* d_out, int out_size, void* d_ws, size_t ws_size,
                              hipStream_t stream)
{
    const float* qx = (const float*)d_in[0];
    const float* kx = (const float*)d_in[1];
    const float* vx = (const float*)d_in[2];
    const float* WQ = (const float*)d_in[3];
    const float* bQ = (const float*)d_in[4];
    const float* WK = (const float*)d_in[5];
    const float* bK = (const float*)d_in[6];
    const float* WV = (const float*)d_in[7];
    const float* bV = (const float*)d_in[8];
    const float* WO = (const float*)d_in[9];
    const float* bO = (const float*)d_in[10];
    float* out = (float*)d_out;

    char* wsb = (char*)d_ws;
    float*          q    = (float*)(wsb);                            // 4 MB
    float*          k    = (float*)(wsb + (4u  << 20));              // 4 MB
    float*          v    = (float*)(wsb + (8u  << 20));              // 4 MB
    unsigned short* zh   = (unsigned short*)(wsb + (12u << 20));     // 2 MB
    unsigned short* zl   = (unsigned short*)(wsb + (14u << 20));     // 2 MB
    float*          part = (float*)(wsb + (16u << 20));              // 32 KB

    gemm_qkv_fused<<<dim3(32, 12), 256, 0, stream>>>(qx, kx, vx, WQ, bQ, WK, bK, WV, bV, q, k, v, part);
    attn_all<<<544, 128, 0, stream>>>(q, k, v, part, zh, zl);
    gemm_out_fused<<<dim3(64, 4), 256, 0, stream>>>(zh, zl, WO, bO, out);
}

// Round 12
// 41.120 us; speedup vs baseline: 4.4547x; 1.3576x over previous
//
#include <hip/hip_runtime.h>
#include <hip/hip_bf16.h>

#define B_   2
#define L_   2048
#define C_   256
#define H_   8
#define DK_  32
#define HD_  256
#define RSQRT_DK 0.17677669529663687f  // 1/sqrt(32)

typedef __attribute__((ext_vector_type(8))) short bf16x8;
typedef __attribute__((ext_vector_type(4))) float f32x4;

__device__ __forceinline__ unsigned short f2bf(float x) {
    unsigned int u = __float_as_uint(x);
    u += 0x7fffu + ((u >> 16) & 1u);
    return (unsigned short)(u >> 16);
}
__device__ __forceinline__ float bf2f(unsigned short h) {
    return __uint_as_float((unsigned int)h << 16);
}

// LDS weight-slice layout (per 64x256 plane of shorts): row pitch 256 shorts
// (uniform bank base), 16B-chunk XOR swizzle -> b128 reads/writes at bank floor.
#define WT_IDX(n, k) (((n) << 8) + (((((k) >> 3) ^ ((n) & 7))) << 3) + ((k) & 7))

// Stage W cols [n0, n0+63], k 0..255 from fp32 into LDS planes as split-bf16
// [n][k].  256 threads: wave w handles k-rows [w*64..]; lane n = tid&63.
// Global loads: 64 consecutive lanes read 64 consecutive floats (coalesced).
__device__ __forceinline__ void stage_wT(
    const float* __restrict__ W, int n0, int tid,
    short* __restrict__ WTh, short* __restrict__ WTl)
{
    const int n  = tid & 63;
    const int kc = tid >> 6;           // 0..3
    #pragma unroll
    for (int c8 = 0; c8 < 8; ++c8) {
        const int k0 = kc * 64 + c8 * 8;
        bf16x8 hv, lv;
        #pragma unroll
        for (int e = 0; e < 8; ++e) {
            const float x = W[(size_t)(k0 + e) * HD_ + n0 + n];
            const unsigned short h = f2bf(x);
            hv[e] = (short)h;
            lv[e] = (short)f2bf(x - bf2f(h));
        }
        const int o = (n << 8) + ((((k0 >> 3) ^ (n & 7))) << 3);
        *reinterpret_cast<bf16x8*>(&WTh[o]) = hv;
        *reinterpret_cast<bf16x8*>(&WTl[o]) = lv;
    }
}

// ---------------------------------------------------------------------------
// K1: QKV projection, split-bf16 MFMA, self-contained (W transpose+convert
// fused in LDS; A converted in-loop from fp32).  Grid (32, 12 = proj*4+nt),
// 256 thr = 4 waves; block tile 128x64, wave tile 32x64.  Also emits
// deterministic per-block V column-sum partials.  (round-7 verbatim)
// ---------------------------------------------------------------------------
__global__ __launch_bounds__(256) void gemm_qkv_fused(
    const float* __restrict__ qx, const float* __restrict__ kx, const float* __restrict__ vx,
    const float* __restrict__ WQ, const float* __restrict__ bQ,
    const float* __restrict__ WK, const float* __restrict__ bK,
    const float* __restrict__ WV, const float* __restrict__ bV,
    float* __restrict__ q, float* __restrict__ k, float* __restrict__ v,
    float* __restrict__ part)
{
    const int bx = blockIdx.x;          // 0..31
    const int yy = blockIdx.y;          // 0..11
    const int proj = yy >> 2, nt = yy & 3;
    const float* A    = proj == 0 ? qx : (proj == 1 ? kx : vx);
    const float* W    = proj == 0 ? WQ : (proj == 1 ? WK : WV);
    const float* bias = proj == 0 ? bQ : (proj == 1 ? bK : bV);
    float* out        = proj == 0 ? q  : (proj == 1 ? k  : v);
    const int n0 = nt * 64;

    __shared__ short WTh[64 * 256];
    __shared__ short WTl[64 * 256];
    __shared__ float red[4][4][16];

    const int tid = threadIdx.x;
    stage_wT(W, n0, tid, WTh, WTl);
    __syncthreads();

    const int w  = tid >> 6;            // wave 0..3
    const int l  = tid & 63;
    const int lm = l & 15, lk8 = (l >> 4) * 8, cr = (l >> 4) * 4;
    const int R  = bx * 128 + w * 32;

    f32x4 acc[2][4];
    #pragma unroll
    for (int mf = 0; mf < 2; ++mf)
        #pragma unroll
        for (int nf = 0; nf < 4; ++nf)
            acc[mf][nf] = (f32x4){0.f, 0.f, 0.f, 0.f};

    float4 Ab[2][4];
    #define LOAD_A(buf, ks)                                                          \
    {                                                                                \
        const float* p0 = &A[(size_t)(R + lm) * C_ + (ks) * 32 + lk8];               \
        const float* p1 = &A[(size_t)(R + 16 + lm) * C_ + (ks) * 32 + lk8];          \
        Ab[buf][0] = *reinterpret_cast<const float4*>(p0);                           \
        Ab[buf][1] = *reinterpret_cast<const float4*>(p0 + 4);                       \
        Ab[buf][2] = *reinterpret_cast<const float4*>(p1);                           \
        Ab[buf][3] = *reinterpret_cast<const float4*>(p1 + 4);                       \
    }
    LOAD_A(0, 0)
    LOAD_A(1, 1)

    #pragma unroll
    for (int ks = 0; ks < 8; ++ks) {
        const int cur = ks & 1;
        bf16x8 ah[2], al[2];
        #pragma unroll
        for (int mf = 0; mf < 2; ++mf) {
            float4 v0 = Ab[cur][mf * 2], v1 = Ab[cur][mf * 2 + 1];
            float xs[8] = {v0.x, v0.y, v0.z, v0.w, v1.x, v1.y, v1.z, v1.w};
            #pragma unroll
            for (int e = 0; e < 8; ++e) {
                const unsigned short h = f2bf(xs[e]);
                ah[mf][e] = (short)h;
                al[mf][e] = (short)f2bf(xs[e] - bf2f(h));
            }
        }
        if (ks < 6) LOAD_A(cur, ks + 2)
        bf16x8 Bh[4], Bl[4];
        #pragma unroll
        for (int nf = 0; nf < 4; ++nf) {
            const int o = WT_IDX(nf * 16 + lm, ks * 32 + lk8);
            Bh[nf] = *reinterpret_cast<const bf16x8*>(&WTh[o]);
            Bl[nf] = *reinterpret_cast<const bf16x8*>(&WTl[o]);
        }
        #pragma unroll
        for (int mf = 0; mf < 2; ++mf)
            #pragma unroll
            for (int nf = 0; nf < 4; ++nf) {
                acc[mf][nf] = __builtin_amdgcn_mfma_f32_16x16x32_bf16(ah[mf], Bh[nf], acc[mf][nf], 0, 0, 0);
                acc[mf][nf] = __builtin_amdgcn_mfma_f32_16x16x32_bf16(ah[mf], Bl[nf], acc[mf][nf], 0, 0, 0);
                acc[mf][nf] = __builtin_amdgcn_mfma_f32_16x16x32_bf16(al[mf], Bh[nf], acc[mf][nf], 0, 0, 0);
            }
    }
    #undef LOAD_A

    // epilogue: bias + scatter to (B,H,L,DK)
    #pragma unroll
    for (int mf = 0; mf < 2; ++mf)
        #pragma unroll
        for (int nf = 0; nf < 4; ++nf) {
            const int col = n0 + nf * 16 + lm;
            const int h = col >> 5, d = col & 31;
            const float bb = bias[col];
            #pragma unroll
            for (int r = 0; r < 4; ++r) {
                const int m = R + mf * 16 + cr + r;
                const int b = m >> 11, lrow = m & (L_ - 1);
                out[((size_t)(b * H_ + h) * L_ + lrow) * DK_ + d] = acc[mf][nf][r] + bb;
            }
        }

    // V column-sum partials (deterministic, per block = 128 rows x 64 cols)
    if (proj == 2) {
        float sl[4];
        #pragma unroll
        for (int nf = 0; nf < 4; ++nf) {
            float s = 0.f;
            #pragma unroll
            for (int mf = 0; mf < 2; ++mf)
                #pragma unroll
                for (int r = 0; r < 4; ++r) s += acc[mf][nf][r];
            s += __shfl_xor(s, 16);
            s += __shfl_xor(s, 32);
            sl[nf] = s;
        }
        if (l < 16) {
            #pragma unroll
            for (int nf = 0; nf < 4; ++nf) red[w][nf][l] = sl[nf];
        }
        __syncthreads();
        if (tid < 64) {
            const int nf = tid >> 4, lmm = tid & 15;
            float tot = red[0][nf][lmm] + red[1][nf][lmm] + red[2][nf][lmm] + red[3][nf][lmm];
            const int col = n0 + nf * 16 + lmm;
            tot += 128.f * bias[col];
            const int h = col >> 5, d = col & 31;
            const int bh = (bx >> 4) * H_ + h;       // block spans one b
            part[((size_t)bh * 32 + d) * 16 + (bx & 15)] = tot;
        }
    }
}

// ---------------------------------------------------------------------------
// K2: attention (round-7 structure, verbatim).
//  Blocks 0..255   : interior rows, ONE ROW PER LANE (bh = blk>>4, 128-row
//                    chunk = blk&15), K/V/Q staged in LDS, XOR-quad swizzle.
//  Blocks 256..767 : global-row partials (bh, row-pair, 128-col chunk).
// 128 threads (2 waves) per block.
// ---------------------------------------------------------------------------
#define NSLOT 392            // 132 K + 132 V + 128 Q
#define KOFF  0
#define VOFF  132
#define QOFF  264

__global__ __launch_bounds__(128) void attn_main(
    const float* __restrict__ q, const float* __restrict__ k,
    const float* __restrict__ v, const float* __restrict__ part,
    float* __restrict__ pm, float* __restrict__ pZ, float* __restrict__ pzv,
    unsigned short* __restrict__ zh, unsigned short* __restrict__ zl)
{
    __shared__ float Sf[NSLOT * 32 + 32];
    float* vs_sh = &Sf[NSLOT * 32];

    // logical (slot, quad, elem) -> phys dword: slot*32 + ((quad ^ (slot&7))<<2) + elem
    #define LDS_F4(slot, u2) (*reinterpret_cast<const float4*>(&Sf[((slot) << 5) + (((u2) ^ ((slot) & 7)) << 2)]))

    const int blk = blockIdx.x;
    const int t = threadIdx.x;

    if (blk < 256) {
        // ----------------- interior rows, per-lane -----------------
        const int bh = blk >> 4, c = blk & 15;
        const int base = c * 128;                   // slot s (<130) = row base+s
        const float* qb = q + (size_t)bh * L_ * DK_;
        const float* kb = k + (size_t)bh * L_ * DK_;
        const float* vb = v + (size_t)bh * L_ * DK_;

        // stage K(132 slots) V(132) Q(128) = 3136 float4 units
        for (int u = t; u < NSLOT * 8; u += 128) {
            const int slot = u >> 3, quad = u & 7;
            int row; const float* src;
            if (slot < VOFF) {
                const int s = slot;
                row = (s < 130) ? min(base + s, L_ - 1) : ((s == 130) ? 0 : L_ - 1);
                src = kb;
            } else if (slot < QOFF) {
                const int s = slot - VOFF;
                row = (s < 130) ? min(base + s, L_ - 1) : ((s == 130) ? 0 : L_ - 1);
                src = vb;
            } else {
                row = min(base + 1 + (slot - QOFF), L_ - 1);
                src = qb;
            }
            float4 w4 = *reinterpret_cast<const float4*>(&src[(size_t)row * DK_ + quad * 4]);
            float* dst = &Sf[(slot << 5) + ((quad ^ (slot & 7)) << 2)];
            dst[0] = w4.x; dst[1] = w4.y; dst[2] = w4.z; dst[3] = w4.w;
        }
        if (t < 32) {
            const float4* pp = reinterpret_cast<const float4*>(&part[((size_t)bh * 32 + t) * 16]);
            float4 pa = pp[0], pb = pp[1], pc = pp[2], pd = pp[3];
            vs_sh[t] = pa.x + pa.y + pa.z + pa.w + pb.x + pb.y + pb.z + pb.w
                     + pc.x + pc.y + pc.z + pc.w + pd.x + pd.y + pd.z + pd.w;
        }
        __syncthreads();

        const int i = base + 1 + t;
        if (i <= L_ - 2) {
            float qr[32];
            {
                const int qs = QOFF + t;
                #pragma unroll
                for (int u2 = 0; u2 < 8; ++u2) {
                    float4 x = LDS_F4(qs, u2);
                    qr[u2 * 4 + 0] = x.x; qr[u2 * 4 + 1] = x.y;
                    qr[u2 * 4 + 2] = x.z; qr[u2 * 4 + 3] = x.w;
                }
            }
            const int ks_[5] = {130, t, t + 1, t + 2, 131};   // cols 0, i-1, i, i+1, L-1
            float sv[5];
            #pragma unroll
            for (int jj = 0; jj < 5; ++jj) {
                const int s = ks_[jj];
                float p = 0.f;
                #pragma unroll
                for (int u2 = 0; u2 < 8; ++u2) {
                    float4 kv = LDS_F4(s, u2);
                    p += qr[u2 * 4 + 0] * kv.x + qr[u2 * 4 + 1] * kv.y
                       + qr[u2 * 4 + 2] * kv.z + qr[u2 * 4 + 3] * kv.w;
                }
                sv[jj] = p * RSQRT_DK;
            }
            const bool v1 = (i != 1), v3 = (i != L_ - 2);
            float m = fmaxf(0.f, sv[0]);                 // zero fillers join the max
            m = fmaxf(m, sv[2]); m = fmaxf(m, sv[4]);
            if (v1) m = fmaxf(m, sv[1]);
            if (v3) m = fmaxf(m, sv[3]);
            float e[5];
            e[0] = __expf(sv[0] - m);
            e[1] = v1 ? __expf(sv[1] - m) : 0.f;
            e[2] = __expf(sv[2] - m);
            e[3] = v3 ? __expf(sv[3] - m) : 0.f;
            e[4] = __expf(sv[4] - m);
            const int ns = 3 + (int)v1 + (int)v3;
            const float e0 = __expf(-m);
            const float Z = e[0] + e[1] + e[2] + e[3] + e[4] + (float)(L_ - ns) * e0;
            const float rZ = 1.f / Z;
            const float f1 = v1 ? 1.f : 0.f, f3 = v3 ? 1.f : 0.f;

            bf16x8 zh8[4], zl8[4];
            #pragma unroll
            for (int u2 = 0; u2 < 8; ++u2) {
                float4 x0 = LDS_F4(VOFF + 130,   u2);
                float4 x1 = LDS_F4(VOFF + t,     u2);
                float4 x2 = LDS_F4(VOFF + t + 1, u2);
                float4 x3 = LDS_F4(VOFF + t + 2, u2);
                float4 x4 = LDS_F4(VOFF + 131,   u2);
                float a0[4] = {x0.x, x0.y, x0.z, x0.w};
                float a1[4] = {x1.x, x1.y, x1.z, x1.w};
                float a2[4] = {x2.x, x2.y, x2.z, x2.w};
                float a3[4] = {x3.x, x3.y, x3.z, x3.w};
                float a4[4] = {x4.x, x4.y, x4.z, x4.w};
                #pragma unroll
                for (int e2 = 0; e2 < 4; ++e2) {
                    const int d = u2 * 4 + e2;
                    const float num = e[0] * a0[e2] + e[1] * a1[e2] + e[2] * a2[e2]
                                    + e[3] * a3[e2] + e[4] * a4[e2];
                    const float vp = a0[e2] + f1 * a1[e2] + a2[e2] + f3 * a3[e2] + a4[e2];
                    const float zd = (num + e0 * (vs_sh[d] - vp)) * rZ;
                    const unsigned short hb = f2bf(zd);
                    zh8[d >> 3][d & 7] = (short)hb;
                    zl8[d >> 3][d & 7] = (short)f2bf(zd - bf2f(hb));
                }
            }
            const int b = bh >> 3, h = bh & 7;
            const size_t o = (size_t)(b * L_ + i) * HD_ + h * DK_;
            #pragma unroll
            for (int u4 = 0; u4 < 4; ++u4) {
                *reinterpret_cast<bf16x8*>(&zh[o + u4 * 8]) = zh8[u4];
                *reinterpret_cast<bf16x8*>(&zl[o + u4 * 8]) = zl8[u4];
            }
        }
    } else {
        // ----------------- global-row partials -----------------
        const int blk2 = blk - 256;                 // 0..511
        const int bh = blk2 >> 5;
        const int pair = (blk2 >> 4) & 1;
        const int chunk = blk2 & 15;
        const int r = pair ? (L_ - 1) : 0;
        const int j0 = chunk * 128;
        const float* qb = q + (size_t)bh * L_ * DK_;
        const float* kb = k + (size_t)bh * L_ * DK_;
        const float* vb = v + (size_t)bh * L_ * DK_;

        float* qs  = Sf;          // 32
        float* sc  = Sf + 32;     // 128
        float* red = Sf + 160;    // 4
        float* pzs = Sf + 192;    // 128

        if (t < 32) qs[t] = qb[(size_t)r * DK_ + t];
        __syncthreads();

        const int j = j0 + t;
        const float4* kr = reinterpret_cast<const float4*>(&kb[(size_t)j * DK_]);
        float p = 0.f;
        #pragma unroll
        for (int u = 0; u < 8; ++u) {
            float4 kv = kr[u];
            p += qs[u * 4 + 0] * kv.x + qs[u * 4 + 1] * kv.y
               + qs[u * 4 + 2] * kv.z + qs[u * 4 + 3] * kv.w;
        }
        p *= RSQRT_DK;

        float lm = p;
        #pragma unroll
        for (int off = 32; off; off >>= 1) lm = fmaxf(lm, __shfl_xor(lm, off, 64));
        if ((t & 63) == 0) red[t >> 6] = lm;
        __syncthreads();
        const float m = fmaxf(red[0], red[1]);

        const float e = __expf(p - m);
        sc[t] = e;
        float ls = e;
        #pragma unroll
        for (int off = 32; off; off >>= 1) ls += __shfl_xor(ls, off, 64);
        if ((t & 63) == 0) red[2 + (t >> 6)] = ls;
        __syncthreads();
        const float Zc = red[2] + red[3];

        const int d = t & 31, g = t >> 5;
        float acc = 0.f;
        #pragma unroll 4
        for (int jj = 0; jj < 32; ++jj)
            acc += sc[g * 32 + jj] * vb[(size_t)(j0 + g * 32 + jj) * DK_ + d];
        pzs[g * 32 + d] = acc;
        __syncthreads();
        if (g == 0) {
            const float s2 = pzs[d] + pzs[32 + d] + pzs[64 + d] + pzs[96 + d];
            pzv[(size_t)blk2 * 32 + d] = s2;
        }
        if (t == 0) { pm[blk2] = m; pZ[blk2] = Zc; }
    }
    #undef LDS_F4
}

// ---------------------------------------------------------------------------
// K3: out = z @ WO + bO via split-bf16 MFMA, self-contained (WO transpose+
// convert fused in LDS) + INLINE global-row combine (replaces attn_g2):
// blocks bx in {0,31,32,63} compute the z-row their A-tile needs from the
// pm/pZ/pzv partials before the GEMM (256 thr = 256 cols; duplicate writes
// across nt are bit-identical).  Grid (64, 4), 256 thr = 4 waves.
// ---------------------------------------------------------------------------
__global__ __launch_bounds__(256) void gemm_out_fused(
    const unsigned short* __restrict__ zh_c, unsigned short* __restrict__ zh,
    unsigned short* __restrict__ zl,
    const float* __restrict__ pm, const float* __restrict__ pZ,
    const float* __restrict__ pzv,
    const float* __restrict__ WO, const float* __restrict__ bO,
    float* __restrict__ out)
{
    const int bx = blockIdx.x;          // 0..63
    const int nt = blockIdx.y;          // 0..3
    const int n0 = nt * 64;

    __shared__ short WTh[64 * 256];
    __shared__ short WTl[64 * 256];

    const int tid = threadIdx.x;
    stage_wT(WO, n0, tid, WTh, WTl);

    // inline combine of global-row partials (was attn_g2_kernel)
    int zrow = -1;
    if      (bx == 0)  zrow = 0;
    else if (bx == 31) zrow = L_ - 1;
    else if (bx == 32) zrow = L_;
    else if (bx == 63) zrow = 2 * L_ - 1;
    if (zrow >= 0) {
        const int h = tid >> 5, d = tid & 31;
        const int b = zrow >> 11;
        const int r = zrow & (L_ - 1);
        const int pair = r ? 1 : 0;
        const int rowIdx = (b * H_ + h) * 2 + pair;
        const int base = rowIdx * 16;
        float m = -1e30f;
        #pragma unroll
        for (int c = 0; c < 16; ++c) m = fmaxf(m, pm[base + c]);
        float Z = 0.f, zd = 0.f;
        #pragma unroll
        for (int c = 0; c < 16; ++c) {
            const float w2 = __expf(pm[base + c] - m);
            Z  += pZ[base + c] * w2;
            zd += pzv[(size_t)(base + c) * 32 + d] * w2;
        }
        zd /= Z;
        const size_t o = (size_t)zrow * HD_ + h * DK_ + d;
        const unsigned short hb = f2bf(zd);
        zh[o] = hb;
        zl[o] = f2bf(zd - bf2f(hb));
    }
    __syncthreads();   // drains vmcnt: z stores complete before LOAD_Z below

    const int w  = tid >> 6;
    const int l  = tid & 63;
    const int lm = l & 15, lk8 = (l >> 4) * 8, cr = (l >> 4) * 4;
    const int R  = bx * 64 + w * 16;

    f32x4 acc[4];
    #pragma unroll
    for (int nf = 0; nf < 4; ++nf) acc[nf] = (f32x4){0.f, 0.f, 0.f, 0.f};

    bf16x8 Ah[2], Al[2];
    #define LOAD_Z(buf, ks)                                                          \
    {                                                                                \
        const size_t o = (size_t)(R + lm) * HD_ + (ks) * 32 + lk8;                   \
        Ah[buf] = *reinterpret_cast<const bf16x8*>(&zh_c[o]);                        \
        Al[buf] = *reinterpret_cast<const bf16x8*>(&zl[o]);                          \
    }
    LOAD_Z(0, 0)
    LOAD_Z(1, 1)

    #pragma unroll
    for (int ks = 0; ks < 8; ++ks) {
        const int cur = ks & 1;
        const bf16x8 a_h = Ah[cur], a_l = Al[cur];
        if (ks < 6) LOAD_Z(cur, ks + 2)
        #pragma unroll
        for (int nf = 0; nf < 4; ++nf) {
            const int o = WT_IDX(nf * 16 + lm, ks * 32 + lk8);
            const bf16x8 b_h = *reinterpret_cast<const bf16x8*>(&WTh[o]);
            const bf16x8 b_l = *reinterpret_cast<const bf16x8*>(&WTl[o]);
            acc[nf] = __builtin_amdgcn_mfma_f32_16x16x32_bf16(a_h, b_h, acc[nf], 0, 0, 0);
            acc[nf] = __builtin_amdgcn_mfma_f32_16x16x32_bf16(a_h, b_l, acc[nf], 0, 0, 0);
            acc[nf] = __builtin_amdgcn_mfma_f32_16x16x32_bf16(a_l, b_h, acc[nf], 0, 0, 0);
        }
    }
    #undef LOAD_Z

    #pragma unroll
    for (int nf = 0; nf < 4; ++nf) {
        const int col = n0 + nf * 16 + lm;
        const float bb = bO[col];
        #pragma unroll
        for (int r = 0; r < 4; ++r) {
            const int m = R + cr + r;
            out[(size_t)m * HD_ + col] = acc[nf][r] + bb;
        }
    }
}

// ---------------------------------------------------------------------------
extern "C" void kernel_launch(void* const* d_in, const int* in_sizes, int n_in,
                              void* d_out, int out_size, void* d_ws, size_t ws_size,
                              hipStream_t stream)
{
    const float* qx = (const float*)d_in[0];
    const float* kx = (const float*)d_in[1];
    const float* vx = (const float*)d_in[2];
    const float* WQ = (const float*)d_in[3];
    const float* bQ = (const float*)d_in[4];
    const float* WK = (const float*)d_in[5];
    const float* bK = (const float*)d_in[6];
    const float* WV = (const float*)d_in[7];
    const float* bV = (const float*)d_in[8];
    const float* WO = (const float*)d_in[9];
    const float* bO = (const float*)d_in[10];
    float* out = (float*)d_out;

    char* wsb = (char*)d_ws;
    float*          q    = (float*)(wsb);                            // 4 MB
    float*          k    = (float*)(wsb + (4u  << 20));              // 4 MB
    float*          v    = (float*)(wsb + (8u  << 20));              // 4 MB
    unsigned short* zh   = (unsigned short*)(wsb + (12u << 20));     // 2 MB
    unsigned short* zl   = (unsigned short*)(wsb + (14u << 20));     // 2 MB
    float*          part = (float*)(wsb + (16u << 20));              // 32 KB
    float*          pm   = (float*)(wsb + (16u << 20) + (1u << 16)); // 512 f
    float*          pZ   = pm + 512;
    float*          pzv  = pm + 1024;                                // 16384 f

    gemm_qkv_fused<<<dim3(32, 12), 256, 0, stream>>>(qx, kx, vx, WQ, bQ, WK, bK, WV, bV, q, k, v, part);
    attn_main<<<768, 128, 0, stream>>>(q, k, v, part, pm, pZ, pzv, zh, zl);
    gemm_out_fused<<<dim3(64, 4), 256, 0, stream>>>(zh, zh, zl, pm, pZ, pzv, WO, bO, out);
}

// Round 13
// 36.597 us; speedup vs baseline: 5.0053x; 1.1236x over previous
//
#include <hip/hip_runtime.h>
#include <hip/hip_bf16.h>

#define B_   2
#define L_   2048
#define C_   256
#define H_   8
#define DK_  32
#define HD_  256
#define RSQRT_DK 0.17677669529663687f  // 1/sqrt(32)

typedef __attribute__((ext_vector_type(8))) short bf16x8;
typedef __attribute__((ext_vector_type(4))) float f32x4;

__device__ __forceinline__ unsigned short f2bf(float x) {
    unsigned int u = __float_as_uint(x);
    u += 0x7fffu + ((u >> 16) & 1u);
    return (unsigned short)(u >> 16);
}
__device__ __forceinline__ float bf2f(unsigned short h) {
    return __uint_as_float((unsigned int)h << 16);
}

// LDS weight-slice layout (per 64x256 plane of shorts): row pitch 256 shorts
// (uniform bank base), 16B-chunk XOR swizzle -> b128 reads/writes at bank floor.
#define WT_IDX(n, k) (((n) << 8) + (((((k) >> 3) ^ ((n) & 7))) << 3) + ((k) & 7))

// Stage W cols [n0, n0+63], k 0..255 from fp32 into LDS planes as split-bf16
// [n][k].  256 threads: wave w handles k-rows [w*64..]; lane n = tid&63.
// Global loads: 64 consecutive lanes read 64 consecutive floats (coalesced).
__device__ __forceinline__ void stage_wT(
    const float* __restrict__ W, int n0, int tid,
    short* __restrict__ WTh, short* __restrict__ WTl)
{
    const int n  = tid & 63;
    const int kc = tid >> 6;           // 0..3
    #pragma unroll
    for (int c8 = 0; c8 < 8; ++c8) {
        const int k0 = kc * 64 + c8 * 8;
        bf16x8 hv, lv;
        #pragma unroll
        for (int e = 0; e < 8; ++e) {
            const float x = W[(size_t)(k0 + e) * HD_ + n0 + n];
            const unsigned short h = f2bf(x);
            hv[e] = (short)h;
            lv[e] = (short)f2bf(x - bf2f(h));
        }
        const int o = (n << 8) + ((((k0 >> 3) ^ (n & 7))) << 3);
        *reinterpret_cast<bf16x8*>(&WTh[o]) = hv;
        *reinterpret_cast<bf16x8*>(&WTl[o]) = lv;
    }
}

// ---------------------------------------------------------------------------
// K1: QKV projection, split-bf16 MFMA, self-contained (W transpose+convert
// fused in LDS; A converted in-loop from fp32).  Grid (32, 12 = proj*4+nt),
// 256 thr = 4 waves; block tile 128x64, wave tile 32x64.  Also emits
// deterministic per-block V column-sum partials.  (round-12 verbatim)
// ---------------------------------------------------------------------------
__global__ __launch_bounds__(256) void gemm_qkv_fused(
    const float* __restrict__ qx, const float* __restrict__ kx, const float* __restrict__ vx,
    const float* __restrict__ WQ, const float* __restrict__ bQ,
    const float* __restrict__ WK, const float* __restrict__ bK,
    const float* __restrict__ WV, const float* __restrict__ bV,
    float* __restrict__ q, float* __restrict__ k, float* __restrict__ v,
    float* __restrict__ part)
{
    const int bx = blockIdx.x;          // 0..31
    const int yy = blockIdx.y;          // 0..11
    const int proj = yy >> 2, nt = yy & 3;
    const float* A    = proj == 0 ? qx : (proj == 1 ? kx : vx);
    const float* W    = proj == 0 ? WQ : (proj == 1 ? WK : WV);
    const float* bias = proj == 0 ? bQ : (proj == 1 ? bK : bV);
    float* out        = proj == 0 ? q  : (proj == 1 ? k  : v);
    const int n0 = nt * 64;

    __shared__ short WTh[64 * 256];
    __shared__ short WTl[64 * 256];
    __shared__ float red[4][4][16];

    const int tid = threadIdx.x;
    stage_wT(W, n0, tid, WTh, WTl);
    __syncthreads();

    const int w  = tid >> 6;            // wave 0..3
    const int l  = tid & 63;
    const int lm = l & 15, lk8 = (l >> 4) * 8, cr = (l >> 4) * 4;
    const int R  = bx * 128 + w * 32;

    f32x4 acc[2][4];
    #pragma unroll
    for (int mf = 0; mf < 2; ++mf)
        #pragma unroll
        for (int nf = 0; nf < 4; ++nf)
            acc[mf][nf] = (f32x4){0.f, 0.f, 0.f, 0.f};

    float4 Ab[2][4];
    #define LOAD_A(buf, ks)                                                          \
    {                                                                                \
        const float* p0 = &A[(size_t)(R + lm) * C_ + (ks) * 32 + lk8];               \
        const float* p1 = &A[(size_t)(R + 16 + lm) * C_ + (ks) * 32 + lk8];          \
        Ab[buf][0] = *reinterpret_cast<const float4*>(p0);                           \
        Ab[buf][1] = *reinterpret_cast<const float4*>(p0 + 4);                       \
        Ab[buf][2] = *reinterpret_cast<const float4*>(p1);                           \
        Ab[buf][3] = *reinterpret_cast<const float4*>(p1 + 4);                       \
    }
    LOAD_A(0, 0)
    LOAD_A(1, 1)

    #pragma unroll
    for (int ks = 0; ks < 8; ++ks) {
        const int cur = ks & 1;
        bf16x8 ah[2], al[2];
        #pragma unroll
        for (int mf = 0; mf < 2; ++mf) {
            float4 v0 = Ab[cur][mf * 2], v1 = Ab[cur][mf * 2 + 1];
            float xs[8] = {v0.x, v0.y, v0.z, v0.w, v1.x, v1.y, v1.z, v1.w};
            #pragma unroll
            for (int e = 0; e < 8; ++e) {
                const unsigned short h = f2bf(xs[e]);
                ah[mf][e] = (short)h;
                al[mf][e] = (short)f2bf(xs[e] - bf2f(h));
            }
        }
        if (ks < 6) LOAD_A(cur, ks + 2)
        bf16x8 Bh[4], Bl[4];
        #pragma unroll
        for (int nf = 0; nf < 4; ++nf) {
            const int o = WT_IDX(nf * 16 + lm, ks * 32 + lk8);
            Bh[nf] = *reinterpret_cast<const bf16x8*>(&WTh[o]);
            Bl[nf] = *reinterpret_cast<const bf16x8*>(&WTl[o]);
        }
        #pragma unroll
        for (int mf = 0; mf < 2; ++mf)
            #pragma unroll
            for (int nf = 0; nf < 4; ++nf) {
                acc[mf][nf] = __builtin_amdgcn_mfma_f32_16x16x32_bf16(ah[mf], Bh[nf], acc[mf][nf], 0, 0, 0);
                acc[mf][nf] = __builtin_amdgcn_mfma_f32_16x16x32_bf16(ah[mf], Bl[nf], acc[mf][nf], 0, 0, 0);
                acc[mf][nf] = __builtin_amdgcn_mfma_f32_16x16x32_bf16(al[mf], Bh[nf], acc[mf][nf], 0, 0, 0);
            }
    }
    #undef LOAD_A

    // epilogue: bias + scatter to (B,H,L,DK)
    #pragma unroll
    for (int mf = 0; mf < 2; ++mf)
        #pragma unroll
        for (int nf = 0; nf < 4; ++nf) {
            const int col = n0 + nf * 16 + lm;
            const int h = col >> 5, d = col & 31;
            const float bb = bias[col];
            #pragma unroll
            for (int r = 0; r < 4; ++r) {
                const int m = R + mf * 16 + cr + r;
                const int b = m >> 11, lrow = m & (L_ - 1);
                out[((size_t)(b * H_ + h) * L_ + lrow) * DK_ + d] = acc[mf][nf][r] + bb;
            }
        }

    // V column-sum partials (deterministic, per block = 128 rows x 64 cols)
    if (proj == 2) {
        float sl[4];
        #pragma unroll
        for (int nf = 0; nf < 4; ++nf) {
            float s = 0.f;
            #pragma unroll
            for (int mf = 0; mf < 2; ++mf)
                #pragma unroll
                for (int r = 0; r < 4; ++r) s += acc[mf][nf][r];
            s += __shfl_xor(s, 16);
            s += __shfl_xor(s, 32);
            sl[nf] = s;
        }
        if (l < 16) {
            #pragma unroll
            for (int nf = 0; nf < 4; ++nf) red[w][nf][l] = sl[nf];
        }
        __syncthreads();
        if (tid < 64) {
            const int nf = tid >> 4, lmm = tid & 15;
            float tot = red[0][nf][lmm] + red[1][nf][lmm] + red[2][nf][lmm] + red[3][nf][lmm];
            const int col = n0 + nf * 16 + lmm;
            tot += 128.f * bias[col];
            const int h = col >> 5, d = col & 31;
            const int bh = (bx >> 4) * H_ + h;       // block spans one b
            part[((size_t)bh * 32 + d) * 16 + (bx & 15)] = tot;
        }
    }
}

// ---------------------------------------------------------------------------
// K2: attention.
//  Blocks 0..255   : interior rows, ONE ROW PER LANE (bh = blk>>4, 128-row
//                    chunk = blk&15).  K+V staged in LDS via ONE fused loop
//                    (shared row calc); Q read DIRECT from global (no reuse).
//  Blocks 256..767 : global-row partials (bh, row-pair, 128-col chunk).
// 128 threads (2 waves) per block.  LDS 34 KB.
// ---------------------------------------------------------------------------
#define NSLOT 264            // 132 K + 132 V
#define VOFF  132

__global__ __launch_bounds__(128) void attn_main(
    const float* __restrict__ q, const float* __restrict__ k,
    const float* __restrict__ v, const float* __restrict__ part,
    float* __restrict__ pm, float* __restrict__ pZ, float* __restrict__ pzv,
    unsigned short* __restrict__ zh, unsigned short* __restrict__ zl)
{
    __shared__ float Sf[NSLOT * 32 + 32];
    float* vs_sh = &Sf[NSLOT * 32];

    // logical (slot, quad, elem) -> phys dword: slot*32 + ((quad ^ (slot&7))<<2) + elem
    #define LDS_F4(slot, u2) (*reinterpret_cast<const float4*>(&Sf[((slot) << 5) + (((u2) ^ ((slot) & 7)) << 2)]))

    const int blk = blockIdx.x;
    const int t = threadIdx.x;

    if (blk < 256) {
        // ----------------- interior rows, per-lane -----------------
        const int bh = blk >> 4, c = blk & 15;
        const int base = c * 128;                   // slot s (<130) = row base+s
        const float* qb = q + (size_t)bh * L_ * DK_;
        const float* kb = k + (size_t)bh * L_ * DK_;
        const float* vb = v + (size_t)bh * L_ * DK_;

        // fused K+V staging: 132 slots x 8 quads = 1056 units, 2 loads each
        for (int u = t; u < 1056; u += 128) {
            const int slot = u >> 3, quad = u & 7;
            const int row = (slot < 130) ? min(base + slot, L_ - 1)
                                         : ((slot == 130) ? 0 : L_ - 1);
            const size_t go = (size_t)row * DK_ + quad * 4;
            float4 kw = *reinterpret_cast<const float4*>(&kb[go]);
            float4 vw = *reinterpret_cast<const float4*>(&vb[go]);
            const int so = ((quad ^ (slot & 7)) << 2);
            float* dk = &Sf[(slot << 5) + so];
            float* dv = &Sf[((slot + VOFF) << 5) + (((quad ^ ((slot + VOFF) & 7))) << 2)];
            dk[0] = kw.x; dk[1] = kw.y; dk[2] = kw.z; dk[3] = kw.w;
            dv[0] = vw.x; dv[1] = vw.y; dv[2] = vw.z; dv[3] = vw.w;
        }
        if (t < 32) {
            const float4* pp = reinterpret_cast<const float4*>(&part[((size_t)bh * 32 + t) * 16]);
            float4 pa = pp[0], pb = pp[1], pc = pp[2], pd = pp[3];
            vs_sh[t] = pa.x + pa.y + pa.z + pa.w + pb.x + pb.y + pb.z + pb.w
                     + pc.x + pc.y + pc.z + pc.w + pd.x + pd.y + pd.z + pd.w;
        }
        __syncthreads();

        const int i = base + 1 + t;
        if (i <= L_ - 2) {
            // Q row read direct from global (zero reuse across threads)
            float qr[32];
            {
                const float4* qp = reinterpret_cast<const float4*>(&qb[(size_t)i * DK_]);
                #pragma unroll
                for (int u2 = 0; u2 < 8; ++u2) {
                    float4 x = qp[u2];
                    qr[u2 * 4 + 0] = x.x; qr[u2 * 4 + 1] = x.y;
                    qr[u2 * 4 + 2] = x.z; qr[u2 * 4 + 3] = x.w;
                }
            }
            const int ks_[5] = {130, t, t + 1, t + 2, 131};   // cols 0, i-1, i, i+1, L-1
            float sv[5];
            #pragma unroll
            for (int jj = 0; jj < 5; ++jj) {
                const int s = ks_[jj];
                float p = 0.f;
                #pragma unroll
                for (int u2 = 0; u2 < 8; ++u2) {
                    float4 kv = LDS_F4(s, u2);
                    p += qr[u2 * 4 + 0] * kv.x + qr[u2 * 4 + 1] * kv.y
                       + qr[u2 * 4 + 2] * kv.z + qr[u2 * 4 + 3] * kv.w;
                }
                sv[jj] = p * RSQRT_DK;
            }
            const bool v1 = (i != 1), v3 = (i != L_ - 2);
            float m = fmaxf(0.f, sv[0]);                 // zero fillers join the max
            m = fmaxf(m, sv[2]); m = fmaxf(m, sv[4]);
            if (v1) m = fmaxf(m, sv[1]);
            if (v3) m = fmaxf(m, sv[3]);
            float e[5];
            e[0] = __expf(sv[0] - m);
            e[1] = v1 ? __expf(sv[1] - m) : 0.f;
            e[2] = __expf(sv[2] - m);
            e[3] = v3 ? __expf(sv[3] - m) : 0.f;
            e[4] = __expf(sv[4] - m);
            const int ns = 3 + (int)v1 + (int)v3;
            const float e0 = __expf(-m);
            const float Z = e[0] + e[1] + e[2] + e[3] + e[4] + (float)(L_ - ns) * e0;
            const float rZ = 1.f / Z;
            const float f1 = v1 ? 1.f : 0.f, f3 = v3 ? 1.f : 0.f;

            bf16x8 zh8[4], zl8[4];
            #pragma unroll
            for (int u2 = 0; u2 < 8; ++u2) {
                float4 x0 = LDS_F4(VOFF + 130,   u2);
                float4 x1 = LDS_F4(VOFF + t,     u2);
                float4 x2 = LDS_F4(VOFF + t + 1, u2);
                float4 x3 = LDS_F4(VOFF + t + 2, u2);
                float4 x4 = LDS_F4(VOFF + 131,   u2);
                float a0[4] = {x0.x, x0.y, x0.z, x0.w};
                float a1[4] = {x1.x, x1.y, x1.z, x1.w};
                float a2[4] = {x2.x, x2.y, x2.z, x2.w};
                float a3[4] = {x3.x, x3.y, x3.z, x3.w};
                float a4[4] = {x4.x, x4.y, x4.z, x4.w};
                #pragma unroll
                for (int e2 = 0; e2 < 4; ++e2) {
                    const int d = u2 * 4 + e2;
                    const float num = e[0] * a0[e2] + e[1] * a1[e2] + e[2] * a2[e2]
                                    + e[3] * a3[e2] + e[4] * a4[e2];
                    const float vp = a0[e2] + f1 * a1[e2] + a2[e2] + f3 * a3[e2] + a4[e2];
                    const float zd = (num + e0 * (vs_sh[d] - vp)) * rZ;
                    const unsigned short hb = f2bf(zd);
                    zh8[d >> 3][d & 7] = (short)hb;
                    zl8[d >> 3][d & 7] = (short)f2bf(zd - bf2f(hb));
                }
            }
            const int b = bh >> 3, h = bh & 7;
            const size_t o = (size_t)(b * L_ + i) * HD_ + h * DK_;
            #pragma unroll
            for (int u4 = 0; u4 < 4; ++u4) {
                *reinterpret_cast<bf16x8*>(&zh[o + u4 * 8]) = zh8[u4];
                *reinterpret_cast<bf16x8*>(&zl[o + u4 * 8]) = zl8[u4];
            }
        }
    } else {
        // ----------------- global-row partials -----------------
        const int blk2 = blk - 256;                 // 0..511
        const int bh = blk2 >> 5;
        const int pair = (blk2 >> 4) & 1;
        const int chunk = blk2 & 15;
        const int r = pair ? (L_ - 1) : 0;
        const int j0 = chunk * 128;
        const float* qb = q + (size_t)bh * L_ * DK_;
        const float* kb = k + (size_t)bh * L_ * DK_;
        const float* vb = v + (size_t)bh * L_ * DK_;

        float* qs  = Sf;          // 32
        float* sc  = Sf + 32;     // 128
        float* red = Sf + 160;    // 4
        float* pzs = Sf + 192;    // 128

        if (t < 32) qs[t] = qb[(size_t)r * DK_ + t];
        __syncthreads();

        const int j = j0 + t;
        const float4* kr = reinterpret_cast<const float4*>(&kb[(size_t)j * DK_]);
        float p = 0.f;
        #pragma unroll
        for (int u = 0; u < 8; ++u) {
            float4 kv = kr[u];
            p += qs[u * 4 + 0] * kv.x + qs[u * 4 + 1] * kv.y
               + qs[u * 4 + 2] * kv.z + qs[u * 4 + 3] * kv.w;
        }
        p *= RSQRT_DK;

        float lm = p;
        #pragma unroll
        for (int off = 32; off; off >>= 1) lm = fmaxf(lm, __shfl_xor(lm, off, 64));
        if ((t & 63) == 0) red[t >> 6] = lm;
        __syncthreads();
        const float m = fmaxf(red[0], red[1]);

        const float e = __expf(p - m);
        sc[t] = e;
        float ls = e;
        #pragma unroll
        for (int off = 32; off; off >>= 1) ls += __shfl_xor(ls, off, 64);
        if ((t & 63) == 0) red[2 + (t >> 6)] = ls;
        __syncthreads();
        const float Zc = red[2] + red[3];

        const int d = t & 31, g = t >> 5;
        float acc = 0.f;
        #pragma unroll 4
        for (int jj = 0; jj < 32; ++jj)
            acc += sc[g * 32 + jj] * vb[(size_t)(j0 + g * 32 + jj) * DK_ + d];
        pzs[g * 32 + d] = acc;
        __syncthreads();
        if (g == 0) {
            const float s2 = pzs[d] + pzs[32 + d] + pzs[64 + d] + pzs[96 + d];
            pzv[(size_t)blk2 * 32 + d] = s2;
        }
        if (t == 0) { pm[blk2] = m; pZ[blk2] = Zc; }
    }
    #undef LDS_F4
}

// ---------------------------------------------------------------------------
// K3: out = z @ WO + bO via split-bf16 MFMA, self-contained (WO transpose+
// convert fused in LDS) + INLINE global-row combine (round-12 verbatim).
// Grid (64, 4), 256 thr = 4 waves; block tile 64x64, wave tile 16x64.
// ---------------------------------------------------------------------------
__global__ __launch_bounds__(256) void gemm_out_fused(
    const unsigned short* __restrict__ zh_c, unsigned short* __restrict__ zh,
    unsigned short* __restrict__ zl,
    const float* __restrict__ pm, const float* __restrict__ pZ,
    const float* __restrict__ pzv,
    const float* __restrict__ WO, const float* __restrict__ bO,
    float* __restrict__ out)
{
    const int bx = blockIdx.x;          // 0..63
    const int nt = blockIdx.y;          // 0..3
    const int n0 = nt * 64;

    __shared__ short WTh[64 * 256];
    __shared__ short WTl[64 * 256];

    const int tid = threadIdx.x;
    stage_wT(WO, n0, tid, WTh, WTl);

    // inline combine of global-row partials (was attn_g2_kernel)
    int zrow = -1;
    if      (bx == 0)  zrow = 0;
    else if (bx == 31) zrow = L_ - 1;
    else if (bx == 32) zrow = L_;
    else if (bx == 63) zrow = 2 * L_ - 1;
    if (zrow >= 0) {
        const int h = tid >> 5, d = tid & 31;
        const int b = zrow >> 11;
        const int r = zrow & (L_ - 1);
        const int pair = r ? 1 : 0;
        const int rowIdx = (b * H_ + h) * 2 + pair;
        const int base = rowIdx * 16;
        float m = -1e30f;
        #pragma unroll
        for (int c = 0; c < 16; ++c) m = fmaxf(m, pm[base + c]);
        float Z = 0.f, zd = 0.f;
        #pragma unroll
        for (int c = 0; c < 16; ++c) {
            const float w2 = __expf(pm[base + c] - m);
            Z  += pZ[base + c] * w2;
            zd += pzv[(size_t)(base + c) * 32 + d] * w2;
        }
        zd /= Z;
        const size_t o = (size_t)zrow * HD_ + h * DK_ + d;
        const unsigned short hb = f2bf(zd);
        zh[o] = hb;
        zl[o] = f2bf(zd - bf2f(hb));
    }
    __syncthreads();   // drains vmcnt: z stores complete before LOAD_Z below

    const int w  = tid >> 6;
    const int l  = tid & 63;
    const int lm = l & 15, lk8 = (l >> 4) * 8, cr = (l >> 4) * 4;
    const int R  = bx * 64 + w * 16;

    f32x4 acc[4];
    #pragma unroll
    for (int nf = 0; nf < 4; ++nf) acc[nf] = (f32x4){0.f, 0.f, 0.f, 0.f};

    bf16x8 Ah[2], Al[2];
    #define LOAD_Z(buf, ks)                                                          \
    {                                                                                \
        const size_t o = (size_t)(R + lm) * HD_ + (ks) * 32 + lk8;                   \
        Ah[buf] = *reinterpret_cast<const bf16x8*>(&zh_c[o]);                        \
        Al[buf] = *reinterpret_cast<const bf16x8*>(&zl[o]);                          \
    }
    LOAD_Z(0, 0)
    LOAD_Z(1, 1)

    #pragma unroll
    for (int ks = 0; ks < 8; ++ks) {
        const int cur = ks & 1;
        const bf16x8 a_h = Ah[cur], a_l = Al[cur];
        if (ks < 6) LOAD_Z(cur, ks + 2)
        #pragma unroll
        for (int nf = 0; nf < 4; ++nf) {
            const int o = WT_IDX(nf * 16 + lm, ks * 32 + lk8);
            const bf16x8 b_h = *reinterpret_cast<const bf16x8*>(&WTh[o]);
            const bf16x8 b_l = *reinterpret_cast<const bf16x8*>(&WTl[o]);
            acc[nf] = __builtin_amdgcn_mfma_f32_16x16x32_bf16(a_h, b_h, acc[nf], 0, 0, 0);
            acc[nf] = __builtin_amdgcn_mfma_f32_16x16x32_bf16(a_h, b_l, acc[nf], 0, 0, 0);
            acc[nf] = __builtin_amdgcn_mfma_f32_16x16x32_bf16(a_l, b_h, acc[nf], 0, 0, 0);
        }
    }
    #undef LOAD_Z

    #pragma unroll
    for (int nf = 0; nf < 4; ++nf) {
        const int col = n0 + nf * 16 + lm;
        const float bb = bO[col];
        #pragma unroll
        for (int r = 0; r < 4; ++r) {
            const int m = R + cr + r;
            out[(size_t)m * HD_ + col] = acc[nf][r] + bb;
        }
    }
}

// ---------------------------------------------------------------------------
extern "C" void kernel_launch(void* const* d_in, const int* in_sizes, int n_in,
                              void* d_out, int out_size, void* d_ws, size_t ws_size,
                              hipStream_t stream)
{
    const float* qx = (const float*)d_in[0];
    const float* kx = (const float*)d_in[1];
    const float* vx = (const float*)d_in[2];
    const float* WQ = (const float*)d_in[3];
    const float* bQ = (const float*)d_in[4];
    const float* WK = (const float*)d_in[5];
    const float* bK = (const float*)d_in[6];
    const float* WV = (const float*)d_in[7];
    const float* bV = (const float*)d_in[8];
    const float* WO = (const float*)d_in[9];
    const float* bO = (const float*)d_in[10];
    float* out = (float*)d_out;

    char* wsb = (char*)d_ws;
    float*          q    = (float*)(wsb);                            // 4 MB
    float*          k    = (float*)(wsb + (4u  << 20));              // 4 MB
    float*          v    = (float*)(wsb + (8u  << 20));              // 4 MB
    unsigned short* zh   = (unsigned short*)(wsb + (12u << 20));     // 2 MB
    unsigned short* zl   = (unsigned short*)(wsb + (14u << 20));     // 2 MB
    float*          part = (float*)(wsb + (16u << 20));              // 32 KB
    float*          pm   = (float*)(wsb + (16u << 20) + (1u << 16)); // 512 f
    float*          pZ   = pm + 512;
    float*          pzv  = pm + 1024;                                // 16384 f

    gemm_qkv_fused<<<dim3(32, 12), 256, 0, stream>>>(qx, kx, vx, WQ, bQ, WK, bK, WV, bV, q, k, v, part);
    attn_main<<<768, 128, 0, stream>>>(q, k, v, part, pm, pZ, pzv, zh, zl);
    gemm_out_fused<<<dim3(64, 4), 256, 0, stream>>>(zh, zh, zl, pm, pZ, pzv, WO, bO, out);
}

// Round 15
// 35.161 us; speedup vs baseline: 5.2096x; 1.0408x over previous
//
#include <hip/hip_runtime.h>
#include <hip/hip_bf16.h>

#define B_   2
#define L_   2048
#define C_   256
#define H_   8
#define DK_  32
#define HD_  256
#define RSQRT_DK 0.17677669529663687f  // 1/sqrt(32)

typedef __attribute__((ext_vector_type(8))) short bf16x8;
typedef __attribute__((ext_vector_type(4))) float f32x4;
typedef __attribute__((ext_vector_type(4))) unsigned int u32x4;

__device__ __forceinline__ unsigned short f2bf(float x) {
    unsigned int u = __float_as_uint(x);
    u += 0x7fffu + ((u >> 16) & 1u);
    return (unsigned short)(u >> 16);
}
__device__ __forceinline__ float bf2f(unsigned short h) {
    return __uint_as_float((unsigned int)h << 16);
}

// Packed split-bf16 conversion: (x0,x1) -> {hi pair, lo pair} (each one u32
// of 2 bf16).  Uses __float22bfloat162_rn, which the compiler lowers to HW
// v_cvt_pk_bf16_f32 (RTNE — bit-identical to the manual f2bf path).
__device__ __forceinline__ uint2 split2(float x0, float x1) {
    __hip_bfloat162 h2 = __float22bfloat162_rn(make_float2(x0, x1));
    unsigned hu; __builtin_memcpy(&hu, &h2, 4);
    const float e0 = __uint_as_float(hu << 16);
    const float e1 = __uint_as_float(hu & 0xffff0000u);
    __hip_bfloat162 l2 = __float22bfloat162_rn(make_float2(x0 - e0, x1 - e1));
    unsigned lu; __builtin_memcpy(&lu, &l2, 4);
    return make_uint2(hu, lu);
}
__device__ __forceinline__ bf16x8 as_bf16x8(u32x4 v) {
    bf16x8 r; __builtin_memcpy(&r, &v, 16); return r;
}

// LDS weight-slice layout (per 64x256 plane of shorts): row pitch 256 shorts
// (uniform bank base), 16B-chunk XOR swizzle -> b128 reads/writes at bank floor.
#define WT_IDX(n, k) (((n) << 8) + (((((k) >> 3) ^ ((n) & 7))) << 3) + ((k) & 7))

// Stage W cols [n0, n0+63], k 0..255 from fp32 into LDS planes as split-bf16
// [n][k] via packed converts.  Layout identical to the prior short-wise fill.
__device__ __forceinline__ void stage_wT(
    const float* __restrict__ W, int n0, int tid,
    short* __restrict__ WTh, short* __restrict__ WTl)
{
    const int n  = tid & 63;
    const int kc = tid >> 6;           // 0..3
    #pragma unroll
    for (int c8 = 0; c8 < 8; ++c8) {
        const int k0 = kc * 64 + c8 * 8;
        u32x4 hv, lv;
        #pragma unroll
        for (int e = 0; e < 4; ++e) {
            const float x0 = W[(size_t)(k0 + 2 * e)     * HD_ + n0 + n];
            const float x1 = W[(size_t)(k0 + 2 * e + 1) * HD_ + n0 + n];
            const uint2 hl = split2(x0, x1);
            hv[e] = hl.x; lv[e] = hl.y;
        }
        const int o = (n << 8) + ((((k0 >> 3) ^ (n & 7))) << 3);
        *reinterpret_cast<u32x4*>(&WTh[o]) = hv;
        *reinterpret_cast<u32x4*>(&WTl[o]) = lv;
    }
}

// ---------------------------------------------------------------------------
// K1: QKV projection, split-bf16 MFMA, self-contained (W transpose+convert
// fused in LDS; A converted in-loop via packed cvt).  Grid (32, 12), 256 thr
// = 4 waves; block tile 128x64, wave tile 32x64.  Emits V col-sum partials.
// ---------------------------------------------------------------------------
__global__ __launch_bounds__(256) void gemm_qkv_fused(
    const float* __restrict__ qx, const float* __restrict__ kx, const float* __restrict__ vx,
    const float* __restrict__ WQ, const float* __restrict__ bQ,
    const float* __restrict__ WK, const float* __restrict__ bK,
    const float* __restrict__ WV, const float* __restrict__ bV,
    float* __restrict__ q, float* __restrict__ k, float* __restrict__ v,
    float* __restrict__ part)
{
    const int bx = blockIdx.x;          // 0..31
    const int yy = blockIdx.y;          // 0..11
    const int proj = yy >> 2, nt = yy & 3;
    const float* A    = proj == 0 ? qx : (proj == 1 ? kx : vx);
    const float* W    = proj == 0 ? WQ : (proj == 1 ? WK : WV);
    const float* bias = proj == 0 ? bQ : (proj == 1 ? bK : bV);
    float* out        = proj == 0 ? q  : (proj == 1 ? k  : v);
    const int n0 = nt * 64;

    __shared__ short WTh[64 * 256];
    __shared__ short WTl[64 * 256];
    __shared__ float red[4][4][16];

    const int tid = threadIdx.x;
    stage_wT(W, n0, tid, WTh, WTl);
    __syncthreads();

    const int w  = tid >> 6;            // wave 0..3
    const int l  = tid & 63;
    const int lm = l & 15, lk8 = (l >> 4) * 8, cr = (l >> 4) * 4;
    const int R  = bx * 128 + w * 32;

    f32x4 acc[2][4];
    #pragma unroll
    for (int mf = 0; mf < 2; ++mf)
        #pragma unroll
        for (int nf = 0; nf < 4; ++nf)
            acc[mf][nf] = (f32x4){0.f, 0.f, 0.f, 0.f};

    float4 Ab[2][4];
    #define LOAD_A(buf, ks)                                                          \
    {                                                                                \
        const float* p0 = &A[(size_t)(R + lm) * C_ + (ks) * 32 + lk8];               \
        const float* p1 = &A[(size_t)(R + 16 + lm) * C_ + (ks) * 32 + lk8];          \
        Ab[buf][0] = *reinterpret_cast<const float4*>(p0);                           \
        Ab[buf][1] = *reinterpret_cast<const float4*>(p0 + 4);                       \
        Ab[buf][2] = *reinterpret_cast<const float4*>(p1);                           \
        Ab[buf][3] = *reinterpret_cast<const float4*>(p1 + 4);                       \
    }
    LOAD_A(0, 0)
    LOAD_A(1, 1)

    #pragma unroll
    for (int ks = 0; ks < 8; ++ks) {
        const int cur = ks & 1;
        bf16x8 ah[2], al[2];
        #pragma unroll
        for (int mf = 0; mf < 2; ++mf) {
            float4 v0 = Ab[cur][mf * 2], v1 = Ab[cur][mf * 2 + 1];
            u32x4 hq, lq;
            {
                const uint2 r0 = split2(v0.x, v0.y);
                const uint2 r1 = split2(v0.z, v0.w);
                const uint2 r2 = split2(v1.x, v1.y);
                const uint2 r3 = split2(v1.z, v1.w);
                hq[0] = r0.x; lq[0] = r0.y;
                hq[1] = r1.x; lq[1] = r1.y;
                hq[2] = r2.x; lq[2] = r2.y;
                hq[3] = r3.x; lq[3] = r3.y;
            }
            ah[mf] = as_bf16x8(hq);
            al[mf] = as_bf16x8(lq);
        }
        if (ks < 6) LOAD_A(cur, ks + 2)
        bf16x8 Bh[4], Bl[4];
        #pragma unroll
        for (int nf = 0; nf < 4; ++nf) {
            const int o = WT_IDX(nf * 16 + lm, ks * 32 + lk8);
            Bh[nf] = *reinterpret_cast<const bf16x8*>(&WTh[o]);
            Bl[nf] = *reinterpret_cast<const bf16x8*>(&WTl[o]);
        }
        #pragma unroll
        for (int mf = 0; mf < 2; ++mf)
            #pragma unroll
            for (int nf = 0; nf < 4; ++nf) {
                acc[mf][nf] = __builtin_amdgcn_mfma_f32_16x16x32_bf16(ah[mf], Bh[nf], acc[mf][nf], 0, 0, 0);
                acc[mf][nf] = __builtin_amdgcn_mfma_f32_16x16x32_bf16(ah[mf], Bl[nf], acc[mf][nf], 0, 0, 0);
                acc[mf][nf] = __builtin_amdgcn_mfma_f32_16x16x32_bf16(al[mf], Bh[nf], acc[mf][nf], 0, 0, 0);
            }
    }
    #undef LOAD_A

    // epilogue: bias + scatter to (B,H,L,DK)
    #pragma unroll
    for (int mf = 0; mf < 2; ++mf)
        #pragma unroll
        for (int nf = 0; nf < 4; ++nf) {
            const int col = n0 + nf * 16 + lm;
            const int h = col >> 5, d = col & 31;
            const float bb = bias[col];
            #pragma unroll
            for (int r = 0; r < 4; ++r) {
                const int m = R + mf * 16 + cr + r;
                const int b = m >> 11, lrow = m & (L_ - 1);
                out[((size_t)(b * H_ + h) * L_ + lrow) * DK_ + d] = acc[mf][nf][r] + bb;
            }
        }

    // V column-sum partials (deterministic, per block = 128 rows x 64 cols)
    if (proj == 2) {
        float sl[4];
        #pragma unroll
        for (int nf = 0; nf < 4; ++nf) {
            float s = 0.f;
            #pragma unroll
            for (int mf = 0; mf < 2; ++mf)
                #pragma unroll
                for (int r = 0; r < 4; ++r) s += acc[mf][nf][r];
            s += __shfl_xor(s, 16);
            s += __shfl_xor(s, 32);
            sl[nf] = s;
        }
        if (l < 16) {
            #pragma unroll
            for (int nf = 0; nf < 4; ++nf) red[w][nf][l] = sl[nf];
        }
        __syncthreads();
        if (tid < 64) {
            const int nf = tid >> 4, lmm = tid & 15;
            float tot = red[0][nf][lmm] + red[1][nf][lmm] + red[2][nf][lmm] + red[3][nf][lmm];
            const int col = n0 + nf * 16 + lmm;
            tot += 128.f * bias[col];
            const int h = col >> 5, d = col & 31;
            const int bh = (bx >> 4) * H_ + h;       // block spans one b
            part[((size_t)bh * 32 + d) * 16 + (bx & 15)] = tot;
        }
    }
}

// ---------------------------------------------------------------------------
// K2: attention (round-13 structure; packed z-epilogue converts).
//  Blocks 0..255   : interior rows, ONE ROW PER LANE (bh = blk>>4, 128-row
//                    chunk = blk&15).  K+V staged in LDS via one fused loop;
//                    Q read direct from global.
//  Blocks 256..767 : global-row partials (bh, row-pair, 128-col chunk).
// 128 threads (2 waves) per block.  LDS 34 KB.
// ---------------------------------------------------------------------------
#define NSLOT 264            // 132 K + 132 V
#define VOFF  132

__global__ __launch_bounds__(128) void attn_main(
    const float* __restrict__ q, const float* __restrict__ k,
    const float* __restrict__ v, const float* __restrict__ part,
    float* __restrict__ pm, float* __restrict__ pZ, float* __restrict__ pzv,
    unsigned short* __restrict__ zh, unsigned short* __restrict__ zl)
{
    __shared__ float Sf[NSLOT * 32 + 32];
    float* vs_sh = &Sf[NSLOT * 32];

    // logical (slot, quad, elem) -> phys dword: slot*32 + ((quad ^ (slot&7))<<2) + elem
    #define LDS_F4(slot, u2) (*reinterpret_cast<const float4*>(&Sf[((slot) << 5) + (((u2) ^ ((slot) & 7)) << 2)]))

    const int blk = blockIdx.x;
    const int t = threadIdx.x;

    if (blk < 256) {
        // ----------------- interior rows, per-lane -----------------
        const int bh = blk >> 4, c = blk & 15;
        const int base = c * 128;                   // slot s (<130) = row base+s
        const float* qb = q + (size_t)bh * L_ * DK_;
        const float* kb = k + (size_t)bh * L_ * DK_;
        const float* vb = v + (size_t)bh * L_ * DK_;

        // fused K+V staging: 132 slots x 8 quads = 1056 units, 2 loads each
        for (int u = t; u < 1056; u += 128) {
            const int slot = u >> 3, quad = u & 7;
            const int row = (slot < 130) ? min(base + slot, L_ - 1)
                                         : ((slot == 130) ? 0 : L_ - 1);
            const size_t go = (size_t)row * DK_ + quad * 4;
            float4 kw = *reinterpret_cast<const float4*>(&kb[go]);
            float4 vw = *reinterpret_cast<const float4*>(&vb[go]);
            const int so = ((quad ^ (slot & 7)) << 2);
            float* dk = &Sf[(slot << 5) + so];
            float* dv = &Sf[((slot + VOFF) << 5) + (((quad ^ ((slot + VOFF) & 7))) << 2)];
            dk[0] = kw.x; dk[1] = kw.y; dk[2] = kw.z; dk[3] = kw.w;
            dv[0] = vw.x; dv[1] = vw.y; dv[2] = vw.z; dv[3] = vw.w;
        }
        if (t < 32) {
            const float4* pp = reinterpret_cast<const float4*>(&part[((size_t)bh * 32 + t) * 16]);
            float4 pa = pp[0], pb = pp[1], pc = pp[2], pd = pp[3];
            vs_sh[t] = pa.x + pa.y + pa.z + pa.w + pb.x + pb.y + pb.z + pb.w
                     + pc.x + pc.y + pc.z + pc.w + pd.x + pd.y + pd.z + pd.w;
        }
        __syncthreads();

        const int i = base + 1 + t;
        if (i <= L_ - 2) {
            // Q row read direct from global (zero reuse across threads)
            float qr[32];
            {
                const float4* qp = reinterpret_cast<const float4*>(&qb[(size_t)i * DK_]);
                #pragma unroll
                for (int u2 = 0; u2 < 8; ++u2) {
                    float4 x = qp[u2];
                    qr[u2 * 4 + 0] = x.x; qr[u2 * 4 + 1] = x.y;
                    qr[u2 * 4 + 2] = x.z; qr[u2 * 4 + 3] = x.w;
                }
            }
            const int ks_[5] = {130, t, t + 1, t + 2, 131};   // cols 0, i-1, i, i+1, L-1
            float sv[5];
            #pragma unroll
            for (int jj = 0; jj < 5; ++jj) {
                const int s = ks_[jj];
                float p = 0.f;
                #pragma unroll
                for (int u2 = 0; u2 < 8; ++u2) {
                    float4 kv = LDS_F4(s, u2);
                    p += qr[u2 * 4 + 0] * kv.x + qr[u2 * 4 + 1] * kv.y
                       + qr[u2 * 4 + 2] * kv.z + qr[u2 * 4 + 3] * kv.w;
                }
                sv[jj] = p * RSQRT_DK;
            }
            const bool v1 = (i != 1), v3 = (i != L_ - 2);
            float m = fmaxf(0.f, sv[0]);                 // zero fillers join the max
            m = fmaxf(m, sv[2]); m = fmaxf(m, sv[4]);
            if (v1) m = fmaxf(m, sv[1]);
            if (v3) m = fmaxf(m, sv[3]);
            float e[5];
            e[0] = __expf(sv[0] - m);
            e[1] = v1 ? __expf(sv[1] - m) : 0.f;
            e[2] = __expf(sv[2] - m);
            e[3] = v3 ? __expf(sv[3] - m) : 0.f;
            e[4] = __expf(sv[4] - m);
            const int ns = 3 + (int)v1 + (int)v3;
            const float e0 = __expf(-m);
            const float Z = e[0] + e[1] + e[2] + e[3] + e[4] + (float)(L_ - ns) * e0;
            const float rZ = 1.f / Z;
            const float f1 = v1 ? 1.f : 0.f, f3 = v3 ? 1.f : 0.f;

            u32x4 zhq[4], zlq[4];
            #pragma unroll
            for (int u2 = 0; u2 < 8; ++u2) {
                float4 x0 = LDS_F4(VOFF + 130,   u2);
                float4 x1 = LDS_F4(VOFF + t,     u2);
                float4 x2 = LDS_F4(VOFF + t + 1, u2);
                float4 x3 = LDS_F4(VOFF + t + 2, u2);
                float4 x4 = LDS_F4(VOFF + 131,   u2);
                float a0[4] = {x0.x, x0.y, x0.z, x0.w};
                float a1[4] = {x1.x, x1.y, x1.z, x1.w};
                float a2[4] = {x2.x, x2.y, x2.z, x2.w};
                float a3[4] = {x3.x, x3.y, x3.z, x3.w};
                float a4[4] = {x4.x, x4.y, x4.z, x4.w};
                float zd4[4];
                #pragma unroll
                for (int e2 = 0; e2 < 4; ++e2) {
                    const int d = u2 * 4 + e2;
                    const float num = e[0] * a0[e2] + e[1] * a1[e2] + e[2] * a2[e2]
                                    + e[3] * a3[e2] + e[4] * a4[e2];
                    const float vp = a0[e2] + f1 * a1[e2] + a2[e2] + f3 * a3[e2] + a4[e2];
                    zd4[e2] = (num + e0 * (vs_sh[d] - vp)) * rZ;
                }
                const uint2 p0 = split2(zd4[0], zd4[1]);
                const uint2 p1 = split2(zd4[2], zd4[3]);
                zhq[u2 >> 1][(u2 & 1) * 2 + 0] = p0.x;
                zhq[u2 >> 1][(u2 & 1) * 2 + 1] = p1.x;
                zlq[u2 >> 1][(u2 & 1) * 2 + 0] = p0.y;
                zlq[u2 >> 1][(u2 & 1) * 2 + 1] = p1.y;
            }
            const int b = bh >> 3, h = bh & 7;
            const size_t o = (size_t)(b * L_ + i) * HD_ + h * DK_;
            #pragma unroll
            for (int u4 = 0; u4 < 4; ++u4) {
                *reinterpret_cast<u32x4*>(&zh[o + u4 * 8]) = zhq[u4];
                *reinterpret_cast<u32x4*>(&zl[o + u4 * 8]) = zlq[u4];
            }
        }
    } else {
        // ----------------- global-row partials -----------------
        const int blk2 = blk - 256;                 // 0..511
        const int bh = blk2 >> 5;
        const int pair = (blk2 >> 4) & 1;
        const int chunk = blk2 & 15;
        const int r = pair ? (L_ - 1) : 0;
        const int j0 = chunk * 128;
        const float* qb = q + (size_t)bh * L_ * DK_;
        const float* kb = k + (size_t)bh * L_ * DK_;
        const float* vb = v + (size_t)bh * L_ * DK_;

        float* qs  = Sf;          // 32
        float* sc  = Sf + 32;     // 128
        float* red = Sf + 160;    // 4
        float* pzs = Sf + 192;    // 128

        if (t < 32) qs[t] = qb[(size_t)r * DK_ + t];
        __syncthreads();

        const int j = j0 + t;
        const float4* kr = reinterpret_cast<const float4*>(&kb[(size_t)j * DK_]);
        float p = 0.f;
        #pragma unroll
        for (int u = 0; u < 8; ++u) {
            float4 kv = kr[u];
            p += qs[u * 4 + 0] * kv.x + qs[u * 4 + 1] * kv.y
               + qs[u * 4 + 2] * kv.z + qs[u * 4 + 3] * kv.w;
        }
        p *= RSQRT_DK;

        float lm = p;
        #pragma unroll
        for (int off = 32; off; off >>= 1) lm = fmaxf(lm, __shfl_xor(lm, off, 64));
        if ((t & 63) == 0) red[t >> 6] = lm;
        __syncthreads();
        const float m = fmaxf(red[0], red[1]);

        const float e = __expf(p - m);
        sc[t] = e;
        float ls = e;
        #pragma unroll
        for (int off = 32; off; off >>= 1) ls += __shfl_xor(ls, off, 64);
        if ((t & 63) == 0) red[2 + (t >> 6)] = ls;
        __syncthreads();
        const float Zc = red[2] + red[3];

        const int d = t & 31, g = t >> 5;
        float acc = 0.f;
        #pragma unroll 4
        for (int jj = 0; jj < 32; ++jj)
            acc += sc[g * 32 + jj] * vb[(size_t)(j0 + g * 32 + jj) * DK_ + d];
        pzs[g * 32 + d] = acc;
        __syncthreads();
        if (g == 0) {
            const float s2 = pzs[d] + pzs[32 + d] + pzs[64 + d] + pzs[96 + d];
            pzv[(size_t)blk2 * 32 + d] = s2;
        }
        if (t == 0) { pm[blk2] = m; pZ[blk2] = Zc; }
    }
    #undef LDS_F4
}

// ---------------------------------------------------------------------------
// K3: out = z @ WO + bO via split-bf16 MFMA, self-contained (WO transpose+
// convert fused in LDS) + INLINE global-row combine (round-12 structure).
// Grid (64, 4), 256 thr = 4 waves; block tile 64x64, wave tile 16x64.
// ---------------------------------------------------------------------------
__global__ __launch_bounds__(256) void gemm_out_fused(
    const unsigned short* __restrict__ zh_c, unsigned short* __restrict__ zh,
    unsigned short* __restrict__ zl,
    const float* __restrict__ pm, const float* __restrict__ pZ,
    const float* __restrict__ pzv,
    const float* __restrict__ WO, const float* __restrict__ bO,
    float* __restrict__ out)
{
    const int bx = blockIdx.x;          // 0..63
    const int nt = blockIdx.y;          // 0..3
    const int n0 = nt * 64;

    __shared__ short WTh[64 * 256];
    __shared__ short WTl[64 * 256];

    const int tid = threadIdx.x;
    stage_wT(WO, n0, tid, WTh, WTl);

    // inline combine of global-row partials (was attn_g2_kernel)
    int zrow = -1;
    if      (bx == 0)  zrow = 0;
    else if (bx == 31) zrow = L_ - 1;
    else if (bx == 32) zrow = L_;
    else if (bx == 63) zrow = 2 * L_ - 1;
    if (zrow >= 0) {
        const int h = tid >> 5, d = tid & 31;
        const int b = zrow >> 11;
        const int r = zrow & (L_ - 1);
        const int pair = r ? 1 : 0;
        const int rowIdx = (b * H_ + h) * 2 + pair;
        const int base = rowIdx * 16;
        float m = -1e30f;
        #pragma unroll
        for (int c = 0; c < 16; ++c) m = fmaxf(m, pm[base + c]);
        float Z = 0.f, zd = 0.f;
        #pragma unroll
        for (int c = 0; c < 16; ++c) {
            const float w2 = __expf(pm[base + c] - m);
            Z  += pZ[base + c] * w2;
            zd += pzv[(size_t)(base + c) * 32 + d] * w2;
        }
        zd /= Z;
        const size_t o = (size_t)zrow * HD_ + h * DK_ + d;
        const unsigned short hb = f2bf(zd);
        zh[o] = hb;
        zl[o] = f2bf(zd - bf2f(hb));
    }
    __syncthreads();   // drains vmcnt: z stores complete before LOAD_Z below

    const int w  = tid >> 6;
    const int l  = tid & 63;
    const int lm = l & 15, lk8 = (l >> 4) * 8, cr = (l >> 4) * 4;
    const int R  = bx * 64 + w * 16;

    f32x4 acc[4];
    #pragma unroll
    for (int nf = 0; nf < 4; ++nf) acc[nf] = (f32x4){0.f, 0.f, 0.f, 0.f};

    bf16x8 Ah[2], Al[2];
    #define LOAD_Z(buf, ks)                                                          \
    {                                                                                \
        const size_t o = (size_t)(R + lm) * HD_ + (ks) * 32 + lk8;                   \
        Ah[buf] = *reinterpret_cast<const bf16x8*>(&zh_c[o]);                        \
        Al[buf] = *reinterpret_cast<const bf16x8*>(&zl[o]);                          \
    }
    LOAD_Z(0, 0)
    LOAD_Z(1, 1)

    #pragma unroll
    for (int ks = 0; ks < 8; ++ks) {
        const int cur = ks & 1;
        const bf16x8 a_h = Ah[cur], a_l = Al[cur];
        if (ks < 6) LOAD_Z(cur, ks + 2)
        #pragma unroll
        for (int nf = 0; nf < 4; ++nf) {
            const int o = WT_IDX(nf * 16 + lm, ks * 32 + lk8);
            const bf16x8 b_h = *reinterpret_cast<const bf16x8*>(&WTh[o]);
            const bf16x8 b_l = *reinterpret_cast<const bf16x8*>(&WTl[o]);
            acc[nf] = __builtin_amdgcn_mfma_f32_16x16x32_bf16(a_h, b_h, acc[nf], 0, 0, 0);
            acc[nf] = __builtin_amdgcn_mfma_f32_16x16x32_bf16(a_h, b_l, acc[nf], 0, 0, 0);
            acc[nf] = __builtin_amdgcn_mfma_f32_16x16x32_bf16(a_l, b_h, acc[nf], 0, 0, 0);
        }
    }
    #undef LOAD_Z

    #pragma unroll
    for (int nf = 0; nf < 4; ++nf) {
        const int col = n0 + nf * 16 + lm;
        const float bb = bO[col];
        #pragma unroll
        for (int r = 0; r < 4; ++r) {
            const int m = R + cr + r;
            out[(size_t)m * HD_ + col] = acc[nf][r] + bb;
        }
    }
}

// ---------------------------------------------------------------------------
extern "C" void kernel_launch(void* const* d_in, const int* in_sizes, int n_in,
                              void* d_out, int out_size, void* d_ws, size_t ws_size,
                              hipStream_t stream)
{
    const float* qx = (const float*)d_in[0];
    const float* kx = (const float*)d_in[1];
    const float* vx = (const float*)d_in[2];
    const float* WQ = (const float*)d_in[3];
    const float* bQ = (const float*)d_in[4];
    const float* WK = (const float*)d_in[5];
    const float* bK = (const float*)d_in[6];
    const float* WV = (const float*)d_in[7];
    const float* bV = (const float*)d_in[8];
    const float* WO = (const float*)d_in[9];
    const float* bO = (const float*)d_in[10];
    float* out = (float*)d_out;

    char* wsb = (char*)d_ws;
    float*          q    = (float*)(wsb);                            // 4 MB
    float*          k    = (float*)(wsb + (4u  << 20));              // 4 MB
    float*          v    = (float*)(wsb + (8u  << 20));              // 4 MB
    unsigned short* zh   = (unsigned short*)(wsb + (12u << 20));     // 2 MB
    unsigned short* zl   = (unsigned short*)(wsb + (14u << 20));     // 2 MB
    float*          part = (float*)(wsb + (16u << 20));              // 32 KB
    float*          pm   = (float*)(wsb + (16u << 20) + (1u << 16)); // 512 f
    float*          pZ   = pm + 512;
    float*          pzv  = pm + 1024;                                // 16384 f

    gemm_qkv_fused<<<dim3(32, 12), 256, 0, stream>>>(qx, kx, vx, WQ, bQ, WK, bK, WV, bV, q, k, v, part);
    attn_main<<<768, 128, 0, stream>>>(q, k, v, part, pm, pZ, pzv, zh, zl);
    gemm_out_fused<<<dim3(64, 4), 256, 0, stream>>>(zh, zh, zl, pm, pZ, pzv, WO, bO, out);
}

// Round 16
// 33.849 us; speedup vs baseline: 5.4116x; 1.0388x over previous
//
#include <hip/hip_runtime.h>
#include <hip/hip_bf16.h>

#define B_   2
#define L_   2048
#define C_   256
#define H_   8
#define DK_  32
#define HD_  256
#define RSQRT_DK 0.17677669529663687f  // 1/sqrt(32)

typedef __attribute__((ext_vector_type(8))) short bf16x8;
typedef __attribute__((ext_vector_type(4))) float f32x4;
typedef __attribute__((ext_vector_type(4))) unsigned int u32x4;

__device__ __forceinline__ unsigned short f2bf(float x) {
    unsigned int u = __float_as_uint(x);
    u += 0x7fffu + ((u >> 16) & 1u);
    return (unsigned short)(u >> 16);
}
__device__ __forceinline__ float bf2f(unsigned short h) {
    return __uint_as_float((unsigned int)h << 16);
}

// Packed split-bf16 conversion: (x0,x1) -> {hi pair, lo pair} (each one u32
// of 2 bf16).  __float22bfloat162_rn lowers to HW v_cvt_pk_bf16_f32 (RTNE —
// bit-identical to the manual f2bf path).
__device__ __forceinline__ uint2 split2(float x0, float x1) {
    __hip_bfloat162 h2 = __float22bfloat162_rn(make_float2(x0, x1));
    unsigned hu; __builtin_memcpy(&hu, &h2, 4);
    const float e0 = __uint_as_float(hu << 16);
    const float e1 = __uint_as_float(hu & 0xffff0000u);
    __hip_bfloat162 l2 = __float22bfloat162_rn(make_float2(x0 - e0, x1 - e1));
    unsigned lu; __builtin_memcpy(&lu, &l2, 4);
    return make_uint2(hu, lu);
}
__device__ __forceinline__ bf16x8 as_bf16x8(u32x4 v) {
    bf16x8 r; __builtin_memcpy(&r, &v, 16); return r;
}

// LDS weight-slice layout (per 64x256 plane of shorts): row pitch 256 shorts
// (uniform bank base), 16B-chunk XOR swizzle -> b128 reads/writes at bank floor.
#define WT_IDX(n, k) (((n) << 8) + (((((k) >> 3) ^ ((n) & 7))) << 3) + ((k) & 7))

// Stage W cols [n0, n0+63], k 0..255 from fp32 into LDS planes as split-bf16
// [n][k] via packed converts.  (used by K1 for its own W slice)
__device__ __forceinline__ void stage_wT(
    const float* __restrict__ W, int n0, int tid,
    short* __restrict__ WTh, short* __restrict__ WTl)
{
    const int n  = tid & 63;
    const int kc = tid >> 6;           // 0..3
    #pragma unroll
    for (int c8 = 0; c8 < 8; ++c8) {
        const int k0 = kc * 64 + c8 * 8;
        u32x4 hv, lv;
        #pragma unroll
        for (int e = 0; e < 4; ++e) {
            const float x0 = W[(size_t)(k0 + 2 * e)     * HD_ + n0 + n];
            const float x1 = W[(size_t)(k0 + 2 * e + 1) * HD_ + n0 + n];
            const uint2 hl = split2(x0, x1);
            hv[e] = hl.x; lv[e] = hl.y;
        }
        const int o = (n << 8) + ((((k0 >> 3) ^ (n & 7))) << 3);
        *reinterpret_cast<u32x4*>(&WTh[o]) = hv;
        *reinterpret_cast<u32x4*>(&WTl[o]) = lv;
    }
}

// Copy a pre-converted 64-col weight slice (cols n0..n0+63, k 0..255) from
// global wT (hi at [n*256+k], lo at +65536) into swizzled LDS.  Pure
// coalesced bf16x8 copy — measured 0.9us K3 variant (round 10).
__device__ __forceinline__ void stage_wT_copy(
    const unsigned short* __restrict__ wTp, int n0, int tid,
    short* __restrict__ WTh, short* __restrict__ WTl)
{
    #pragma unroll
    for (int it = 0; it < 8; ++it) {
        const int c = tid + it * 256;      // chunk 0..2047
        const int n = c >> 5, k8 = c & 31;
        const size_t go = (size_t)(n0 + n) * 256 + k8 * 8;
        const int o = (n << 8) + ((k8 ^ (n & 7)) << 3);
        *reinterpret_cast<bf16x8*>(&WTh[o]) = *reinterpret_cast<const bf16x8*>(&wTp[go]);
        *reinterpret_cast<bf16x8*>(&WTl[o]) = *reinterpret_cast<const bf16x8*>(&wTp[65536 + go]);
    }
}

// ---------------------------------------------------------------------------
// K1: QKV projection, split-bf16 MFMA, self-contained.  Grid (32, 13):
//  yy 0..11 : proj*4 + nt GEMM blocks (128x64 tile, 4 waves), V col-sums.
//  yy 12    : 32 blocks convert WO (fp32 [k][n]) -> global wT split-bf16
//             [n][k] planes for K3 (one-time, deduplicated, co-scheduled).
// ---------------------------------------------------------------------------
__global__ __launch_bounds__(256) void gemm_qkv_fused(
    const float* __restrict__ qx, const float* __restrict__ kx, const float* __restrict__ vx,
    const float* __restrict__ WQ, const float* __restrict__ bQ,
    const float* __restrict__ WK, const float* __restrict__ bK,
    const float* __restrict__ WV, const float* __restrict__ bV,
    const float* __restrict__ WO, unsigned short* __restrict__ wT,
    float* __restrict__ q, float* __restrict__ k, float* __restrict__ v,
    float* __restrict__ part)
{
    const int bx = blockIdx.x;          // 0..31
    const int yy = blockIdx.y;          // 0..12
    const int tid = threadIdx.x;

    if (yy == 12) {
        // WO -> wT conversion: n = bx*8 + (tid>>5), k-chunk = (tid&31)*8
        const int n  = bx * 8 + (tid >> 5);
        const int k8 = (tid & 31) * 8;
        u32x4 hv, lv;
        #pragma unroll
        for (int e = 0; e < 4; ++e) {
            const float x0 = WO[(size_t)(k8 + 2 * e)     * HD_ + n];
            const float x1 = WO[(size_t)(k8 + 2 * e + 1) * HD_ + n];
            const uint2 hl = split2(x0, x1);
            hv[e] = hl.x; lv[e] = hl.y;
        }
        *reinterpret_cast<u32x4*>(&wT[(size_t)n * 256 + k8])         = hv;
        *reinterpret_cast<u32x4*>(&wT[65536 + (size_t)n * 256 + k8]) = lv;
        return;
    }

    const int proj = yy >> 2, nt = yy & 3;
    const float* A    = proj == 0 ? qx : (proj == 1 ? kx : vx);
    const float* W    = proj == 0 ? WQ : (proj == 1 ? WK : WV);
    const float* bias = proj == 0 ? bQ : (proj == 1 ? bK : bV);
    float* out        = proj == 0 ? q  : (proj == 1 ? k  : v);
    const int n0 = nt * 64;

    __shared__ short WTh[64 * 256];
    __shared__ short WTl[64 * 256];
    __shared__ float red[4][4][16];

    stage_wT(W, n0, tid, WTh, WTl);
    __syncthreads();

    const int w  = tid >> 6;            // wave 0..3
    const int l  = tid & 63;
    const int lm = l & 15, lk8 = (l >> 4) * 8, cr = (l >> 4) * 4;
    const int R  = bx * 128 + w * 32;

    f32x4 acc[2][4];
    #pragma unroll
    for (int mf = 0; mf < 2; ++mf)
        #pragma unroll
        for (int nf = 0; nf < 4; ++nf)
            acc[mf][nf] = (f32x4){0.f, 0.f, 0.f, 0.f};

    float4 Ab[2][4];
    #define LOAD_A(buf, ks)                                                          \
    {                                                                                \
        const float* p0 = &A[(size_t)(R + lm) * C_ + (ks) * 32 + lk8];               \
        const float* p1 = &A[(size_t)(R + 16 + lm) * C_ + (ks) * 32 + lk8];          \
        Ab[buf][0] = *reinterpret_cast<const float4*>(p0);                           \
        Ab[buf][1] = *reinterpret_cast<const float4*>(p0 + 4);                       \
        Ab[buf][2] = *reinterpret_cast<const float4*>(p1);                           \
        Ab[buf][3] = *reinterpret_cast<const float4*>(p1 + 4);                       \
    }
    LOAD_A(0, 0)
    LOAD_A(1, 1)

    #pragma unroll
    for (int ks = 0; ks < 8; ++ks) {
        const int cur = ks & 1;
        bf16x8 ah[2], al[2];
        #pragma unroll
        for (int mf = 0; mf < 2; ++mf) {
            float4 v0 = Ab[cur][mf * 2], v1 = Ab[cur][mf * 2 + 1];
            u32x4 hq, lq;
            {
                const uint2 r0 = split2(v0.x, v0.y);
                const uint2 r1 = split2(v0.z, v0.w);
                const uint2 r2 = split2(v1.x, v1.y);
                const uint2 r3 = split2(v1.z, v1.w);
                hq[0] = r0.x; lq[0] = r0.y;
                hq[1] = r1.x; lq[1] = r1.y;
                hq[2] = r2.x; lq[2] = r2.y;
                hq[3] = r3.x; lq[3] = r3.y;
            }
            ah[mf] = as_bf16x8(hq);
            al[mf] = as_bf16x8(lq);
        }
        if (ks < 6) LOAD_A(cur, ks + 2)
        bf16x8 Bh[4], Bl[4];
        #pragma unroll
        for (int nf = 0; nf < 4; ++nf) {
            const int o = WT_IDX(nf * 16 + lm, ks * 32 + lk8);
            Bh[nf] = *reinterpret_cast<const bf16x8*>(&WTh[o]);
            Bl[nf] = *reinterpret_cast<const bf16x8*>(&WTl[o]);
        }
        #pragma unroll
        for (int mf = 0; mf < 2; ++mf)
            #pragma unroll
            for (int nf = 0; nf < 4; ++nf) {
                acc[mf][nf] = __builtin_amdgcn_mfma_f32_16x16x32_bf16(ah[mf], Bh[nf], acc[mf][nf], 0, 0, 0);
                acc[mf][nf] = __builtin_amdgcn_mfma_f32_16x16x32_bf16(ah[mf], Bl[nf], acc[mf][nf], 0, 0, 0);
                acc[mf][nf] = __builtin_amdgcn_mfma_f32_16x16x32_bf16(al[mf], Bh[nf], acc[mf][nf], 0, 0, 0);
            }
    }
    #undef LOAD_A

    // epilogue: bias + scatter to (B,H,L,DK)
    #pragma unroll
    for (int mf = 0; mf < 2; ++mf)
        #pragma unroll
        for (int nf = 0; nf < 4; ++nf) {
            const int col = n0 + nf * 16 + lm;
            const int h = col >> 5, d = col & 31;
            const float bb = bias[col];
            #pragma unroll
            for (int r = 0; r < 4; ++r) {
                const int m = R + mf * 16 + cr + r;
                const int b = m >> 11, lrow = m & (L_ - 1);
                out[((size_t)(b * H_ + h) * L_ + lrow) * DK_ + d] = acc[mf][nf][r] + bb;
            }
        }

    // V column-sum partials (deterministic, per block = 128 rows x 64 cols)
    if (proj == 2) {
        float sl[4];
        #pragma unroll
        for (int nf = 0; nf < 4; ++nf) {
            float s = 0.f;
            #pragma unroll
            for (int mf = 0; mf < 2; ++mf)
                #pragma unroll
                for (int r = 0; r < 4; ++r) s += acc[mf][nf][r];
            s += __shfl_xor(s, 16);
            s += __shfl_xor(s, 32);
            sl[nf] = s;
        }
        if (l < 16) {
            #pragma unroll
            for (int nf = 0; nf < 4; ++nf) red[w][nf][l] = sl[nf];
        }
        __syncthreads();
        if (tid < 64) {
            const int nf = tid >> 4, lmm = tid & 15;
            float tot = red[0][nf][lmm] + red[1][nf][lmm] + red[2][nf][lmm] + red[3][nf][lmm];
            const int col = n0 + nf * 16 + lmm;
            tot += 128.f * bias[col];
            const int h = col >> 5, d = col & 31;
            const int bh = (bx >> 4) * H_ + h;       // block spans one b
            part[((size_t)bh * 32 + d) * 16 + (bx & 15)] = tot;
        }
    }
}

// ---------------------------------------------------------------------------
// K2: attention.
//  Blocks 0..255   : interior rows, ONE ROW PER LANE, fully DIRECT loads
//                    (Q/K/V from L1/L2 — band rows have 3x in-wave reuse,
//                    rows 0/2047 broadcast).  Only LDS: 32-float vsum.
//  Blocks 256..767 : global-row partials (bh, row-pair, 128-col chunk).
// 128 threads (2 waves) per block.  LDS ~1.3 KB -> high occupancy.
// ---------------------------------------------------------------------------
__global__ __launch_bounds__(128) void attn_main(
    const float* __restrict__ q, const float* __restrict__ k,
    const float* __restrict__ v, const float* __restrict__ part,
    float* __restrict__ pm, float* __restrict__ pZ, float* __restrict__ pzv,
    unsigned short* __restrict__ zh, unsigned short* __restrict__ zl)
{
    __shared__ float Sf[324];

    const int blk = blockIdx.x;
    const int t = threadIdx.x;

    if (blk < 256) {
        // ----------------- interior rows, per-lane, direct -----------------
        const int bh = blk >> 4, c = blk & 15;
        const int base = c * 128;
        const float* qb = q + (size_t)bh * L_ * DK_;
        const float* kb = k + (size_t)bh * L_ * DK_;
        const float* vb = v + (size_t)bh * L_ * DK_;
        float* vs_sh = Sf;

        if (t < 32) {
            const float4* pp = reinterpret_cast<const float4*>(&part[((size_t)bh * 32 + t) * 16]);
            float4 pa = pp[0], pb = pp[1], pc = pp[2], pd = pp[3];
            vs_sh[t] = pa.x + pa.y + pa.z + pa.w + pb.x + pb.y + pb.z + pb.w
                     + pc.x + pc.y + pc.z + pc.w + pd.x + pd.y + pd.z + pd.w;
        }
        __syncthreads();

        const int i = base + 1 + t;
        if (i <= L_ - 2) {
            float qr[32];
            {
                const float4* qp = reinterpret_cast<const float4*>(&qb[(size_t)i * DK_]);
                #pragma unroll
                for (int u2 = 0; u2 < 8; ++u2) {
                    float4 x = qp[u2];
                    qr[u2 * 4 + 0] = x.x; qr[u2 * 4 + 1] = x.y;
                    qr[u2 * 4 + 2] = x.z; qr[u2 * 4 + 3] = x.w;
                }
            }
            const int rows[5] = {0, i - 1, i, i + 1, L_ - 1};
            float sv[5];
            #pragma unroll
            for (int jj = 0; jj < 5; ++jj) {
                const float4* kp = reinterpret_cast<const float4*>(&kb[(size_t)rows[jj] * DK_]);
                float p = 0.f;
                #pragma unroll
                for (int u2 = 0; u2 < 8; ++u2) {
                    float4 kv = kp[u2];
                    p += qr[u2 * 4 + 0] * kv.x + qr[u2 * 4 + 1] * kv.y
                       + qr[u2 * 4 + 2] * kv.z + qr[u2 * 4 + 3] * kv.w;
                }
                sv[jj] = p * RSQRT_DK;
            }
            const bool v1 = (i != 1), v3 = (i != L_ - 2);
            float m = fmaxf(0.f, sv[0]);                 // zero fillers join the max
            m = fmaxf(m, sv[2]); m = fmaxf(m, sv[4]);
            if (v1) m = fmaxf(m, sv[1]);
            if (v3) m = fmaxf(m, sv[3]);
            float e[5];
            e[0] = __expf(sv[0] - m);
            e[1] = v1 ? __expf(sv[1] - m) : 0.f;
            e[2] = __expf(sv[2] - m);
            e[3] = v3 ? __expf(sv[3] - m) : 0.f;
            e[4] = __expf(sv[4] - m);
            const int ns = 3 + (int)v1 + (int)v3;
            const float e0 = __expf(-m);
            const float Z = e[0] + e[1] + e[2] + e[3] + e[4] + (float)(L_ - ns) * e0;
            const float rZ = 1.f / Z;
            const float f1 = v1 ? 1.f : 0.f, f3 = v3 ? 1.f : 0.f;

            const float4* vp0 = reinterpret_cast<const float4*>(&vb[0]);
            const float4* vp1 = reinterpret_cast<const float4*>(&vb[(size_t)rows[1] * DK_]);
            const float4* vp2 = reinterpret_cast<const float4*>(&vb[(size_t)i * DK_]);
            const float4* vp3 = reinterpret_cast<const float4*>(&vb[(size_t)rows[3] * DK_]);
            const float4* vp4 = reinterpret_cast<const float4*>(&vb[(size_t)(L_ - 1) * DK_]);

            u32x4 zhq[4], zlq[4];
            #pragma unroll
            for (int u2 = 0; u2 < 8; ++u2) {
                float4 x0 = vp0[u2], x1 = vp1[u2], x2 = vp2[u2], x3 = vp3[u2], x4 = vp4[u2];
                float a0[4] = {x0.x, x0.y, x0.z, x0.w};
                float a1[4] = {x1.x, x1.y, x1.z, x1.w};
                float a2[4] = {x2.x, x2.y, x2.z, x2.w};
                float a3[4] = {x3.x, x3.y, x3.z, x3.w};
                float a4[4] = {x4.x, x4.y, x4.z, x4.w};
                float zd4[4];
                #pragma unroll
                for (int e2 = 0; e2 < 4; ++e2) {
                    const int d = u2 * 4 + e2;
                    const float num = e[0] * a0[e2] + e[1] * a1[e2] + e[2] * a2[e2]
                                    + e[3] * a3[e2] + e[4] * a4[e2];
                    const float vp_ = a0[e2] + f1 * a1[e2] + a2[e2] + f3 * a3[e2] + a4[e2];
                    zd4[e2] = (num + e0 * (vs_sh[d] - vp_)) * rZ;
                }
                const uint2 p0 = split2(zd4[0], zd4[1]);
                const uint2 p1 = split2(zd4[2], zd4[3]);
                zhq[u2 >> 1][(u2 & 1) * 2 + 0] = p0.x;
                zhq[u2 >> 1][(u2 & 1) * 2 + 1] = p1.x;
                zlq[u2 >> 1][(u2 & 1) * 2 + 0] = p0.y;
                zlq[u2 >> 1][(u2 & 1) * 2 + 1] = p1.y;
            }
            const int b = bh >> 3, h = bh & 7;
            const size_t o = (size_t)(b * L_ + i) * HD_ + h * DK_;
            #pragma unroll
            for (int u4 = 0; u4 < 4; ++u4) {
                *reinterpret_cast<u32x4*>(&zh[o + u4 * 8]) = zhq[u4];
                *reinterpret_cast<u32x4*>(&zl[o + u4 * 8]) = zlq[u4];
            }
        }
    } else {
        // ----------------- global-row partials -----------------
        const int blk2 = blk - 256;                 // 0..511
        const int bh = blk2 >> 5;
        const int pair = (blk2 >> 4) & 1;
        const int chunk = blk2 & 15;
        const int r = pair ? (L_ - 1) : 0;
        const int j0 = chunk * 128;
        const float* qb = q + (size_t)bh * L_ * DK_;
        const float* kb = k + (size_t)bh * L_ * DK_;
        const float* vb = v + (size_t)bh * L_ * DK_;

        float* qs  = Sf;          // 32
        float* sc  = Sf + 32;     // 128
        float* red = Sf + 160;    // 4
        float* pzs = Sf + 192;    // 128

        if (t < 32) qs[t] = qb[(size_t)r * DK_ + t];
        __syncthreads();

        const int j = j0 + t;
        const float4* kr = reinterpret_cast<const float4*>(&kb[(size_t)j * DK_]);
        float p = 0.f;
        #pragma unroll
        for (int u = 0; u < 8; ++u) {
            float4 kv = kr[u];
            p += qs[u * 4 + 0] * kv.x + qs[u * 4 + 1] * kv.y
               + qs[u * 4 + 2] * kv.z + qs[u * 4 + 3] * kv.w;
        }
        p *= RSQRT_DK;

        float lm = p;
        #pragma unroll
        for (int off = 32; off; off >>= 1) lm = fmaxf(lm, __shfl_xor(lm, off, 64));
        if ((t & 63) == 0) red[t >> 6] = lm;
        __syncthreads();
        const float m = fmaxf(red[0], red[1]);

        const float e = __expf(p - m);
        sc[t] = e;
        float ls = e;
        #pragma unroll
        for (int off = 32; off; off >>= 1) ls += __shfl_xor(ls, off, 64);
        if ((t & 63) == 0) red[2 + (t >> 6)] = ls;
        __syncthreads();
        const float Zc = red[2] + red[3];

        const int d = t & 31, g = t >> 5;
        float acc = 0.f;
        #pragma unroll 4
        for (int jj = 0; jj < 32; ++jj)
            acc += sc[g * 32 + jj] * vb[(size_t)(j0 + g * 32 + jj) * DK_ + d];
        pzs[g * 32 + d] = acc;
        __syncthreads();
        if (g == 0) {
            const float s2 = pzs[d] + pzs[32 + d] + pzs[64 + d] + pzs[96 + d];
            pzv[(size_t)blk2 * 32 + d] = s2;
        }
        if (t == 0) { pm[blk2] = m; pZ[blk2] = Zc; }
    }
}

// ---------------------------------------------------------------------------
// K3: out = z @ WO + bO via split-bf16 MFMA; WO slice COPIED pre-converted
// from global wT (0.9us variant, round-10 measured) + INLINE global-row
// combine.  Grid (64, 4), 256 thr = 4 waves; block tile 64x64.
// ---------------------------------------------------------------------------
__global__ __launch_bounds__(256) void gemm_out_fused(
    const unsigned short* __restrict__ zh_c, unsigned short* __restrict__ zh,
    unsigned short* __restrict__ zl,
    const float* __restrict__ pm, const float* __restrict__ pZ,
    const float* __restrict__ pzv,
    const unsigned short* __restrict__ wT, const float* __restrict__ bO,
    float* __restrict__ out)
{
    const int bx = blockIdx.x;          // 0..63
    const int nt = blockIdx.y;          // 0..3
    const int n0 = nt * 64;

    __shared__ short WTh[64 * 256];
    __shared__ short WTl[64 * 256];

    const int tid = threadIdx.x;
    stage_wT_copy(wT, n0, tid, WTh, WTl);

    // inline combine of global-row partials (was attn_g2_kernel)
    int zrow = -1;
    if      (bx == 0)  zrow = 0;
    else if (bx == 31) zrow = L_ - 1;
    else if (bx == 32) zrow = L_;
    else if (bx == 63) zrow = 2 * L_ - 1;
    if (zrow >= 0) {
        const int h = tid >> 5, d = tid & 31;
        const int b = zrow >> 11;
        const int r = zrow & (L_ - 1);
        const int pair = r ? 1 : 0;
        const int rowIdx = (b * H_ + h) * 2 + pair;
        const int base = rowIdx * 16;
        float m = -1e30f;
        #pragma unroll
        for (int c = 0; c < 16; ++c) m = fmaxf(m, pm[base + c]);
        float Z = 0.f, zd = 0.f;
        #pragma unroll
        for (int c = 0; c < 16; ++c) {
            const float w2 = __expf(pm[base + c] - m);
            Z  += pZ[base + c] * w2;
            zd += pzv[(size_t)(base + c) * 32 + d] * w2;
        }
        zd /= Z;
        const size_t o = (size_t)zrow * HD_ + h * DK_ + d;
        const unsigned short hb = f2bf(zd);
        zh[o] = hb;
        zl[o] = f2bf(zd - bf2f(hb));
    }
    __syncthreads();   // drains vmcnt: z stores complete before LOAD_Z below

    const int w  = tid >> 6;
    const int l  = tid & 63;
    const int lm = l & 15, lk8 = (l >> 4) * 8, cr = (l >> 4) * 4;
    const int R  = bx * 64 + w * 16;

    f32x4 acc[4];
    #pragma unroll
    for (int nf = 0; nf < 4; ++nf) acc[nf] = (f32x4){0.f, 0.f, 0.f, 0.f};

    bf16x8 Ah[2], Al[2];
    #define LOAD_Z(buf, ks)                                                          \
    {                                                                                \
        const size_t o = (size_t)(R + lm) * HD_ + (ks) * 32 + lk8;                   \
        Ah[buf] = *reinterpret_cast<const bf16x8*>(&zh_c[o]);                        \
        Al[buf] = *reinterpret_cast<const bf16x8*>(&zl[o]);                          \
    }
    LOAD_Z(0, 0)
    LOAD_Z(1, 1)

    #pragma unroll
    for (int ks = 0; ks < 8; ++ks) {
        const int cur = ks & 1;
        const bf16x8 a_h = Ah[cur], a_l = Al[cur];
        if (ks < 6) LOAD_Z(cur, ks + 2)
        #pragma unroll
        for (int nf = 0; nf < 4; ++nf) {
            const int o = WT_IDX(nf * 16 + lm, ks * 32 + lk8);
            const bf16x8 b_h = *reinterpret_cast<const bf16x8*>(&WTh[o]);
            const bf16x8 b_l = *reinterpret_cast<const bf16x8*>(&WTl[o]);
            acc[nf] = __builtin_amdgcn_mfma_f32_16x16x32_bf16(a_h, b_h, acc[nf], 0, 0, 0);
            acc[nf] = __builtin_amdgcn_mfma_f32_16x16x32_bf16(a_h, b_l, acc[nf], 0, 0, 0);
            acc[nf] = __builtin_amdgcn_mfma_f32_16x16x32_bf16(a_l, b_h, acc[nf], 0, 0, 0);
        }
    }
    #undef LOAD_Z

    #pragma unroll
    for (int nf = 0; nf < 4; ++nf) {
        const int col = n0 + nf * 16 + lm;
        const float bb = bO[col];
        #pragma unroll
        for (int r = 0; r < 4; ++r) {
            const int m = R + cr + r;
            out[(size_t)m * HD_ + col] = acc[nf][r] + bb;
        }
    }
}

// ---------------------------------------------------------------------------
extern "C" void kernel_launch(void* const* d_in, const int* in_sizes, int n_in,
                              void* d_out, int out_size, void* d_ws, size_t ws_size,
                              hipStream_t stream)
{
    const float* qx = (const float*)d_in[0];
    const float* kx = (const float*)d_in[1];
    const float* vx = (const float*)d_in[2];
    const float* WQ = (const float*)d_in[3];
    const float* bQ = (const float*)d_in[4];
    const float* WK = (const float*)d_in[5];
    const float* bK = (const float*)d_in[6];
    const float* WV = (const float*)d_in[7];
    const float* bV = (const float*)d_in[8];
    const float* WO = (const float*)d_in[9];
    const float* bO = (const float*)d_in[10];
    float* out = (float*)d_out;

    char* wsb = (char*)d_ws;
    float*          q    = (float*)(wsb);                            // 4 MB
    float*          k    = (float*)(wsb + (4u  << 20));              // 4 MB
    float*          v    = (float*)(wsb + (8u  << 20));              // 4 MB
    unsigned short* zh   = (unsigned short*)(wsb + (12u << 20));     // 2 MB
    unsigned short* zl   = (unsigned short*)(wsb + (14u << 20));     // 2 MB
    float*          part = (float*)(wsb + (16u << 20));              // 32 KB
    float*          pm   = (float*)(wsb + (16u << 20) + (1u << 16)); // 512 f
    float*          pZ   = pm + 512;
    float*          pzv  = pm + 1024;                                // 16384 f
    unsigned short* wT   = (unsigned short*)(wsb + (17u << 20));     // 256 KB

    gemm_qkv_fused<<<dim3(32, 13), 256, 0, stream>>>(qx, kx, vx, WQ, bQ, WK, bK, WV, bV, WO, wT, q, k, v, part);
    attn_main<<<768, 128, 0, stream>>>(q, k, v, part, pm, pZ, pzv, zh, zl);
    gemm_out_fused<<<dim3(64, 4), 256, 0, stream>>>(zh, zh, zl, pm, pZ, pzv, wT, bO, out);
}

// Round 17
// 32.778 us; speedup vs baseline: 5.5884x; 1.0327x over previous
//
#include <hip/hip_runtime.h>
#include <hip/hip_bf16.h>

#define B_   2
#define L_   2048
#define C_   256
#define H_   8
#define DK_  32
#define HD_  256
#define RSQRT_DK 0.17677669529663687f  // 1/sqrt(32)

typedef __attribute__((ext_vector_type(8))) short bf16x8;
typedef __attribute__((ext_vector_type(4))) float f32x4;
typedef __attribute__((ext_vector_type(4))) unsigned int u32x4;

__device__ __forceinline__ unsigned short f2bf(float x) {
    unsigned int u = __float_as_uint(x);
    u += 0x7fffu + ((u >> 16) & 1u);
    return (unsigned short)(u >> 16);
}
__device__ __forceinline__ float bf2f(unsigned short h) {
    return __uint_as_float((unsigned int)h << 16);
}

// Packed split-bf16 conversion: (x0,x1) -> {hi pair, lo pair} (each one u32
// of 2 bf16).  __float22bfloat162_rn lowers to HW v_cvt_pk_bf16_f32 (RTNE —
// bit-identical to the manual f2bf path).
__device__ __forceinline__ uint2 split2(float x0, float x1) {
    __hip_bfloat162 h2 = __float22bfloat162_rn(make_float2(x0, x1));
    unsigned hu; __builtin_memcpy(&hu, &h2, 4);
    const float e0 = __uint_as_float(hu << 16);
    const float e1 = __uint_as_float(hu & 0xffff0000u);
    __hip_bfloat162 l2 = __float22bfloat162_rn(make_float2(x0 - e0, x1 - e1));
    unsigned lu; __builtin_memcpy(&lu, &l2, 4);
    return make_uint2(hu, lu);
}
__device__ __forceinline__ bf16x8 as_bf16x8(u32x4 v) {
    bf16x8 r; __builtin_memcpy(&r, &v, 16); return r;
}

// LDS weight-slice layout (per 64x256 plane of shorts): row pitch 256 shorts
// (uniform bank base), 16B-chunk XOR swizzle -> b128 reads/writes at bank floor.
#define WT_IDX(n, k) (((n) << 8) + (((((k) >> 3) ^ ((n) & 7))) << 3) + ((k) & 7))

// Stage W cols [n0, n0+63], k 0..255 from fp32 into LDS planes as split-bf16
// [n][k] via packed converts.  512-thread variant: thread handles 4 chunks.
__device__ __forceinline__ void stage_wT_512(
    const float* __restrict__ W, int n0, int tid,
    short* __restrict__ WTh, short* __restrict__ WTl)
{
    const int n  = tid & 63;
    const int kc = tid >> 6;           // 0..7
    #pragma unroll
    for (int c8 = 0; c8 < 4; ++c8) {
        const int k0 = kc * 32 + c8 * 8;
        u32x4 hv, lv;
        #pragma unroll
        for (int e = 0; e < 4; ++e) {
            const float x0 = W[(size_t)(k0 + 2 * e)     * HD_ + n0 + n];
            const float x1 = W[(size_t)(k0 + 2 * e + 1) * HD_ + n0 + n];
            const uint2 hl = split2(x0, x1);
            hv[e] = hl.x; lv[e] = hl.y;
        }
        const int o = (n << 8) + ((((k0 >> 3) ^ (n & 7))) << 3);
        *reinterpret_cast<u32x4*>(&WTh[o]) = hv;
        *reinterpret_cast<u32x4*>(&WTl[o]) = lv;
    }
}

// Copy a pre-converted 64-col weight slice from global wT (hi at [n*256+k],
// lo at +65536) into swizzled LDS.  Pure coalesced bf16x8 copy (256 thr).
__device__ __forceinline__ void stage_wT_copy(
    const unsigned short* __restrict__ wTp, int n0, int tid,
    short* __restrict__ WTh, short* __restrict__ WTl)
{
    #pragma unroll
    for (int it = 0; it < 8; ++it) {
        const int c = tid + it * 256;      // chunk 0..2047
        const int n = c >> 5, k8 = c & 31;
        const size_t go = (size_t)(n0 + n) * 256 + k8 * 8;
        const int o = (n << 8) + ((k8 ^ (n & 7)) << 3);
        *reinterpret_cast<bf16x8*>(&WTh[o]) = *reinterpret_cast<const bf16x8*>(&wTp[go]);
        *reinterpret_cast<bf16x8*>(&WTl[o]) = *reinterpret_cast<const bf16x8*>(&wTp[65536 + go]);
    }
}

// ---------------------------------------------------------------------------
// K1: QKV projection, split-bf16 MFMA, self-contained.  512 thr = 8 waves,
// wave tile 16x64 (2x wave-parallelism vs round 16 for latency hiding).
// Grid (32, 13):
//  yy 0..11 : proj*4 + nt GEMM blocks (block tile 128x64), V col-sums.
//  yy 12    : convert WO (fp32 [k][n]) -> global wT split-bf16 [n][k] for K3.
// ---------------------------------------------------------------------------
__global__ __launch_bounds__(512) void gemm_qkv_fused(
    const float* __restrict__ qx, const float* __restrict__ kx, const float* __restrict__ vx,
    const float* __restrict__ WQ, const float* __restrict__ bQ,
    const float* __restrict__ WK, const float* __restrict__ bK,
    const float* __restrict__ WV, const float* __restrict__ bV,
    const float* __restrict__ WO, unsigned short* __restrict__ wT,
    float* __restrict__ q, float* __restrict__ k, float* __restrict__ v,
    float* __restrict__ part)
{
    const int bx = blockIdx.x;          // 0..31
    const int yy = blockIdx.y;          // 0..12
    const int tid = threadIdx.x;

    if (yy == 12) {
        if (tid < 256) {
            const int n  = bx * 8 + (tid >> 5);
            const int k8 = (tid & 31) * 8;
            u32x4 hv, lv;
            #pragma unroll
            for (int e = 0; e < 4; ++e) {
                const float x0 = WO[(size_t)(k8 + 2 * e)     * HD_ + n];
                const float x1 = WO[(size_t)(k8 + 2 * e + 1) * HD_ + n];
                const uint2 hl = split2(x0, x1);
                hv[e] = hl.x; lv[e] = hl.y;
            }
            *reinterpret_cast<u32x4*>(&wT[(size_t)n * 256 + k8])         = hv;
            *reinterpret_cast<u32x4*>(&wT[65536 + (size_t)n * 256 + k8]) = lv;
        }
        return;
    }

    const int proj = yy >> 2, nt = yy & 3;
    const float* A    = proj == 0 ? qx : (proj == 1 ? kx : vx);
    const float* W    = proj == 0 ? WQ : (proj == 1 ? WK : WV);
    const float* bias = proj == 0 ? bQ : (proj == 1 ? bK : bV);
    float* out        = proj == 0 ? q  : (proj == 1 ? k  : v);
    const int n0 = nt * 64;

    __shared__ short WTh[64 * 256];
    __shared__ short WTl[64 * 256];
    __shared__ float red[8][4][16];

    stage_wT_512(W, n0, tid, WTh, WTl);
    __syncthreads();

    const int w  = tid >> 6;            // wave 0..7
    const int l  = tid & 63;
    const int lm = l & 15, lk8 = (l >> 4) * 8, cr = (l >> 4) * 4;
    const int R  = bx * 128 + w * 16;   // wave tile 16x64

    f32x4 acc[4];
    #pragma unroll
    for (int nf = 0; nf < 4; ++nf) acc[nf] = (f32x4){0.f, 0.f, 0.f, 0.f};

    float4 Ab[2][2];
    #define LOAD_A(buf, ks)                                                          \
    {                                                                                \
        const float* p0 = &A[(size_t)(R + lm) * C_ + (ks) * 32 + lk8];               \
        Ab[buf][0] = *reinterpret_cast<const float4*>(p0);                           \
        Ab[buf][1] = *reinterpret_cast<const float4*>(p0 + 4);                       \
    }
    LOAD_A(0, 0)
    LOAD_A(1, 1)

    #pragma unroll
    for (int ks = 0; ks < 8; ++ks) {
        const int cur = ks & 1;
        bf16x8 ah, al;
        {
            float4 v0 = Ab[cur][0], v1 = Ab[cur][1];
            u32x4 hq, lq;
            const uint2 r0 = split2(v0.x, v0.y);
            const uint2 r1 = split2(v0.z, v0.w);
            const uint2 r2 = split2(v1.x, v1.y);
            const uint2 r3 = split2(v1.z, v1.w);
            hq[0] = r0.x; lq[0] = r0.y;
            hq[1] = r1.x; lq[1] = r1.y;
            hq[2] = r2.x; lq[2] = r2.y;
            hq[3] = r3.x; lq[3] = r3.y;
            ah = as_bf16x8(hq);
            al = as_bf16x8(lq);
        }
        if (ks < 6) LOAD_A(cur, ks + 2)
        #pragma unroll
        for (int nf = 0; nf < 4; ++nf) {
            const int o = WT_IDX(nf * 16 + lm, ks * 32 + lk8);
            const bf16x8 b_h = *reinterpret_cast<const bf16x8*>(&WTh[o]);
            const bf16x8 b_l = *reinterpret_cast<const bf16x8*>(&WTl[o]);
            acc[nf] = __builtin_amdgcn_mfma_f32_16x16x32_bf16(ah, b_h, acc[nf], 0, 0, 0);
            acc[nf] = __builtin_amdgcn_mfma_f32_16x16x32_bf16(ah, b_l, acc[nf], 0, 0, 0);
            acc[nf] = __builtin_amdgcn_mfma_f32_16x16x32_bf16(al, b_h, acc[nf], 0, 0, 0);
        }
    }
    #undef LOAD_A

    // epilogue: bias + scatter to (B,H,L,DK)
    #pragma unroll
    for (int nf = 0; nf < 4; ++nf) {
        const int col = n0 + nf * 16 + lm;
        const int h = col >> 5, d = col & 31;
        const float bb = bias[col];
        #pragma unroll
        for (int r = 0; r < 4; ++r) {
            const int m = R + cr + r;
            const int b = m >> 11, lrow = m & (L_ - 1);
            out[((size_t)(b * H_ + h) * L_ + lrow) * DK_ + d] = acc[nf][r] + bb;
        }
    }

    // V column-sum partials (deterministic, per block = 128 rows x 64 cols)
    if (proj == 2) {
        float sl[4];
        #pragma unroll
        for (int nf = 0; nf < 4; ++nf) {
            float s = acc[nf][0] + acc[nf][1] + acc[nf][2] + acc[nf][3];
            s += __shfl_xor(s, 16);
            s += __shfl_xor(s, 32);
            sl[nf] = s;          // 16-row column sums, uniform over lanes w/ same lm
        }
        if (l < 16) {
            #pragma unroll
            for (int nf = 0; nf < 4; ++nf) red[w][nf][l] = sl[nf];
        }
        __syncthreads();
        if (tid < 64) {
            const int nf = tid >> 4, lmm = tid & 15;
            float tot = 0.f;
            #pragma unroll
            for (int ww = 0; ww < 8; ++ww) tot += red[ww][nf][lmm];
            const int col = n0 + nf * 16 + lmm;
            tot += 128.f * bias[col];
            const int h = col >> 5, d = col & 31;
            const int bh = (bx >> 4) * H_ + h;       // block spans one b
            part[((size_t)bh * 32 + d) * 16 + (bx & 15)] = tot;
        }
    }
}

// ---------------------------------------------------------------------------
// K2: attention (round-16 verbatim).
//  Blocks 0..255   : interior rows, ONE ROW PER LANE, fully DIRECT loads.
//  Blocks 256..767 : global-row partials (bh, row-pair, 128-col chunk).
// 128 threads (2 waves) per block.  LDS ~1.3 KB -> high occupancy.
// ---------------------------------------------------------------------------
__global__ __launch_bounds__(128) void attn_main(
    const float* __restrict__ q, const float* __restrict__ k,
    const float* __restrict__ v, const float* __restrict__ part,
    float* __restrict__ pm, float* __restrict__ pZ, float* __restrict__ pzv,
    unsigned short* __restrict__ zh, unsigned short* __restrict__ zl)
{
    __shared__ float Sf[324];

    const int blk = blockIdx.x;
    const int t = threadIdx.x;

    if (blk < 256) {
        // ----------------- interior rows, per-lane, direct -----------------
        const int bh = blk >> 4, c = blk & 15;
        const int base = c * 128;
        const float* qb = q + (size_t)bh * L_ * DK_;
        const float* kb = k + (size_t)bh * L_ * DK_;
        const float* vb = v + (size_t)bh * L_ * DK_;
        float* vs_sh = Sf;

        if (t < 32) {
            const float4* pp = reinterpret_cast<const float4*>(&part[((size_t)bh * 32 + t) * 16]);
            float4 pa = pp[0], pb = pp[1], pc = pp[2], pd = pp[3];
            vs_sh[t] = pa.x + pa.y + pa.z + pa.w + pb.x + pb.y + pb.z + pb.w
                     + pc.x + pc.y + pc.z + pc.w + pd.x + pd.y + pd.z + pd.w;
        }
        __syncthreads();

        const int i = base + 1 + t;
        if (i <= L_ - 2) {
            float qr[32];
            {
                const float4* qp = reinterpret_cast<const float4*>(&qb[(size_t)i * DK_]);
                #pragma unroll
                for (int u2 = 0; u2 < 8; ++u2) {
                    float4 x = qp[u2];
                    qr[u2 * 4 + 0] = x.x; qr[u2 * 4 + 1] = x.y;
                    qr[u2 * 4 + 2] = x.z; qr[u2 * 4 + 3] = x.w;
                }
            }
            const int rows[5] = {0, i - 1, i, i + 1, L_ - 1};
            float sv[5];
            #pragma unroll
            for (int jj = 0; jj < 5; ++jj) {
                const float4* kp = reinterpret_cast<const float4*>(&kb[(size_t)rows[jj] * DK_]);
                float p = 0.f;
                #pragma unroll
                for (int u2 = 0; u2 < 8; ++u2) {
                    float4 kv = kp[u2];
                    p += qr[u2 * 4 + 0] * kv.x + qr[u2 * 4 + 1] * kv.y
                       + qr[u2 * 4 + 2] * kv.z + qr[u2 * 4 + 3] * kv.w;
                }
                sv[jj] = p * RSQRT_DK;
            }
            const bool v1 = (i != 1), v3 = (i != L_ - 2);
            float m = fmaxf(0.f, sv[0]);                 // zero fillers join the max
            m = fmaxf(m, sv[2]); m = fmaxf(m, sv[4]);
            if (v1) m = fmaxf(m, sv[1]);
            if (v3) m = fmaxf(m, sv[3]);
            float e[5];
            e[0] = __expf(sv[0] - m);
            e[1] = v1 ? __expf(sv[1] - m) : 0.f;
            e[2] = __expf(sv[2] - m);
            e[3] = v3 ? __expf(sv[3] - m) : 0.f;
            e[4] = __expf(sv[4] - m);
            const int ns = 3 + (int)v1 + (int)v3;
            const float e0 = __expf(-m);
            const float Z = e[0] + e[1] + e[2] + e[3] + e[4] + (float)(L_ - ns) * e0;
            const float rZ = 1.f / Z;
            const float f1 = v1 ? 1.f : 0.f, f3 = v3 ? 1.f : 0.f;

            const float4* vp0 = reinterpret_cast<const float4*>(&vb[0]);
            const float4* vp1 = reinterpret_cast<const float4*>(&vb[(size_t)rows[1] * DK_]);
            const float4* vp2 = reinterpret_cast<const float4*>(&vb[(size_t)i * DK_]);
            const float4* vp3 = reinterpret_cast<const float4*>(&vb[(size_t)rows[3] * DK_]);
            const float4* vp4 = reinterpret_cast<const float4*>(&vb[(size_t)(L_ - 1) * DK_]);

            u32x4 zhq[4], zlq[4];
            #pragma unroll
            for (int u2 = 0; u2 < 8; ++u2) {
                float4 x0 = vp0[u2], x1 = vp1[u2], x2 = vp2[u2], x3 = vp3[u2], x4 = vp4[u2];
                float a0[4] = {x0.x, x0.y, x0.z, x0.w};
                float a1[4] = {x1.x, x1.y, x1.z, x1.w};
                float a2[4] = {x2.x, x2.y, x2.z, x2.w};
                float a3[4] = {x3.x, x3.y, x3.z, x3.w};
                float a4[4] = {x4.x, x4.y, x4.z, x4.w};
                float zd4[4];
                #pragma unroll
                for (int e2 = 0; e2 < 4; ++e2) {
                    const int d = u2 * 4 + e2;
                    const float num = e[0] * a0[e2] + e[1] * a1[e2] + e[2] * a2[e2]
                                    + e[3] * a3[e2] + e[4] * a4[e2];
                    const float vp_ = a0[e2] + f1 * a1[e2] + a2[e2] + f3 * a3[e2] + a4[e2];
                    zd4[e2] = (num + e0 * (vs_sh[d] - vp_)) * rZ;
                }
                const uint2 p0 = split2(zd4[0], zd4[1]);
                const uint2 p1 = split2(zd4[2], zd4[3]);
                zhq[u2 >> 1][(u2 & 1) * 2 + 0] = p0.x;
                zhq[u2 >> 1][(u2 & 1) * 2 + 1] = p1.x;
                zlq[u2 >> 1][(u2 & 1) * 2 + 0] = p0.y;
                zlq[u2 >> 1][(u2 & 1) * 2 + 1] = p1.y;
            }
            const int b = bh >> 3, h = bh & 7;
            const size_t o = (size_t)(b * L_ + i) * HD_ + h * DK_;
            #pragma unroll
            for (int u4 = 0; u4 < 4; ++u4) {
                *reinterpret_cast<u32x4*>(&zh[o + u4 * 8]) = zhq[u4];
                *reinterpret_cast<u32x4*>(&zl[o + u4 * 8]) = zlq[u4];
            }
        }
    } else {
        // ----------------- global-row partials -----------------
        const int blk2 = blk - 256;                 // 0..511
        const int bh = blk2 >> 5;
        const int pair = (blk2 >> 4) & 1;
        const int chunk = blk2 & 15;
        const int r = pair ? (L_ - 1) : 0;
        const int j0 = chunk * 128;
        const float* qb = q + (size_t)bh * L_ * DK_;
        const float* kb = k + (size_t)bh * L_ * DK_;
        const float* vb = v + (size_t)bh * L_ * DK_;

        float* qs  = Sf;          // 32
        float* sc  = Sf + 32;     // 128
        float* red = Sf + 160;    // 4
        float* pzs = Sf + 192;    // 128

        if (t < 32) qs[t] = qb[(size_t)r * DK_ + t];
        __syncthreads();

        const int j = j0 + t;
        const float4* kr = reinterpret_cast<const float4*>(&kb[(size_t)j * DK_]);
        float p = 0.f;
        #pragma unroll
        for (int u = 0; u < 8; ++u) {
            float4 kv = kr[u];
            p += qs[u * 4 + 0] * kv.x + qs[u * 4 + 1] * kv.y
               + qs[u * 4 + 2] * kv.z + qs[u * 4 + 3] * kv.w;
        }
        p *= RSQRT_DK;

        float lm = p;
        #pragma unroll
        for (int off = 32; off; off >>= 1) lm = fmaxf(lm, __shfl_xor(lm, off, 64));
        if ((t & 63) == 0) red[t >> 6] = lm;
        __syncthreads();
        const float m = fmaxf(red[0], red[1]);

        const float e = __expf(p - m);
        sc[t] = e;
        float ls = e;
        #pragma unroll
        for (int off = 32; off; off >>= 1) ls += __shfl_xor(ls, off, 64);
        if ((t & 63) == 0) red[2 + (t >> 6)] = ls;
        __syncthreads();
        const float Zc = red[2] + red[3];

        const int d = t & 31, g = t >> 5;
        float acc = 0.f;
        #pragma unroll 4
        for (int jj = 0; jj < 32; ++jj)
            acc += sc[g * 32 + jj] * vb[(size_t)(j0 + g * 32 + jj) * DK_ + d];
        pzs[g * 32 + d] = acc;
        __syncthreads();
        if (g == 0) {
            const float s2 = pzs[d] + pzs[32 + d] + pzs[64 + d] + pzs[96 + d];
            pzv[(size_t)blk2 * 32 + d] = s2;
        }
        if (t == 0) { pm[blk2] = m; pZ[blk2] = Zc; }
    }
}

// ---------------------------------------------------------------------------
// K3: out = z @ WO + bO via split-bf16 MFMA; WO slice COPIED pre-converted
// from global wT + INLINE global-row combine (round-16 verbatim).
// Grid (64, 4), 256 thr = 4 waves; block tile 64x64.
// ---------------------------------------------------------------------------
__global__ __launch_bounds__(256) void gemm_out_fused(
    const unsigned short* __restrict__ zh_c, unsigned short* __restrict__ zh,
    unsigned short* __restrict__ zl,
    const float* __restrict__ pm, const float* __restrict__ pZ,
    const float* __restrict__ pzv,
    const unsigned short* __restrict__ wT, const float* __restrict__ bO,
    float* __restrict__ out)
{
    const int bx = blockIdx.x;          // 0..63
    const int nt = blockIdx.y;          // 0..3
    const int n0 = nt * 64;

    __shared__ short WTh[64 * 256];
    __shared__ short WTl[64 * 256];

    const int tid = threadIdx.x;
    stage_wT_copy(wT, n0, tid, WTh, WTl);

    // inline combine of global-row partials (was attn_g2_kernel)
    int zrow = -1;
    if      (bx == 0)  zrow = 0;
    else if (bx == 31) zrow = L_ - 1;
    else if (bx == 32) zrow = L_;
    else if (bx == 63) zrow = 2 * L_ - 1;
    if (zrow >= 0) {
        const int h = tid >> 5, d = tid & 31;
        const int b = zrow >> 11;
        const int r = zrow & (L_ - 1);
        const int pair = r ? 1 : 0;
        const int rowIdx = (b * H_ + h) * 2 + pair;
        const int base = rowIdx * 16;
        float m = -1e30f;
        #pragma unroll
        for (int c = 0; c < 16; ++c) m = fmaxf(m, pm[base + c]);
        float Z = 0.f, zd = 0.f;
        #pragma unroll
        for (int c = 0; c < 16; ++c) {
            const float w2 = __expf(pm[base + c] - m);
            Z  += pZ[base + c] * w2;
            zd += pzv[(size_t)(base + c) * 32 + d] * w2;
        }
        zd /= Z;
        const size_t o = (size_t)zrow * HD_ + h * DK_ + d;
        const unsigned short hb = f2bf(zd);
        zh[o] = hb;
        zl[o] = f2bf(zd - bf2f(hb));
    }
    __syncthreads();   // drains vmcnt: z stores complete before LOAD_Z below

    const int w  = tid >> 6;
    const int l  = tid & 63;
    const int lm = l & 15, lk8 = (l >> 4) * 8, cr = (l >> 4) * 4;
    const int R  = bx * 64 + w * 16;

    f32x4 acc[4];
    #pragma unroll
    for (int nf = 0; nf < 4; ++nf) acc[nf] = (f32x4){0.f, 0.f, 0.f, 0.f};

    bf16x8 Ah[2], Al[2];
    #define LOAD_Z(buf, ks)                                                          \
    {                                                                                \
        const size_t o = (size_t)(R + lm) * HD_ + (ks) * 32 + lk8;                   \
        Ah[buf] = *reinterpret_cast<const bf16x8*>(&zh_c[o]);                        \
        Al[buf] = *reinterpret_cast<const bf16x8*>(&zl[o]);                          \
    }
    LOAD_Z(0, 0)
    LOAD_Z(1, 1)

    #pragma unroll
    for (int ks = 0; ks < 8; ++ks) {
        const int cur = ks & 1;
        const bf16x8 a_h = Ah[cur], a_l = Al[cur];
        if (ks < 6) LOAD_Z(cur, ks + 2)
        #pragma unroll
        for (int nf = 0; nf < 4; ++nf) {
            const int o = WT_IDX(nf * 16 + lm, ks * 32 + lk8);
            const bf16x8 b_h = *reinterpret_cast<const bf16x8*>(&WTh[o]);
            const bf16x8 b_l = *reinterpret_cast<const bf16x8*>(&WTl[o]);
            acc[nf] = __builtin_amdgcn_mfma_f32_16x16x32_bf16(a_h, b_h, acc[nf], 0, 0, 0);
            acc[nf] = __builtin_amdgcn_mfma_f32_16x16x32_bf16(a_h, b_l, acc[nf], 0, 0, 0);
            acc[nf] = __builtin_amdgcn_mfma_f32_16x16x32_bf16(a_l, b_h, acc[nf], 0, 0, 0);
        }
    }
    #undef LOAD_Z

    #pragma unroll
    for (int nf = 0; nf < 4; ++nf) {
        const int col = n0 + nf * 16 + lm;
        const float bb = bO[col];
        #pragma unroll
        for (int r = 0; r < 4; ++r) {
            const int m = R + cr + r;
            out[(size_t)m * HD_ + col] = acc[nf][r] + bb;
        }
    }
}

// ---------------------------------------------------------------------------
extern "C" void kernel_launch(void* const* d_in, const int* in_sizes, int n_in,
                              void* d_out, int out_size, void* d_ws, size_t ws_size,
                              hipStream_t stream)
{
    const float* qx = (const float*)d_in[0];
    const float* kx = (const float*)d_in[1];
    const float* vx = (const float*)d_in[2];
    const float* WQ = (const float*)d_in[3];
    const float* bQ = (const float*)d_in[4];
    const float* WK = (const float*)d_in[5];
    const float* bK = (const float*)d_in[6];
    const float* WV = (const float*)d_in[7];
    const float* bV = (const float*)d_in[8];
    const float* WO = (const float*)d_in[9];
    const float* bO = (const float*)d_in[10];
    float* out = (float*)d_out;

    char* wsb = (char*)d_ws;
    float*          q    = (float*)(wsb);                            // 4 MB
    float*          k    = (float*)(wsb + (4u  << 20));              // 4 MB
    float*          v    = (float*)(wsb + (8u  << 20));              // 4 MB
    unsigned short* zh   = (unsigned short*)(wsb + (12u << 20));     // 2 MB
    unsigned short* zl   = (unsigned short*)(wsb + (14u << 20));     // 2 MB
    float*          part = (float*)(wsb + (16u << 20));              // 32 KB
    float*          pm   = (float*)(wsb + (16u << 20) + (1u << 16)); // 512 f
    float*          pZ   = pm + 512;
    float*          pzv  = pm + 1024;                                // 16384 f
    unsigned short* wT   = (unsigned short*)(wsb + (17u << 20));     // 256 KB

    gemm_qkv_fused<<<dim3(32, 13), 512, 0, stream>>>(qx, kx, vx, WQ, bQ, WK, bK, WV, bV, WO, wT, q, k, v, part);
    attn_main<<<768, 128, 0, stream>>>(q, k, v, part, pm, pZ, pzv, zh, zl);
    gemm_out_fused<<<dim3(64, 4), 256, 0, stream>>>(zh, zh, zl, pm, pZ, pzv, wT, bO, out);
}